// Round 1
// 487.723 us; speedup vs baseline: 1.1672x; 1.1672x over previous
//
#include <hip/hip_runtime.h>
#include <hip/hip_bf16.h>

#define NP 16384   // H*W
#define NB 4

typedef __hip_bfloat16 bf16;
typedef unsigned short u16;
typedef unsigned short us8 __attribute__((ext_vector_type(8)));
__device__ __forceinline__ float bf2f(const bf16 v) { return __bfloat162float(v); }
__device__ __forceinline__ bf16 f2bf(float v) { return __float2bfloat16(v); }
__device__ __forceinline__ float bfu(u16 h) {
  return __uint_as_float(((unsigned)h) << 16);
}
__device__ __forceinline__ u16 fbu(float v) {
  bf16 b = f2bf(v);
  return *(u16*)&b;
}

// Inputs/outputs fp32 (reference dtype). Internal tensors bf16, math fp32.

// ---------------------------------------------------------------------------
// K1: maxpool2x2(fb fp32) -> conv1x1+bias -> Y raw (pre-BN, bf16). 64x64 tile.
// wS stride 65 (bank-conflict-free weight reads); float2 pool loads.
// ---------------------------------------------------------------------------
__global__ __launch_bounds__(256) void k_pool_conv(
    const float* __restrict__ fb, const float* __restrict__ wconv,
    const float* __restrict__ bconv, bf16* __restrict__ Y) {
  __shared__ float wS[64 * 65], bS[64], Xs[4096];
  int tid = threadIdx.x;
  int b = blockIdx.x >> 8, tile = blockIdx.x & 255;
  int n0 = tile * 64;
  for (int i = tid; i < 4096; i += 256) wS[(i >> 6) * 65 + (i & 63)] = wconv[i];
  if (tid < 64) bS[tid] = bconv[tid];
  for (int i = tid; i < 4096; i += 256) {
    int c = i >> 6, px = i & 63;
    int n = n0 + px, h = n >> 7, w = n & 127;
    size_t fbase = ((size_t)((b * 64 + c) * 256 + 2 * h)) * 256 + 2 * w;
    float2 v01 = *(const float2*)(fb + fbase);
    float2 v23 = *(const float2*)(fb + fbase + 256);
    Xs[i] = fmaxf(fmaxf(v01.x, v01.y), fmaxf(v23.x, v23.y));
  }
  __syncthreads();
  int ty = tid >> 4, tx = tid & 15;
  float acc[4][4];
#pragma unroll
  for (int i = 0; i < 4; ++i) {
    float bv = bS[ty + 16 * i];
#pragma unroll
    for (int j = 0; j < 4; ++j) acc[i][j] = bv;
  }
  for (int c = 0; c < 64; ++c) {
    float xv[4], wv[4];
#pragma unroll
    for (int j = 0; j < 4; ++j) xv[j] = Xs[c * 64 + tx * 4 + j];
#pragma unroll
    for (int i = 0; i < 4; ++i) wv[i] = wS[(ty + 16 * i) * 65 + c];
#pragma unroll
    for (int i = 0; i < 4; ++i)
#pragma unroll
      for (int j = 0; j < 4; ++j) acc[i][j] = fmaf(wv[i], xv[j], acc[i][j]);
  }
#pragma unroll
  for (int i = 0; i < 4; ++i) {
    int ch = ty + 16 * i;
    bf16* yb = Y + (size_t)(b * 64 + ch) * NP + n0 + tx * 4;
#pragma unroll
    for (int j = 0; j < 4; ++j) yb[j] = f2bf(acc[i][j]);
  }
}

// ---------------------------------------------------------------------------
// K2a: stats stage 1. 512 blocks; each reduces 8192 contiguous bf16 of one
// (channel, batch, half) slab with ushort8 loads. PS[blk]=sum, PS[512+blk]=sq.
// ---------------------------------------------------------------------------
__global__ __launch_bounds__(256) void k_stats_p1(const bf16* __restrict__ Y,
                                                  float* __restrict__ PS) {
  int blk = blockIdx.x, tid = threadIdx.x;
  int o = blk >> 3, slab = blk & 7;
  int b = slab >> 1, half = slab & 1;
  const us8* vp =
      (const us8*)(Y + ((size_t)(b * 64 + o)) * NP + half * 8192);
  float s = 0.f, ss = 0.f;
#pragma unroll
  for (int it = 0; it < 4; ++it) {
    us8 v = vp[tid + 256 * it];
#pragma unroll
    for (int e = 0; e < 8; ++e) {
      float f = bfu(v[e]);
      s += f;
      ss = fmaf(f, f, ss);
    }
  }
  for (int off = 32; off > 0; off >>= 1) {
    s += __shfl_down(s, off, 64);
    ss += __shfl_down(ss, off, 64);
  }
  __shared__ float sh[8];
  int wv = tid >> 6, ln = tid & 63;
  if (ln == 0) { sh[wv] = s; sh[4 + wv] = ss; }
  __syncthreads();
  if (tid == 0) {
    PS[blk] = sh[0] + sh[1] + sh[2] + sh[3];
    PS[512 + blk] = sh[4] + sh[5] + sh[6] + sh[7];
  }
}

// K2b: stats stage 2 + BN scale/shift + scalar header (fused)
__global__ __launch_bounds__(64) void k_stats_p2(
    const float* __restrict__ PS, const float* __restrict__ bng,
    const float* __restrict__ bnb, float* __restrict__ SCALE,
    float* __restrict__ SHIFT, const float* xg, const float* fg,
    const float* pg, const float* pg2, const float* cg,
    float* __restrict__ HDR) {
  int o = threadIdx.x;
  float s = 0.f, ss = 0.f;
#pragma unroll
  for (int k = 0; k < 8; ++k) {
    s += PS[o * 8 + k];
    ss += PS[512 + o * 8 + k];
  }
  const float inv = 1.0f / (NB * NP);
  float mu = s * inv;
  float var = ss * inv - mu * mu;
  float r = rsqrtf(var + 1e-5f);
  float sc = r * bng[o];
  SCALE[o] = sc;
  SHIFT[o] = bnb[o] - mu * sc;
  if (o == 0) {
    float vpg = pg[0];
    HDR[1] = vpg * xg[0];
    HDR[2] = pg2[0] * fg[0];
    HDR[3] = 2.0f + vpg;
    HDR[4] = pg2[0];
    HDR[5] = cg[0];
  }
}

// ---------------------------------------------------------------------------
// K4: fused q|k|v conv1x1: 80 out-ch x 128 px, 5x8 thread tile.
// Xs staged as u16 bf16 (LDS 37 KB -> 4 blocks/CU). wS stride 65.
// ---------------------------------------------------------------------------
template <bool BN>
__global__ __launch_bounds__(256) void k_conv80(
    const void* __restrict__ inp, const float* __restrict__ SCALE,
    const float* __restrict__ SHIFT,
    const float* __restrict__ qw, const float* __restrict__ qb,
    const float* __restrict__ kw, const float* __restrict__ kb,
    const float* __restrict__ vw, const float* __restrict__ vb,
    bf16* __restrict__ Q, bf16* __restrict__ K, bf16* __restrict__ V) {
  __shared__ float wS[80 * 65], bS[80];
  __shared__ u16 Xs[8192];
  int tid = threadIdx.x;
  int b = blockIdx.x >> 7, tile = blockIdx.x & 127;
  int n0 = tile * 128;
  for (int i = tid; i < 512; i += 256) {
    wS[(i >> 6) * 65 + (i & 63)] = qw[i];
    wS[(8 + (i >> 6)) * 65 + (i & 63)] = kw[i];
  }
  for (int i = tid; i < 4096; i += 256)
    wS[(16 + (i >> 6)) * 65 + (i & 63)] = vw[i];
  if (tid < 8) { bS[tid] = qb[tid]; bS[8 + tid] = kb[tid]; }
  if (tid < 64) bS[16 + tid] = vb[tid];
  for (int i = tid; i < 8192; i += 256) {
    int c = i >> 7, px = i & 127;
    size_t idx = (size_t)(b * 64 + c) * NP + n0 + px;
    float v;
    if (BN) {
      v = bf2f(((const bf16*)inp)[idx]);
      v = fmaf(v, SCALE[c], SHIFT[c]);
      v = fmaxf(v, 0.f);
    } else {
      v = ((const float*)inp)[idx];
    }
    Xs[i] = fbu(v);
  }
  __syncthreads();
  int ty = tid >> 4, tx = tid & 15;
  float acc[5][8];
#pragma unroll
  for (int i = 0; i < 5; ++i) {
    float bv = bS[ty + 16 * i];
#pragma unroll
    for (int j = 0; j < 8; ++j) acc[i][j] = bv;
  }
  for (int c = 0; c < 64; ++c) {
    float xv[8], wv[5];
#pragma unroll
    for (int j = 0; j < 8; ++j) xv[j] = bfu(Xs[c * 128 + tx + 16 * j]);
#pragma unroll
    for (int i = 0; i < 5; ++i) wv[i] = wS[(ty + 16 * i) * 65 + c];
#pragma unroll
    for (int i = 0; i < 5; ++i)
#pragma unroll
      for (int j = 0; j < 8; ++j) acc[i][j] = fmaf(wv[i], xv[j], acc[i][j]);
  }
#pragma unroll
  for (int i = 0; i < 5; ++i) {
    int ch = ty + 16 * i;
    bf16* dst;
    size_t base;
    if (ch < 8) { dst = Q; base = (size_t)(b * 8 + ch) * NP; }
    else if (ch < 16) { dst = K; base = (size_t)(b * 8 + ch - 8) * NP; }
    else { dst = V; base = (size_t)(b * 64 + ch - 16) * NP; }
#pragma unroll
    for (int j = 0; j < 8; ++j) dst[base + n0 + tx + 16 * j] = f2bf(acc[i][j]);
  }
}

// ---------------------------------------------------------------------------
// K5: 128x128 bf16 plane transpose (also covers Q+K in one call: contiguous)
// ---------------------------------------------------------------------------
__global__ __launch_bounds__(256) void k_transpose(const u16* __restrict__ in,
                                                   u16* __restrict__ out) {
  int tileId = blockIdx.x & 15;
  int plane = blockIdx.x >> 4;
  int th = tileId >> 2, tw = tileId & 3;
  __shared__ u16 t[32][33];
  int lx = threadIdx.x & 31, ly = threadIdx.x >> 5;
  const u16* ip = in + (size_t)plane * NP;
  for (int i = 0; i < 32; i += 8)
    t[ly + i][lx] = ip[(size_t)(th * 32 + ly + i) * 128 + tw * 32 + lx];
  __syncthreads();
  u16* op = out + (size_t)plane * NP;
  for (int i = 0; i < 32; i += 8)
    op[(size_t)(tw * 32 + ly + i) * 128 + th * 32 + lx] = t[lx][ly + i];
}

// ---------------------------------------------------------------------------
// K6a: e_w per-row max/sumexp -> raw stats into MW/LW
// ---------------------------------------------------------------------------
__global__ __launch_bounds__(256) void k_ew_stats(
    const bf16* __restrict__ Q, const bf16* __restrict__ K,
    float* __restrict__ MW, float* __restrict__ LW) {
  int b = blockIdx.x >> 7, h = blockIdx.x & 127;
  __shared__ float qs[1024], ks[1024], red[256];
  int tid = threadIdx.x;
  for (int i = tid; i < 1024; i += 256) {
    int c = i >> 7, j = i & 127;
    size_t idx = (size_t)(b * 8 + c) * NP + (size_t)h * 128 + j;
    qs[i] = bf2f(Q[idx]);
    ks[i] = bf2f(K[idx]);
  }
  __syncthreads();
  int w = tid & 127, half = tid >> 7;
  float qr[8];
#pragma unroll
  for (int c = 0; c < 8; ++c) qr[c] = qs[c * 128 + w];
  float m = -3.0e38f;
  for (int v0 = 0; v0 < 64; ++v0) {
    int v = half * 64 + v0;
    float s = 0.f;
#pragma unroll
    for (int c = 0; c < 8; ++c) s = fmaf(qr[c], ks[c * 128 + v], s);
    m = fmaxf(m, s);
  }
  red[tid] = m;
  __syncthreads();
  float mj = fmaxf(red[w], red[128 + w]);
  __syncthreads();
  float l = 0.f;
  for (int v0 = 0; v0 < 64; ++v0) {
    int v = half * 64 + v0;
    float s = 0.f;
#pragma unroll
    for (int c = 0; c < 8; ++c) s = fmaf(qr[c], ks[c * 128 + v], s);
    l += __expf(s - mj);
  }
  red[tid] = l;
  __syncthreads();
  if (half == 0) {
    size_t o = (size_t)b * NP + (size_t)h * 128 + w;
    MW[o] = mj;
    LW[o] = red[w] + red[128 + w];
  }
}

// ---------------------------------------------------------------------------
// K6b: e_h per-row stats (diag masked) + in-place combine -> MW=M, LW=1/L
// ---------------------------------------------------------------------------
__global__ __launch_bounds__(256) void k_eh_combine(
    const bf16* __restrict__ QT, const bf16* __restrict__ KT,
    float* __restrict__ MW, float* __restrict__ LW) {
  int b = blockIdx.x >> 7, w = blockIdx.x & 127;
  __shared__ float qs[1024], ks[1024], red[256];
  int tid = threadIdx.x;
  for (int i = tid; i < 1024; i += 256) {
    int c = i >> 7, j = i & 127;
    size_t idx = (size_t)(b * 8 + c) * NP + (size_t)w * 128 + j;
    qs[i] = bf2f(QT[idx]);
    ks[i] = bf2f(KT[idx]);
  }
  __syncthreads();
  int h = tid & 127, half = tid >> 7;
  float qr[8];
#pragma unroll
  for (int c = 0; c < 8; ++c) qr[c] = qs[c * 128 + h];
  float m = -3.0e38f;
  for (int g0 = 0; g0 < 64; ++g0) {
    int g = half * 64 + g0;
    float s = 0.f;
#pragma unroll
    for (int c = 0; c < 8; ++c) s = fmaf(qr[c], ks[c * 128 + g], s);
    if (g == h) s = -1.0e30f;
    m = fmaxf(m, s);
  }
  red[tid] = m;
  __syncthreads();
  float mj = fmaxf(red[h], red[128 + h]);
  __syncthreads();
  float l = 0.f;
  for (int g0 = 0; g0 < 64; ++g0) {
    int g = half * 64 + g0;
    float s = 0.f;
#pragma unroll
    for (int c = 0; c < 8; ++c) s = fmaf(qr[c], ks[c * 128 + g], s);
    l += (g == h) ? 0.f : __expf(s - mj);
  }
  red[tid] = l;
  __syncthreads();
  if (half == 0) {
    size_t o = (size_t)b * NP + (size_t)h * 128 + w;
    float lh = red[h] + red[128 + h];
    float mw = MW[o], lw = LW[o];
    float mm = fmaxf(mw, mj);
    float ll = lw * __expf(mw - mm) + lh * __expf(mj - mm);
    MW[o] = mm;
    LW[o] = 1.0f / ll;
  }
}

// ---------------------------------------------------------------------------
// K7: merged out_w + out_h. 1024 blocks: even = av_w (b,h plane, writes ACC
// fp32 scaled), odd = av_h (b,w plane, writes OHT bf16 raw). The two halves
// are fully independent; merging doubles resident blocks/CU (2 -> 4, LDS
// 38.4 KB each) so 2 waves/SIMD instead of 1 -> latency hiding.
// ---------------------------------------------------------------------------
__global__ __launch_bounds__(128) void k_av(
    const bf16* __restrict__ Q, const bf16* __restrict__ K,
    const bf16* __restrict__ V, const bf16* __restrict__ QT,
    const bf16* __restrict__ KT, const bf16* __restrict__ VT,
    const float* __restrict__ M, const float* __restrict__ LI,
    float* __restrict__ ACC, bf16* __restrict__ OHT,
    const float* __restrict__ HDR, int scIdx, int accum) {
  int mode = blockIdx.x & 1;       // 0: out_w, 1: out_h
  int bid = blockIdx.x >> 1;
  int b = bid >> 7, h = bid & 127; // h is the fixed row (mode 0) / col (mode 1)
  const bf16* Qp = mode ? QT : Q;
  const bf16* Kp = mode ? KT : K;
  const bf16* Vp = mode ? VT : V;
  __shared__ u16 qrow[8 * 128], krow[8 * 128];
  __shared__ u16 Vs[64 * 130];
  __shared__ float As[32 * 129];
  __shared__ float Ml[128], Li[128];
  int tid = threadIdx.x;
  {  // q/k rows: 1024 u16 each = one us8 load per thread
    int c = tid >> 4, vj = tid & 15;
    const us8* qp = (const us8*)(Qp + ((size_t)(b * 8 + c)) * NP + (size_t)h * 128);
    const us8* kp = (const us8*)(Kp + ((size_t)(b * 8 + c)) * NP + (size_t)h * 128);
    us8 qv = qp[vj], kv = kp[vj];
#pragma unroll
    for (int e = 0; e < 8; ++e) {
      qrow[c * 128 + vj * 8 + e] = qv[e];
      krow[c * 128 + vj * 8 + e] = kv[e];
    }
  }
  for (int i2 = tid; i2 < 1024; i2 += 128) {  // V: 8192 u16, us8 loads
    int c = i2 >> 4, vj = i2 & 15;
    const us8* vp =
        (const us8*)(Vp + ((size_t)(b * 64 + c)) * NP + (size_t)h * 128);
    us8 vv = vp[vj];
#pragma unroll
    for (int e = 0; e < 8; ++e) Vs[c * 130 + vj * 8 + e] = vv[e];
  }
  if (mode == 0) {
    Ml[tid] = M[(size_t)b * NP + (size_t)h * 128 + tid];
    Li[tid] = LI[(size_t)b * NP + (size_t)h * 128 + tid];
  } else {
    Ml[tid] = M[(size_t)b * NP + (size_t)tid * 128 + h];
    Li[tid] = LI[(size_t)b * NP + (size_t)tid * 128 + h];
  }
  float sc = HDR[scIdx];
  int ig = tid & 7, cg = tid >> 3, c0 = cg * 4;
  int ar = tid >> 2, av = tid & 3;
  float* accBase = ACC + (size_t)(b * 64) * NP + (size_t)h * 128;
  bf16* outBase = OHT + (size_t)(b * 64) * NP + (size_t)h * 128;
  for (int chunk = 0; chunk < 4; ++chunk) {
    __syncthreads();
    {
      int w = chunk * 32 + ar;
      float mv = Ml[w], li = Li[w];
      float qr[8];
#pragma unroll
      for (int c = 0; c < 8; ++c) qr[c] = bfu(qrow[c * 128 + w]);
      for (int k = 0; k < 32; ++k) {
        int v = av * 8 + (k & 7) + (k >> 3) * 32;
        float s = 0.f;
#pragma unroll
        for (int c = 0; c < 8; ++c) s = fmaf(qr[c], bfu(krow[c * 128 + v]), s);
        float e = __expf(s - mv) * li;
        As[ar * 129 + v] = (mode && v == w) ? 0.f : e;
      }
    }
    __syncthreads();
    float acc[4][4];
#pragma unroll
    for (int ii = 0; ii < 4; ++ii)
#pragma unroll
      for (int cc = 0; cc < 4; ++cc) acc[ii][cc] = 0.f;
    for (int j = 0; j < 128; ++j) {
      float a[4], vv[4];
#pragma unroll
      for (int ii = 0; ii < 4; ++ii) a[ii] = As[(ig * 4 + ii) * 129 + j];
#pragma unroll
      for (int cc = 0; cc < 4; ++cc) vv[cc] = bfu(Vs[(c0 + cc) * 130 + j]);
#pragma unroll
      for (int ii = 0; ii < 4; ++ii)
#pragma unroll
        for (int cc = 0; cc < 4; ++cc) acc[ii][cc] = fmaf(a[ii], vv[cc], acc[ii][cc]);
    }
    int i0 = chunk * 32 + ig * 4;
    if (mode == 0) {
#pragma unroll
      for (int ii = 0; ii < 4; ++ii)
#pragma unroll
        for (int cc = 0; cc < 4; ++cc) {
          size_t oidx = (size_t)(c0 + cc) * NP + (size_t)(i0 + ii);
          float val = sc * acc[ii][cc];
          accBase[oidx] = (accum ? accBase[oidx] : 0.f) + val;
        }
    } else {
#pragma unroll
      for (int ii = 0; ii < 4; ++ii)
#pragma unroll
        for (int cc = 0; cc < 4; ++cc) {
          size_t oidx = (size_t)(c0 + cc) * NP + (size_t)(i0 + ii);
          outBase[oidx] = f2bf(acc[ii][cc]);
        }
    }
  }
}

// ---------------------------------------------------------------------------
// K8b: transpose-add: ACC[b][c][h][w] += sc * OHT[b][c][w][h]. 32x32 LDS.
// ---------------------------------------------------------------------------
__global__ __launch_bounds__(256) void k_merge(const bf16* __restrict__ OHT,
                                               float* __restrict__ ACC,
                                               const float* __restrict__ HDR,
                                               int scIdx) {
  int tileId = blockIdx.x & 15;
  int plane = blockIdx.x >> 4;
  int th = tileId >> 2, tw = tileId & 3;
  __shared__ float t[32][33];
  int lx = threadIdx.x & 31, ly = threadIdx.x >> 5;
  const bf16* ip = OHT + (size_t)plane * NP;
  for (int i = 0; i < 32; i += 8)
    t[ly + i][lx] = bf2f(ip[(size_t)(th * 32 + ly + i) * 128 + tw * 32 + lx]);
  __syncthreads();
  float sc = HDR[scIdx];
  float* op = ACC + (size_t)plane * NP;
  for (int i = 0; i < 32; i += 8) {
    int h = tw * 32 + ly + i, w = th * 32 + lx;
    op[(size_t)h * 128 + w] += sc * t[lx][ly + i];
  }
}

// ---------------------------------------------------------------------------
// K9: partial Gram of y=BN(Y) applied at staging
// ---------------------------------------------------------------------------
__global__ __launch_bounds__(256) void k_gram(const bf16* __restrict__ Y,
                                              const float* __restrict__ SCALE,
                                              const float* __restrict__ SHIFT,
                                              float* __restrict__ GP) {
  int b = blockIdx.x >> 5, ch = blockIdx.x & 31;
  int tid = threadIdx.x;
  __shared__ float fs[64 * 129];
  int cg = tid >> 4, dg = tid & 15;
  float acc[4][4];
#pragma unroll
  for (int i = 0; i < 4; ++i)
#pragma unroll
    for (int jx = 0; jx < 4; ++jx) acc[i][jx] = 0.f;
  const bf16* yb = Y + (size_t)b * 64 * NP + ch * 512;
  for (int t = 0; t < 4; ++t) {
    __syncthreads();
    for (int idx = tid; idx < 8192; idx += 256) {
      int c = idx >> 7, j = idx & 127;
      float v = fmaf(bf2f(yb[(size_t)c * NP + t * 128 + j]), SCALE[c], SHIFT[c]);
      fs[c * 129 + j] = fmaxf(v, 0.f);
    }
    __syncthreads();
    for (int j = 0; j < 128; ++j) {
      float a[4], d[4];
#pragma unroll
      for (int i = 0; i < 4; ++i) a[i] = fs[(cg * 4 + i) * 129 + j];
#pragma unroll
      for (int i = 0; i < 4; ++i) d[i] = fs[(dg * 4 + i) * 129 + j];
#pragma unroll
      for (int i = 0; i < 4; ++i)
#pragma unroll
        for (int jx = 0; jx < 4; ++jx) acc[i][jx] = fmaf(a[i], d[jx], acc[i][jx]);
    }
  }
  float* gp = GP + ((size_t)b * 32 + ch) * 4096;
#pragma unroll
  for (int i = 0; i < 4; ++i)
#pragma unroll
    for (int jx = 0; jx < 4; ++jx)
      gp[(cg * 4 + i) * 64 + dg * 4 + jx] = acc[i][jx];
}

// K10: reduce Gram partials; row softmax of (max-E)
__global__ __launch_bounds__(256) void k_gram_reduce(const float* __restrict__ GP,
                                                     float* __restrict__ CATT) {
  int b = blockIdx.x, tid = threadIdx.x;
  __shared__ float Es[4096];
  for (int e = tid; e < 4096; e += 256) {
    float s = 0.f;
    for (int k = 0; k < 32; ++k) s += GP[((size_t)b * 32 + k) * 4096 + e];
    Es[e] = s;
  }
  __syncthreads();
  int wv = tid >> 6, ln = tid & 63;
  for (int r = wv; r < 64; r += 4) {
    float v = Es[r * 64 + ln];
    float mn = v;
    for (int off = 32; off; off >>= 1) mn = fminf(mn, __shfl_xor(mn, off, 64));
    float e = __expf(mn - v);
    float s = e;
    for (int off = 32; off; off >>= 1) s += __shfl_xor(s, off, 64);
    CATT[((size_t)b * 64 + r) * 64 + ln] = e / s;
  }
}

// ---------------------------------------------------------------------------
// K11: out = (2+pg)*x + pg2*y + ACC + cg*(catt@y). In-place fp32 on d_out.
// ---------------------------------------------------------------------------
__global__ __launch_bounds__(256) void k_final(
    const float* __restrict__ x, const bf16* __restrict__ Y,
    const float* __restrict__ SCALE, const float* __restrict__ SHIFT,
    const float* __restrict__ CATT, const float* __restrict__ HDR,
    float* __restrict__ OUT) {
  __shared__ float attS[64 * 65], Ys[64 * 65];
  int tid = threadIdx.x;
  int b = blockIdx.x >> 8, tile = blockIdx.x & 255;
  int n0 = tile * 64;
  for (int i = tid; i < 4096; i += 256)
    attS[(i >> 6) * 65 + (i & 63)] = CATT[(size_t)b * 4096 + i];
  for (int i = tid; i < 4096; i += 256) {
    int d = i >> 6, px = i & 63;
    float v = fmaf(bf2f(Y[(size_t)(b * 64 + d) * NP + n0 + px]), SCALE[d], SHIFT[d]);
    Ys[d * 65 + px] = fmaxf(v, 0.f);
  }
  __syncthreads();
  int cg = tid >> 4, pgx = tid & 15;
  int c0 = cg * 4, p0 = pgx * 4;
  float acc[4][4];
#pragma unroll
  for (int i = 0; i < 4; ++i)
#pragma unroll
    for (int j = 0; j < 4; ++j) acc[i][j] = 0.f;
  for (int d = 0; d < 64; ++d) {
    float a[4], yv[4];
#pragma unroll
    for (int i = 0; i < 4; ++i) a[i] = attS[(c0 + i) * 65 + d];
#pragma unroll
    for (int j = 0; j < 4; ++j) yv[j] = Ys[d * 65 + p0 + j];
#pragma unroll
    for (int i = 0; i < 4; ++i)
#pragma unroll
      for (int j = 0; j < 4; ++j) acc[i][j] = fmaf(a[i], yv[j], acc[i][j]);
  }
  float c2pg = HDR[3], fpg2 = HDR[4], fcg = HDR[5];
#pragma unroll
  for (int i = 0; i < 4; ++i) {
    size_t base = (size_t)(b * 64 + c0 + i) * NP + n0 + p0;
#pragma unroll
    for (int j = 0; j < 4; ++j) {
      float yv = Ys[(c0 + i) * 65 + p0 + j];
      OUT[base + j] =
          c2pg * x[base + j] + fpg2 * yv + OUT[base + j] + fcg * acc[i][j];
    }
  }
}

// ---------------------------------------------------------------------------
extern "C" void kernel_launch(void* const* d_in, const int* in_sizes, int n_in,
                              void* d_out, int out_size, void* d_ws, size_t ws_size,
                              hipStream_t stream) {
  const float* x = (const float*)d_in[0];
  const float* fbp = (const float*)d_in[1];

  // Workspace: 38,277,120 bytes total (proven extent).
  char* base = (char*)d_ws;
  float* HDR = (float*)base;
  float* SCALE = HDR + 16;
  float* SHIFT = SCALE + 64;
  char* p = base + 4096;
  bf16* Y = (bf16*)p;   p += 8388608;
  bf16* Q = (bf16*)p;   p += 1048576;
  bf16* K = (bf16*)p;   p += 1048576;
  bf16* QT = (bf16*)p;  p += 1048576;
  bf16* KT = (bf16*)p;  p += 1048576;
  bf16* V = (bf16*)p;   p += 8388608;
  bf16* VT = (bf16*)p;  p += 8388608;
  float* MW = (float*)p; p += 262144;   // joint M after combine
  float* LW = (float*)p; p += 262144;   // joint 1/L after combine
  bf16* OHT = (bf16*)p;  p += 8388608;  // out_h in [b][c][w][h] layout
  float* ACC = (float*)d_out;           // fp32, 16 MB
  float* PS = (float*)Q;     // stats partials (4 KB), Q unused until conv80
  float* GP = (float*)Q;     // Gram partials after module loop
  float* CATT = (float*)QT;  // reuses QT

  k_pool_conv<<<1024, 256, 0, stream>>>(fbp, (const float*)d_in[2],
                                        (const float*)d_in[3], Y);
  k_stats_p1<<<512, 256, 0, stream>>>(Y, PS);
  k_stats_p2<<<1, 64, 0, stream>>>(PS, (const float*)d_in[4],
                                   (const float*)d_in[5], SCALE, SHIFT,
                                   (const float*)d_in[12], (const float*)d_in[19],
                                   (const float*)d_in[20], (const float*)d_in[21],
                                   (const float*)d_in[22], HDR);

  for (int m = 0; m < 2; ++m) {
    const float *qw, *qb, *kw, *kb, *vw, *vb;
    if (m == 0) {
      qw = (const float*)d_in[6]; qb = (const float*)d_in[7];
      kw = (const float*)d_in[8]; kb = (const float*)d_in[9];
      vw = (const float*)d_in[10]; vb = (const float*)d_in[11];
    } else {
      qw = (const float*)d_in[13]; qb = (const float*)d_in[14];
      kw = (const float*)d_in[15]; kb = (const float*)d_in[16];
      vw = (const float*)d_in[17]; vb = (const float*)d_in[18];
    }
    if (m == 0)
      k_conv80<false><<<512, 256, 0, stream>>>(x, SCALE, SHIFT, qw, qb, kw, kb,
                                               vw, vb, Q, K, V);
    else
      k_conv80<true><<<512, 256, 0, stream>>>(Y, SCALE, SHIFT, qw, qb, kw, kb,
                                              vw, vb, Q, K, V);
    // Q,K contiguous and QT,KT contiguous: one call transposes both (64 planes)
    k_transpose<<<1024, 256, 0, stream>>>((const u16*)Q, (u16*)QT);
    k_transpose<<<4096, 256, 0, stream>>>((const u16*)V, (u16*)VT);
    k_ew_stats<<<512, 256, 0, stream>>>(Q, K, MW, LW);
    k_eh_combine<<<512, 256, 0, stream>>>(QT, KT, MW, LW);
    // merged out_w + out_h: 1024 blocks (even=w, odd=h) -> 4 blocks/CU
    k_av<<<1024, 128, 0, stream>>>(Q, K, V, QT, KT, VT, MW, LW, ACC, OHT,
                                   HDR, 1 + m, m);
    k_merge<<<4096, 256, 0, stream>>>(OHT, ACC, HDR, 1 + m);
  }

  k_gram<<<128, 256, 0, stream>>>(Y, SCALE, SHIFT, GP);
  k_gram_reduce<<<4, 256, 0, stream>>>(GP, CATT);
  k_final<<<1024, 256, 0, stream>>>(x, Y, SCALE, SHIFT, CATT, HDR,
                                    (float*)d_out);
}

// Round 2
// 474.967 us; speedup vs baseline: 1.1985x; 1.0269x over previous
//
#include <hip/hip_runtime.h>
#include <hip/hip_bf16.h>

#define NP 16384   // H*W
#define NB 4

typedef __hip_bfloat16 bf16;
typedef unsigned short u16;
typedef unsigned short us8 __attribute__((ext_vector_type(8)));
typedef unsigned short us4 __attribute__((ext_vector_type(4)));
typedef float f32x4 __attribute__((ext_vector_type(4)));
__device__ __forceinline__ float bf2f(const bf16 v) { return __bfloat162float(v); }
__device__ __forceinline__ bf16 f2bf(float v) { return __float2bfloat16(v); }
__device__ __forceinline__ float bfu(u16 h) {
  return __uint_as_float(((unsigned)h) << 16);
}
__device__ __forceinline__ u16 fbu(float v) {
  bf16 b = f2bf(v);
  return *(u16*)&b;
}

// Inputs/outputs fp32 (reference dtype). Internal tensors bf16, math fp32.

// ---------------------------------------------------------------------------
// K1: maxpool2x2(fb fp32) -> conv1x1+bias -> Y raw (pre-BN, bf16). 64x64 tile.
// wS stride 65 (bank-conflict-free weight reads); float2 pool loads.
// ---------------------------------------------------------------------------
__global__ __launch_bounds__(256) void k_pool_conv(
    const float* __restrict__ fb, const float* __restrict__ wconv,
    const float* __restrict__ bconv, bf16* __restrict__ Y) {
  __shared__ float wS[64 * 65], bS[64], Xs[4096];
  int tid = threadIdx.x;
  int b = blockIdx.x >> 8, tile = blockIdx.x & 255;
  int n0 = tile * 64;
  for (int i = tid; i < 4096; i += 256) wS[(i >> 6) * 65 + (i & 63)] = wconv[i];
  if (tid < 64) bS[tid] = bconv[tid];
  for (int i = tid; i < 4096; i += 256) {
    int c = i >> 6, px = i & 63;
    int n = n0 + px, h = n >> 7, w = n & 127;
    size_t fbase = ((size_t)((b * 64 + c) * 256 + 2 * h)) * 256 + 2 * w;
    float2 v01 = *(const float2*)(fb + fbase);
    float2 v23 = *(const float2*)(fb + fbase + 256);
    Xs[i] = fmaxf(fmaxf(v01.x, v01.y), fmaxf(v23.x, v23.y));
  }
  __syncthreads();
  int ty = tid >> 4, tx = tid & 15;
  float acc[4][4];
#pragma unroll
  for (int i = 0; i < 4; ++i) {
    float bv = bS[ty + 16 * i];
#pragma unroll
    for (int j = 0; j < 4; ++j) acc[i][j] = bv;
  }
  for (int c = 0; c < 64; ++c) {
    float xv[4], wv[4];
#pragma unroll
    for (int j = 0; j < 4; ++j) xv[j] = Xs[c * 64 + tx * 4 + j];
#pragma unroll
    for (int i = 0; i < 4; ++i) wv[i] = wS[(ty + 16 * i) * 65 + c];
#pragma unroll
    for (int i = 0; i < 4; ++i)
#pragma unroll
      for (int j = 0; j < 4; ++j) acc[i][j] = fmaf(wv[i], xv[j], acc[i][j]);
  }
#pragma unroll
  for (int i = 0; i < 4; ++i) {
    int ch = ty + 16 * i;
    bf16* yb = Y + (size_t)(b * 64 + ch) * NP + n0 + tx * 4;
#pragma unroll
    for (int j = 0; j < 4; ++j) yb[j] = f2bf(acc[i][j]);
  }
}

// ---------------------------------------------------------------------------
// K2a: stats stage 1. 512 blocks; each reduces 8192 contiguous bf16 of one
// (channel, batch, half) slab with ushort8 loads. PS[blk]=sum, PS[512+blk]=sq.
// ---------------------------------------------------------------------------
__global__ __launch_bounds__(256) void k_stats_p1(const bf16* __restrict__ Y,
                                                  float* __restrict__ PS) {
  int blk = blockIdx.x, tid = threadIdx.x;
  int o = blk >> 3, slab = blk & 7;
  int b = slab >> 1, half = slab & 1;
  const us8* vp =
      (const us8*)(Y + ((size_t)(b * 64 + o)) * NP + half * 8192);
  float s = 0.f, ss = 0.f;
#pragma unroll
  for (int it = 0; it < 4; ++it) {
    us8 v = vp[tid + 256 * it];
#pragma unroll
    for (int e = 0; e < 8; ++e) {
      float f = bfu(v[e]);
      s += f;
      ss = fmaf(f, f, ss);
    }
  }
  for (int off = 32; off > 0; off >>= 1) {
    s += __shfl_down(s, off, 64);
    ss += __shfl_down(ss, off, 64);
  }
  __shared__ float sh[8];
  int wv = tid >> 6, ln = tid & 63;
  if (ln == 0) { sh[wv] = s; sh[4 + wv] = ss; }
  __syncthreads();
  if (tid == 0) {
    PS[blk] = sh[0] + sh[1] + sh[2] + sh[3];
    PS[512 + blk] = sh[4] + sh[5] + sh[6] + sh[7];
  }
}

// K2b: stats stage 2 + BN scale/shift + scalar header (fused)
__global__ __launch_bounds__(64) void k_stats_p2(
    const float* __restrict__ PS, const float* __restrict__ bng,
    const float* __restrict__ bnb, float* __restrict__ SCALE,
    float* __restrict__ SHIFT, const float* xg, const float* fg,
    const float* pg, const float* pg2, const float* cg,
    float* __restrict__ HDR) {
  int o = threadIdx.x;
  float s = 0.f, ss = 0.f;
#pragma unroll
  for (int k = 0; k < 8; ++k) {
    s += PS[o * 8 + k];
    ss += PS[512 + o * 8 + k];
  }
  const float inv = 1.0f / (NB * NP);
  float mu = s * inv;
  float var = ss * inv - mu * mu;
  float r = rsqrtf(var + 1e-5f);
  float sc = r * bng[o];
  SCALE[o] = sc;
  SHIFT[o] = bnb[o] - mu * sc;
  if (o == 0) {
    float vpg = pg[0];
    HDR[1] = vpg * xg[0];
    HDR[2] = pg2[0] * fg[0];
    HDR[3] = 2.0f + vpg;
    HDR[4] = pg2[0];
    HDR[5] = cg[0];
  }
}

// ---------------------------------------------------------------------------
// K4: fused q|k|v conv1x1: 80 out-ch x 128 px, 5x8 thread tile.
// Xs staged as u16 bf16 (LDS 37 KB -> 4 blocks/CU). wS stride 65.
// ---------------------------------------------------------------------------
template <bool BN>
__global__ __launch_bounds__(256) void k_conv80(
    const void* __restrict__ inp, const float* __restrict__ SCALE,
    const float* __restrict__ SHIFT,
    const float* __restrict__ qw, const float* __restrict__ qb,
    const float* __restrict__ kw, const float* __restrict__ kb,
    const float* __restrict__ vw, const float* __restrict__ vb,
    bf16* __restrict__ Q, bf16* __restrict__ K, bf16* __restrict__ V) {
  __shared__ float wS[80 * 65], bS[80];
  __shared__ u16 Xs[8192];
  int tid = threadIdx.x;
  int b = blockIdx.x >> 7, tile = blockIdx.x & 127;
  int n0 = tile * 128;
  for (int i = tid; i < 512; i += 256) {
    wS[(i >> 6) * 65 + (i & 63)] = qw[i];
    wS[(8 + (i >> 6)) * 65 + (i & 63)] = kw[i];
  }
  for (int i = tid; i < 4096; i += 256)
    wS[(16 + (i >> 6)) * 65 + (i & 63)] = vw[i];
  if (tid < 8) { bS[tid] = qb[tid]; bS[8 + tid] = kb[tid]; }
  if (tid < 64) bS[16 + tid] = vb[tid];
  for (int i = tid; i < 8192; i += 256) {
    int c = i >> 7, px = i & 127;
    size_t idx = (size_t)(b * 64 + c) * NP + n0 + px;
    float v;
    if (BN) {
      v = bf2f(((const bf16*)inp)[idx]);
      v = fmaf(v, SCALE[c], SHIFT[c]);
      v = fmaxf(v, 0.f);
    } else {
      v = ((const float*)inp)[idx];
    }
    Xs[i] = fbu(v);
  }
  __syncthreads();
  int ty = tid >> 4, tx = tid & 15;
  float acc[5][8];
#pragma unroll
  for (int i = 0; i < 5; ++i) {
    float bv = bS[ty + 16 * i];
#pragma unroll
    for (int j = 0; j < 8; ++j) acc[i][j] = bv;
  }
  for (int c = 0; c < 64; ++c) {
    float xv[8], wv[5];
#pragma unroll
    for (int j = 0; j < 8; ++j) xv[j] = bfu(Xs[c * 128 + tx + 16 * j]);
#pragma unroll
    for (int i = 0; i < 5; ++i) wv[i] = wS[(ty + 16 * i) * 65 + c];
#pragma unroll
    for (int i = 0; i < 5; ++i)
#pragma unroll
      for (int j = 0; j < 8; ++j) acc[i][j] = fmaf(wv[i], xv[j], acc[i][j]);
  }
#pragma unroll
  for (int i = 0; i < 5; ++i) {
    int ch = ty + 16 * i;
    bf16* dst;
    size_t base;
    if (ch < 8) { dst = Q; base = (size_t)(b * 8 + ch) * NP; }
    else if (ch < 16) { dst = K; base = (size_t)(b * 8 + ch - 8) * NP; }
    else { dst = V; base = (size_t)(b * 64 + ch - 16) * NP; }
#pragma unroll
    for (int j = 0; j < 8; ++j) dst[base + n0 + tx + 16 * j] = f2bf(acc[i][j]);
  }
}

// ---------------------------------------------------------------------------
// K5: 128x128 bf16 plane transpose (also covers Q+K in one call: contiguous)
// ---------------------------------------------------------------------------
__global__ __launch_bounds__(256) void k_transpose(const u16* __restrict__ in,
                                                   u16* __restrict__ out) {
  int tileId = blockIdx.x & 15;
  int plane = blockIdx.x >> 4;
  int th = tileId >> 2, tw = tileId & 3;
  __shared__ u16 t[32][33];
  int lx = threadIdx.x & 31, ly = threadIdx.x >> 5;
  const u16* ip = in + (size_t)plane * NP;
  for (int i = 0; i < 32; i += 8)
    t[ly + i][lx] = ip[(size_t)(th * 32 + ly + i) * 128 + tw * 32 + lx];
  __syncthreads();
  u16* op = out + (size_t)plane * NP;
  for (int i = 0; i < 32; i += 8)
    op[(size_t)(tw * 32 + ly + i) * 128 + th * 32 + lx] = t[lx][ly + i];
}

// ---------------------------------------------------------------------------
// K6a: e_w per-row max/sumexp -> raw stats into MW/LW
// ---------------------------------------------------------------------------
__global__ __launch_bounds__(256) void k_ew_stats(
    const bf16* __restrict__ Q, const bf16* __restrict__ K,
    float* __restrict__ MW, float* __restrict__ LW) {
  int b = blockIdx.x >> 7, h = blockIdx.x & 127;
  __shared__ float qs[1024], ks[1024], red[256];
  int tid = threadIdx.x;
  for (int i = tid; i < 1024; i += 256) {
    int c = i >> 7, j = i & 127;
    size_t idx = (size_t)(b * 8 + c) * NP + (size_t)h * 128 + j;
    qs[i] = bf2f(Q[idx]);
    ks[i] = bf2f(K[idx]);
  }
  __syncthreads();
  int w = tid & 127, half = tid >> 7;
  float qr[8];
#pragma unroll
  for (int c = 0; c < 8; ++c) qr[c] = qs[c * 128 + w];
  float m = -3.0e38f;
  for (int v0 = 0; v0 < 64; ++v0) {
    int v = half * 64 + v0;
    float s = 0.f;
#pragma unroll
    for (int c = 0; c < 8; ++c) s = fmaf(qr[c], ks[c * 128 + v], s);
    m = fmaxf(m, s);
  }
  red[tid] = m;
  __syncthreads();
  float mj = fmaxf(red[w], red[128 + w]);
  __syncthreads();
  float l = 0.f;
  for (int v0 = 0; v0 < 64; ++v0) {
    int v = half * 64 + v0;
    float s = 0.f;
#pragma unroll
    for (int c = 0; c < 8; ++c) s = fmaf(qr[c], ks[c * 128 + v], s);
    l += __expf(s - mj);
  }
  red[tid] = l;
  __syncthreads();
  if (half == 0) {
    size_t o = (size_t)b * NP + (size_t)h * 128 + w;
    MW[o] = mj;
    LW[o] = red[w] + red[128 + w];
  }
}

// ---------------------------------------------------------------------------
// K6b: e_h per-row stats (diag masked) + in-place combine -> MW=M, LW=1/L
// ---------------------------------------------------------------------------
__global__ __launch_bounds__(256) void k_eh_combine(
    const bf16* __restrict__ QT, const bf16* __restrict__ KT,
    float* __restrict__ MW, float* __restrict__ LW) {
  int b = blockIdx.x >> 7, w = blockIdx.x & 127;
  __shared__ float qs[1024], ks[1024], red[256];
  int tid = threadIdx.x;
  for (int i = tid; i < 1024; i += 256) {
    int c = i >> 7, j = i & 127;
    size_t idx = (size_t)(b * 8 + c) * NP + (size_t)w * 128 + j;
    qs[i] = bf2f(QT[idx]);
    ks[i] = bf2f(KT[idx]);
  }
  __syncthreads();
  int h = tid & 127, half = tid >> 7;
  float qr[8];
#pragma unroll
  for (int c = 0; c < 8; ++c) qr[c] = qs[c * 128 + h];
  float m = -3.0e38f;
  for (int g0 = 0; g0 < 64; ++g0) {
    int g = half * 64 + g0;
    float s = 0.f;
#pragma unroll
    for (int c = 0; c < 8; ++c) s = fmaf(qr[c], ks[c * 128 + g], s);
    if (g == h) s = -1.0e30f;
    m = fmaxf(m, s);
  }
  red[tid] = m;
  __syncthreads();
  float mj = fmaxf(red[h], red[128 + h]);
  __syncthreads();
  float l = 0.f;
  for (int g0 = 0; g0 < 64; ++g0) {
    int g = half * 64 + g0;
    float s = 0.f;
#pragma unroll
    for (int c = 0; c < 8; ++c) s = fmaf(qr[c], ks[c * 128 + g], s);
    l += (g == h) ? 0.f : __expf(s - mj);
  }
  red[tid] = l;
  __syncthreads();
  if (half == 0) {
    size_t o = (size_t)b * NP + (size_t)h * 128 + w;
    float lh = red[h] + red[128 + h];
    float mw = MW[o], lw = LW[o];
    float mm = fmaxf(mw, mj);
    float ll = lw * __expf(mw - mm) + lh * __expf(mj - mm);
    MW[o] = mm;
    LW[o] = 1.0f / ll;
  }
}

// ---------------------------------------------------------------------------
// K7: merged out_w + out_h, LDS layouts transposed for vector reads.
// All j-indexed tiles stored at permuted row p(j) = ((j&7)<<4)|(j>>3) so the
// us8-load staging scatter-writes are bank-conflict-free.
//   qT/kT: [p][c] 8 u16/row -> score loop: 1 ds_read_b128 per k (was 8 u16).
//   VsT:   [p][c] 68 u16/row -> PV loop: 1 ds_read_b64 per j (was 4 u16).
//   AsT:   [p][i] 36 f32/row, i rotated by 4*((v>>3)&3) -> producer writes
//          exactly 2-way (free), consumer 1 ds_read_b128 per j (was 4 b32).
// LDS = 40960 B -> 4 blocks/CU (unchanged).
// ---------------------------------------------------------------------------
__global__ __launch_bounds__(128) void k_av(
    const bf16* __restrict__ Q, const bf16* __restrict__ K,
    const bf16* __restrict__ V, const bf16* __restrict__ QT,
    const bf16* __restrict__ KT, const bf16* __restrict__ VT,
    const float* __restrict__ M, const float* __restrict__ LI,
    float* __restrict__ ACC, bf16* __restrict__ OHT,
    const float* __restrict__ HDR, int scIdx, int accum) {
  int mode = blockIdx.x & 1;       // 0: out_w, 1: out_h
  int bid = blockIdx.x >> 1;
  int b = bid >> 7, h = bid & 127;
  const bf16* Qp = mode ? QT : Q;
  const bf16* Kp = mode ? KT : K;
  const bf16* Vp = mode ? VT : V;
  __shared__ __align__(16) u16 qT[128 * 8];
  __shared__ __align__(16) u16 kT[128 * 8];
  __shared__ __align__(16) u16 VsT[128 * 68];
  __shared__ __align__(16) float AsT[128 * 36];
  __shared__ float Ml[128], Li[128];
  int tid = threadIdx.x;
  {  // q/k rows: 1024 u16 each = one us8 load per thread, scatter to [p][c]
    int c = tid >> 4, vj = tid & 15;
    const us8* qp = (const us8*)(Qp + ((size_t)(b * 8 + c)) * NP + (size_t)h * 128);
    const us8* kp = (const us8*)(Kp + ((size_t)(b * 8 + c)) * NP + (size_t)h * 128);
    us8 qv = qp[vj], kv = kp[vj];
#pragma unroll
    for (int e = 0; e < 8; ++e) {
      int j = vj * 8 + e;
      int p = ((j & 7) << 4) | (j >> 3);
      qT[p * 8 + c] = qv[e];
      kT[p * 8 + c] = kv[e];
    }
  }
  for (int i2 = tid; i2 < 1024; i2 += 128) {  // V: 8192 u16, scatter to [p][c]
    int c = i2 >> 4, vj = i2 & 15;
    const us8* vp =
        (const us8*)(Vp + ((size_t)(b * 64 + c)) * NP + (size_t)h * 128);
    us8 vv = vp[vj];
#pragma unroll
    for (int e = 0; e < 8; ++e) {
      int j = vj * 8 + e;
      int p = ((j & 7) << 4) | (j >> 3);
      VsT[p * 68 + c] = vv[e];
    }
  }
  if (mode == 0) {
    Ml[tid] = M[(size_t)b * NP + (size_t)h * 128 + tid];
    Li[tid] = LI[(size_t)b * NP + (size_t)h * 128 + tid];
  } else {
    Ml[tid] = M[(size_t)b * NP + (size_t)tid * 128 + h];
    Li[tid] = LI[(size_t)b * NP + (size_t)tid * 128 + h];
  }
  float sc = HDR[scIdx];
  int ig = tid & 7, cg = tid >> 3, c0 = cg * 4;
  int ar = tid >> 2, av = tid & 3;
  float* accBase = ACC + (size_t)(b * 64) * NP + (size_t)h * 128;
  bf16* outBase = OHT + (size_t)(b * 64) * NP + (size_t)h * 128;
  for (int chunk = 0; chunk < 4; ++chunk) {
    __syncthreads();
    {
      int w = chunk * 32 + ar;
      float mv = Ml[w], li = Li[w];
      int pw = ((w & 7) << 4) | (w >> 3);
      us8 qv = *(const us8*)&qT[pw * 8];
      float qr[8];
#pragma unroll
      for (int c = 0; c < 8; ++c) qr[c] = bfu(qv[c]);
      for (int k = 0; k < 32; ++k) {
        int v = av * 8 + (k & 7) + ((k >> 3) << 5);
        int pv = ((v & 7) << 4) | (v >> 3);
        us8 kv = *(const us8*)&kT[pv * 8];
        float s = 0.f;
#pragma unroll
        for (int c = 0; c < 8; ++c) s = fmaf(qr[c], bfu(kv[c]), s);
        float e = __expf(s - mv) * li;
        // row = p(v); within-row rotate i by 4*((v>>3)&3): writes 2-way free
        AsT[pv * 36 + ((ar + 4 * ((v >> 3) & 3)) & 31)] =
            (mode && v == w) ? 0.f : e;
      }
    }
    __syncthreads();
    float acc[4][4];
#pragma unroll
    for (int ii = 0; ii < 4; ++ii)
#pragma unroll
      for (int cc = 0; cc < 4; ++cc) acc[ii][cc] = 0.f;
    // iterate physical (permuted) rows: AsT and VsT share the same perm,
    // and the j-reduction order is irrelevant.
    for (int p = 0; p < 128; ++p) {
      // inverse rotate: stored i' = (i + 4*((v>>3)&3))&31 ; (v>>3)&3 = p&3
      int ao = ((ig + (p & 3)) & 7) << 2;
      f32x4 a4 = *(const f32x4*)&AsT[p * 36 + ao];
      us4 v4 = *(const us4*)&VsT[p * 68 + c0];
      float vv[4];
#pragma unroll
      for (int cc = 0; cc < 4; ++cc) vv[cc] = bfu(v4[cc]);
#pragma unroll
      for (int ii = 0; ii < 4; ++ii)
#pragma unroll
        for (int cc = 0; cc < 4; ++cc)
          acc[ii][cc] = fmaf(a4[ii], vv[cc], acc[ii][cc]);
    }
    int i0 = chunk * 32 + ig * 4;
    if (mode == 0) {
#pragma unroll
      for (int ii = 0; ii < 4; ++ii)
#pragma unroll
        for (int cc = 0; cc < 4; ++cc) {
          size_t oidx = (size_t)(c0 + cc) * NP + (size_t)(i0 + ii);
          float val = sc * acc[ii][cc];
          accBase[oidx] = (accum ? accBase[oidx] : 0.f) + val;
        }
    } else {
#pragma unroll
      for (int ii = 0; ii < 4; ++ii)
#pragma unroll
        for (int cc = 0; cc < 4; ++cc) {
          size_t oidx = (size_t)(c0 + cc) * NP + (size_t)(i0 + ii);
          outBase[oidx] = f2bf(acc[ii][cc]);
        }
    }
  }
}

// ---------------------------------------------------------------------------
// K8b: transpose-add: ACC[b][c][h][w] += sc * OHT[b][c][w][h]. 32x32 LDS.
// ---------------------------------------------------------------------------
__global__ __launch_bounds__(256) void k_merge(const bf16* __restrict__ OHT,
                                               float* __restrict__ ACC,
                                               const float* __restrict__ HDR,
                                               int scIdx) {
  int tileId = blockIdx.x & 15;
  int plane = blockIdx.x >> 4;
  int th = tileId >> 2, tw = tileId & 3;
  __shared__ float t[32][33];
  int lx = threadIdx.x & 31, ly = threadIdx.x >> 5;
  const bf16* ip = OHT + (size_t)plane * NP;
  for (int i = 0; i < 32; i += 8)
    t[ly + i][lx] = bf2f(ip[(size_t)(th * 32 + ly + i) * 128 + tw * 32 + lx]);
  __syncthreads();
  float sc = HDR[scIdx];
  float* op = ACC + (size_t)plane * NP;
  for (int i = 0; i < 32; i += 8) {
    int h = tw * 32 + ly + i, w = th * 32 + lx;
    op[(size_t)h * 128 + w] += sc * t[lx][ly + i];
  }
}

// ---------------------------------------------------------------------------
// K9: partial Gram of y=BN(Y) applied at staging
// ---------------------------------------------------------------------------
__global__ __launch_bounds__(256) void k_gram(const bf16* __restrict__ Y,
                                              const float* __restrict__ SCALE,
                                              const float* __restrict__ SHIFT,
                                              float* __restrict__ GP) {
  int b = blockIdx.x >> 5, ch = blockIdx.x & 31;
  int tid = threadIdx.x;
  __shared__ float fs[64 * 129];
  int cg = tid >> 4, dg = tid & 15;
  float acc[4][4];
#pragma unroll
  for (int i = 0; i < 4; ++i)
#pragma unroll
    for (int jx = 0; jx < 4; ++jx) acc[i][jx] = 0.f;
  const bf16* yb = Y + (size_t)b * 64 * NP + ch * 512;
  for (int t = 0; t < 4; ++t) {
    __syncthreads();
    for (int idx = tid; idx < 8192; idx += 256) {
      int c = idx >> 7, j = idx & 127;
      float v = fmaf(bf2f(yb[(size_t)c * NP + t * 128 + j]), SCALE[c], SHIFT[c]);
      fs[c * 129 + j] = fmaxf(v, 0.f);
    }
    __syncthreads();
    for (int j = 0; j < 128; ++j) {
      float a[4], d[4];
#pragma unroll
      for (int i = 0; i < 4; ++i) a[i] = fs[(cg * 4 + i) * 129 + j];
#pragma unroll
      for (int i = 0; i < 4; ++i) d[i] = fs[(dg * 4 + i) * 129 + j];
#pragma unroll
      for (int i = 0; i < 4; ++i)
#pragma unroll
        for (int jx = 0; jx < 4; ++jx) acc[i][jx] = fmaf(a[i], d[jx], acc[i][jx]);
    }
  }
  float* gp = GP + ((size_t)b * 32 + ch) * 4096;
#pragma unroll
  for (int i = 0; i < 4; ++i)
#pragma unroll
    for (int jx = 0; jx < 4; ++jx)
      gp[(cg * 4 + i) * 64 + dg * 4 + jx] = acc[i][jx];
}

// K10: reduce Gram partials; row softmax of (max-E)
__global__ __launch_bounds__(256) void k_gram_reduce(const float* __restrict__ GP,
                                                     float* __restrict__ CATT) {
  int b = blockIdx.x, tid = threadIdx.x;
  __shared__ float Es[4096];
  for (int e = tid; e < 4096; e += 256) {
    float s = 0.f;
    for (int k = 0; k < 32; ++k) s += GP[((size_t)b * 32 + k) * 4096 + e];
    Es[e] = s;
  }
  __syncthreads();
  int wv = tid >> 6, ln = tid & 63;
  for (int r = wv; r < 64; r += 4) {
    float v = Es[r * 64 + ln];
    float mn = v;
    for (int off = 32; off; off >>= 1) mn = fminf(mn, __shfl_xor(mn, off, 64));
    float e = __expf(mn - v);
    float s = e;
    for (int off = 32; off; off >>= 1) s += __shfl_xor(s, off, 64);
    CATT[((size_t)b * 64 + r) * 64 + ln] = e / s;
  }
}

// ---------------------------------------------------------------------------
// K11: out = (2+pg)*x + pg2*y + ACC + cg*(catt@y). In-place fp32 on d_out.
// ---------------------------------------------------------------------------
__global__ __launch_bounds__(256) void k_final(
    const float* __restrict__ x, const bf16* __restrict__ Y,
    const float* __restrict__ SCALE, const float* __restrict__ SHIFT,
    const float* __restrict__ CATT, const float* __restrict__ HDR,
    float* __restrict__ OUT) {
  __shared__ float attS[64 * 65], Ys[64 * 65];
  int tid = threadIdx.x;
  int b = blockIdx.x >> 8, tile = blockIdx.x & 255;
  int n0 = tile * 64;
  for (int i = tid; i < 4096; i += 256)
    attS[(i >> 6) * 65 + (i & 63)] = CATT[(size_t)b * 4096 + i];
  for (int i = tid; i < 4096; i += 256) {
    int d = i >> 6, px = i & 63;
    float v = fmaf(bf2f(Y[(size_t)(b * 64 + d) * NP + n0 + px]), SCALE[d], SHIFT[d]);
    Ys[d * 65 + px] = fmaxf(v, 0.f);
  }
  __syncthreads();
  int cg = tid >> 4, pgx = tid & 15;
  int c0 = cg * 4, p0 = pgx * 4;
  float acc[4][4];
#pragma unroll
  for (int i = 0; i < 4; ++i)
#pragma unroll
    for (int j = 0; j < 4; ++j) acc[i][j] = 0.f;
  for (int d = 0; d < 64; ++d) {
    float a[4], yv[4];
#pragma unroll
    for (int i = 0; i < 4; ++i) a[i] = attS[(c0 + i) * 65 + d];
#pragma unroll
    for (int j = 0; j < 4; ++j) yv[j] = Ys[d * 65 + p0 + j];
#pragma unroll
    for (int i = 0; i < 4; ++i)
#pragma unroll
      for (int j = 0; j < 4; ++j) acc[i][j] = fmaf(a[i], yv[j], acc[i][j]);
  }
  float c2pg = HDR[3], fpg2 = HDR[4], fcg = HDR[5];
#pragma unroll
  for (int i = 0; i < 4; ++i) {
    size_t base = (size_t)(b * 64 + c0 + i) * NP + n0 + p0;
#pragma unroll
    for (int j = 0; j < 4; ++j) {
      float yv = Ys[(c0 + i) * 65 + p0 + j];
      OUT[base + j] =
          c2pg * x[base + j] + fpg2 * yv + OUT[base + j] + fcg * acc[i][j];
    }
  }
}

// ---------------------------------------------------------------------------
extern "C" void kernel_launch(void* const* d_in, const int* in_sizes, int n_in,
                              void* d_out, int out_size, void* d_ws, size_t ws_size,
                              hipStream_t stream) {
  const float* x = (const float*)d_in[0];
  const float* fbp = (const float*)d_in[1];

  // Workspace: 38,277,120 bytes total (proven extent).
  char* base = (char*)d_ws;
  float* HDR = (float*)base;
  float* SCALE = HDR + 16;
  float* SHIFT = SCALE + 64;
  char* p = base + 4096;
  bf16* Y = (bf16*)p;   p += 8388608;
  bf16* Q = (bf16*)p;   p += 1048576;
  bf16* K = (bf16*)p;   p += 1048576;
  bf16* QT = (bf16*)p;  p += 1048576;
  bf16* KT = (bf16*)p;  p += 1048576;
  bf16* V = (bf16*)p;   p += 8388608;
  bf16* VT = (bf16*)p;  p += 8388608;
  float* MW = (float*)p; p += 262144;   // joint M after combine
  float* LW = (float*)p; p += 262144;   // joint 1/L after combine
  bf16* OHT = (bf16*)p;  p += 8388608;  // out_h in [b][c][w][h] layout
  float* ACC = (float*)d_out;           // fp32, 16 MB
  float* PS = (float*)Q;     // stats partials (4 KB), Q unused until conv80
  float* GP = (float*)Q;     // Gram partials after module loop
  float* CATT = (float*)QT;  // reuses QT

  k_pool_conv<<<1024, 256, 0, stream>>>(fbp, (const float*)d_in[2],
                                        (const float*)d_in[3], Y);
  k_stats_p1<<<512, 256, 0, stream>>>(Y, PS);
  k_stats_p2<<<1, 64, 0, stream>>>(PS, (const float*)d_in[4],
                                   (const float*)d_in[5], SCALE, SHIFT,
                                   (const float*)d_in[12], (const float*)d_in[19],
                                   (const float*)d_in[20], (const float*)d_in[21],
                                   (const float*)d_in[22], HDR);

  for (int m = 0; m < 2; ++m) {
    const float *qw, *qb, *kw, *kb, *vw, *vb;
    if (m == 0) {
      qw = (const float*)d_in[6]; qb = (const float*)d_in[7];
      kw = (const float*)d_in[8]; kb = (const float*)d_in[9];
      vw = (const float*)d_in[10]; vb = (const float*)d_in[11];
    } else {
      qw = (const float*)d_in[13]; qb = (const float*)d_in[14];
      kw = (const float*)d_in[15]; kb = (const float*)d_in[16];
      vw = (const float*)d_in[17]; vb = (const float*)d_in[18];
    }
    if (m == 0)
      k_conv80<false><<<512, 256, 0, stream>>>(x, SCALE, SHIFT, qw, qb, kw, kb,
                                               vw, vb, Q, K, V);
    else
      k_conv80<true><<<512, 256, 0, stream>>>(Y, SCALE, SHIFT, qw, qb, kw, kb,
                                              vw, vb, Q, K, V);
    // Q,K contiguous and QT,KT contiguous: one call transposes both (64 planes)
    k_transpose<<<1024, 256, 0, stream>>>((const u16*)Q, (u16*)QT);
    k_transpose<<<4096, 256, 0, stream>>>((const u16*)V, (u16*)VT);
    k_ew_stats<<<512, 256, 0, stream>>>(Q, K, MW, LW);
    k_eh_combine<<<512, 256, 0, stream>>>(QT, KT, MW, LW);
    // merged out_w + out_h: 1024 blocks (even=w, odd=h) -> 4 blocks/CU
    k_av<<<1024, 128, 0, stream>>>(Q, K, V, QT, KT, VT, MW, LW, ACC, OHT,
                                   HDR, 1 + m, m);
    k_merge<<<4096, 256, 0, stream>>>(OHT, ACC, HDR, 1 + m);
  }

  k_gram<<<128, 256, 0, stream>>>(Y, SCALE, SHIFT, GP);
  k_gram_reduce<<<4, 256, 0, stream>>>(GP, CATT);
  k_final<<<1024, 256, 0, stream>>>(x, Y, SCALE, SHIFT, CATT, HDR,
                                    (float*)d_out);
}

// Round 3
// 429.120 us; speedup vs baseline: 1.3266x; 1.1068x over previous
//
#include <hip/hip_runtime.h>
#include <hip/hip_bf16.h>

#define NP 16384   // H*W
#define NB 4

typedef __hip_bfloat16 bf16;
typedef unsigned short u16;
typedef unsigned short us8 __attribute__((ext_vector_type(8)));
typedef short ss8 __attribute__((ext_vector_type(8)));
typedef float f32x4 __attribute__((ext_vector_type(4)));
__device__ __forceinline__ float bf2f(const bf16 v) { return __bfloat162float(v); }
__device__ __forceinline__ bf16 f2bf(float v) { return __float2bfloat16(v); }
__device__ __forceinline__ float bfu(u16 h) {
  return __uint_as_float(((unsigned)h) << 16);
}
__device__ __forceinline__ u16 fbu(float v) {
  bf16 b = f2bf(v);
  return *(u16*)&b;
}

// Inputs/outputs fp32 (reference dtype). Internal tensors bf16, math fp32.

// ---------------------------------------------------------------------------
// K1: maxpool2x2(fb fp32) -> conv1x1+bias -> Y raw (pre-BN, bf16). 64x64 tile.
// wS stride 65 (bank-conflict-free weight reads); float2 pool loads.
// ---------------------------------------------------------------------------
__global__ __launch_bounds__(256) void k_pool_conv(
    const float* __restrict__ fb, const float* __restrict__ wconv,
    const float* __restrict__ bconv, bf16* __restrict__ Y) {
  __shared__ float wS[64 * 65], bS[64], Xs[4096];
  int tid = threadIdx.x;
  int b = blockIdx.x >> 8, tile = blockIdx.x & 255;
  int n0 = tile * 64;
  for (int i = tid; i < 4096; i += 256) wS[(i >> 6) * 65 + (i & 63)] = wconv[i];
  if (tid < 64) bS[tid] = bconv[tid];
  for (int i = tid; i < 4096; i += 256) {
    int c = i >> 6, px = i & 63;
    int n = n0 + px, h = n >> 7, w = n & 127;
    size_t fbase = ((size_t)((b * 64 + c) * 256 + 2 * h)) * 256 + 2 * w;
    float2 v01 = *(const float2*)(fb + fbase);
    float2 v23 = *(const float2*)(fb + fbase + 256);
    Xs[i] = fmaxf(fmaxf(v01.x, v01.y), fmaxf(v23.x, v23.y));
  }
  __syncthreads();
  int ty = tid >> 4, tx = tid & 15;
  float acc[4][4];
#pragma unroll
  for (int i = 0; i < 4; ++i) {
    float bv = bS[ty + 16 * i];
#pragma unroll
    for (int j = 0; j < 4; ++j) acc[i][j] = bv;
  }
  for (int c = 0; c < 64; ++c) {
    float xv[4], wv[4];
#pragma unroll
    for (int j = 0; j < 4; ++j) xv[j] = Xs[c * 64 + tx * 4 + j];
#pragma unroll
    for (int i = 0; i < 4; ++i) wv[i] = wS[(ty + 16 * i) * 65 + c];
#pragma unroll
    for (int i = 0; i < 4; ++i)
#pragma unroll
      for (int j = 0; j < 4; ++j) acc[i][j] = fmaf(wv[i], xv[j], acc[i][j]);
  }
#pragma unroll
  for (int i = 0; i < 4; ++i) {
    int ch = ty + 16 * i;
    bf16* yb = Y + (size_t)(b * 64 + ch) * NP + n0 + tx * 4;
#pragma unroll
    for (int j = 0; j < 4; ++j) yb[j] = f2bf(acc[i][j]);
  }
}

// ---------------------------------------------------------------------------
// K2a: stats stage 1. 512 blocks; each reduces 8192 contiguous bf16 of one
// (channel, batch, half) slab with ushort8 loads. PS[blk]=sum, PS[512+blk]=sq.
// ---------------------------------------------------------------------------
__global__ __launch_bounds__(256) void k_stats_p1(const bf16* __restrict__ Y,
                                                  float* __restrict__ PS) {
  int blk = blockIdx.x, tid = threadIdx.x;
  int o = blk >> 3, slab = blk & 7;
  int b = slab >> 1, half = slab & 1;
  const us8* vp =
      (const us8*)(Y + ((size_t)(b * 64 + o)) * NP + half * 8192);
  float s = 0.f, ss = 0.f;
#pragma unroll
  for (int it = 0; it < 4; ++it) {
    us8 v = vp[tid + 256 * it];
#pragma unroll
    for (int e = 0; e < 8; ++e) {
      float f = bfu(v[e]);
      s += f;
      ss = fmaf(f, f, ss);
    }
  }
  for (int off = 32; off > 0; off >>= 1) {
    s += __shfl_down(s, off, 64);
    ss += __shfl_down(ss, off, 64);
  }
  __shared__ float sh[8];
  int wv = tid >> 6, ln = tid & 63;
  if (ln == 0) { sh[wv] = s; sh[4 + wv] = ss; }
  __syncthreads();
  if (tid == 0) {
    PS[blk] = sh[0] + sh[1] + sh[2] + sh[3];
    PS[512 + blk] = sh[4] + sh[5] + sh[6] + sh[7];
  }
}

// K2b: stats stage 2 + BN scale/shift + scalar header (fused)
__global__ __launch_bounds__(64) void k_stats_p2(
    const float* __restrict__ PS, const float* __restrict__ bng,
    const float* __restrict__ bnb, float* __restrict__ SCALE,
    float* __restrict__ SHIFT, const float* xg, const float* fg,
    const float* pg, const float* pg2, const float* cg,
    float* __restrict__ HDR) {
  int o = threadIdx.x;
  float s = 0.f, ss = 0.f;
#pragma unroll
  for (int k = 0; k < 8; ++k) {
    s += PS[o * 8 + k];
    ss += PS[512 + o * 8 + k];
  }
  const float inv = 1.0f / (NB * NP);
  float mu = s * inv;
  float var = ss * inv - mu * mu;
  float r = rsqrtf(var + 1e-5f);
  float sc = r * bng[o];
  SCALE[o] = sc;
  SHIFT[o] = bnb[o] - mu * sc;
  if (o == 0) {
    float vpg = pg[0];
    HDR[1] = vpg * xg[0];
    HDR[2] = pg2[0] * fg[0];
    HDR[3] = 2.0f + vpg;
    HDR[4] = pg2[0];
    HDR[5] = cg[0];
  }
}

// ---------------------------------------------------------------------------
// K4: fused q|k|v conv1x1: 80 out-ch x 128 px, 5x8 thread tile.
// Xs staged as u16 bf16 (LDS 37 KB -> 4 blocks/CU). wS stride 65.
// ---------------------------------------------------------------------------
template <bool BN>
__global__ __launch_bounds__(256) void k_conv80(
    const void* __restrict__ inp, const float* __restrict__ SCALE,
    const float* __restrict__ SHIFT,
    const float* __restrict__ qw, const float* __restrict__ qb,
    const float* __restrict__ kw, const float* __restrict__ kb,
    const float* __restrict__ vw, const float* __restrict__ vb,
    bf16* __restrict__ Q, bf16* __restrict__ K, bf16* __restrict__ V) {
  __shared__ float wS[80 * 65], bS[80];
  __shared__ u16 Xs[8192];
  int tid = threadIdx.x;
  int b = blockIdx.x >> 7, tile = blockIdx.x & 127;
  int n0 = tile * 128;
  for (int i = tid; i < 512; i += 256) {
    wS[(i >> 6) * 65 + (i & 63)] = qw[i];
    wS[(8 + (i >> 6)) * 65 + (i & 63)] = kw[i];
  }
  for (int i = tid; i < 4096; i += 256)
    wS[(16 + (i >> 6)) * 65 + (i & 63)] = vw[i];
  if (tid < 8) { bS[tid] = qb[tid]; bS[8 + tid] = kb[tid]; }
  if (tid < 64) bS[16 + tid] = vb[tid];
  for (int i = tid; i < 8192; i += 256) {
    int c = i >> 7, px = i & 127;
    size_t idx = (size_t)(b * 64 + c) * NP + n0 + px;
    float v;
    if (BN) {
      v = bf2f(((const bf16*)inp)[idx]);
      v = fmaf(v, SCALE[c], SHIFT[c]);
      v = fmaxf(v, 0.f);
    } else {
      v = ((const float*)inp)[idx];
    }
    Xs[i] = fbu(v);
  }
  __syncthreads();
  int ty = tid >> 4, tx = tid & 15;
  float acc[5][8];
#pragma unroll
  for (int i = 0; i < 5; ++i) {
    float bv = bS[ty + 16 * i];
#pragma unroll
    for (int j = 0; j < 8; ++j) acc[i][j] = bv;
  }
  for (int c = 0; c < 64; ++c) {
    float xv[8], wv[5];
#pragma unroll
    for (int j = 0; j < 8; ++j) xv[j] = bfu(Xs[c * 128 + tx + 16 * j]);
#pragma unroll
    for (int i = 0; i < 5; ++i) wv[i] = wS[(ty + 16 * i) * 65 + c];
#pragma unroll
    for (int i = 0; i < 5; ++i)
#pragma unroll
      for (int j = 0; j < 8; ++j) acc[i][j] = fmaf(wv[i], xv[j], acc[i][j]);
  }
#pragma unroll
  for (int i = 0; i < 5; ++i) {
    int ch = ty + 16 * i;
    bf16* dst;
    size_t base;
    if (ch < 8) { dst = Q; base = (size_t)(b * 8 + ch) * NP; }
    else if (ch < 16) { dst = K; base = (size_t)(b * 8 + ch - 8) * NP; }
    else { dst = V; base = (size_t)(b * 64 + ch - 16) * NP; }
#pragma unroll
    for (int j = 0; j < 8; ++j) dst[base + n0 + tx + 16 * j] = f2bf(acc[i][j]);
  }
}

// ---------------------------------------------------------------------------
// K5: 128x128 bf16 plane transpose (also covers Q+K in one call: contiguous)
// ---------------------------------------------------------------------------
__global__ __launch_bounds__(256) void k_transpose(const u16* __restrict__ in,
                                                   u16* __restrict__ out) {
  int tileId = blockIdx.x & 15;
  int plane = blockIdx.x >> 4;
  int th = tileId >> 2, tw = tileId & 3;
  __shared__ u16 t[32][33];
  int lx = threadIdx.x & 31, ly = threadIdx.x >> 5;
  const u16* ip = in + (size_t)plane * NP;
  for (int i = 0; i < 32; i += 8)
    t[ly + i][lx] = ip[(size_t)(th * 32 + ly + i) * 128 + tw * 32 + lx];
  __syncthreads();
  u16* op = out + (size_t)plane * NP;
  for (int i = 0; i < 32; i += 8)
    op[(size_t)(tw * 32 + ly + i) * 128 + th * 32 + lx] = t[lx][ly + i];
}

// ---------------------------------------------------------------------------
// K6a: e_w per-row max/sumexp -> raw stats into MW/LW
// ---------------------------------------------------------------------------
__global__ __launch_bounds__(256) void k_ew_stats(
    const bf16* __restrict__ Q, const bf16* __restrict__ K,
    float* __restrict__ MW, float* __restrict__ LW) {
  int b = blockIdx.x >> 7, h = blockIdx.x & 127;
  __shared__ float qs[1024], ks[1024], red[256];
  int tid = threadIdx.x;
  for (int i = tid; i < 1024; i += 256) {
    int c = i >> 7, j = i & 127;
    size_t idx = (size_t)(b * 8 + c) * NP + (size_t)h * 128 + j;
    qs[i] = bf2f(Q[idx]);
    ks[i] = bf2f(K[idx]);
  }
  __syncthreads();
  int w = tid & 127, half = tid >> 7;
  float qr[8];
#pragma unroll
  for (int c = 0; c < 8; ++c) qr[c] = qs[c * 128 + w];
  float m = -3.0e38f;
  for (int v0 = 0; v0 < 64; ++v0) {
    int v = half * 64 + v0;
    float s = 0.f;
#pragma unroll
    for (int c = 0; c < 8; ++c) s = fmaf(qr[c], ks[c * 128 + v], s);
    m = fmaxf(m, s);
  }
  red[tid] = m;
  __syncthreads();
  float mj = fmaxf(red[w], red[128 + w]);
  __syncthreads();
  float l = 0.f;
  for (int v0 = 0; v0 < 64; ++v0) {
    int v = half * 64 + v0;
    float s = 0.f;
#pragma unroll
    for (int c = 0; c < 8; ++c) s = fmaf(qr[c], ks[c * 128 + v], s);
    l += __expf(s - mj);
  }
  red[tid] = l;
  __syncthreads();
  if (half == 0) {
    size_t o = (size_t)b * NP + (size_t)h * 128 + w;
    MW[o] = mj;
    LW[o] = red[w] + red[128 + w];
  }
}

// ---------------------------------------------------------------------------
// K6b: e_h per-row stats (diag masked) + in-place combine -> MW=M, LW=1/L
// ---------------------------------------------------------------------------
__global__ __launch_bounds__(256) void k_eh_combine(
    const bf16* __restrict__ QT, const bf16* __restrict__ KT,
    float* __restrict__ MW, float* __restrict__ LW) {
  int b = blockIdx.x >> 7, w = blockIdx.x & 127;
  __shared__ float qs[1024], ks[1024], red[256];
  int tid = threadIdx.x;
  for (int i = tid; i < 1024; i += 256) {
    int c = i >> 7, j = i & 127;
    size_t idx = (size_t)(b * 8 + c) * NP + (size_t)w * 128 + j;
    qs[i] = bf2f(QT[idx]);
    ks[i] = bf2f(KT[idx]);
  }
  __syncthreads();
  int h = tid & 127, half = tid >> 7;
  float qr[8];
#pragma unroll
  for (int c = 0; c < 8; ++c) qr[c] = qs[c * 128 + h];
  float m = -3.0e38f;
  for (int g0 = 0; g0 < 64; ++g0) {
    int g = half * 64 + g0;
    float s = 0.f;
#pragma unroll
    for (int c = 0; c < 8; ++c) s = fmaf(qr[c], ks[c * 128 + g], s);
    if (g == h) s = -1.0e30f;
    m = fmaxf(m, s);
  }
  red[tid] = m;
  __syncthreads();
  float mj = fmaxf(red[h], red[128 + h]);
  __syncthreads();
  float l = 0.f;
  for (int g0 = 0; g0 < 64; ++g0) {
    int g = half * 64 + g0;
    float s = 0.f;
#pragma unroll
    for (int c = 0; c < 8; ++c) s = fmaf(qr[c], ks[c * 128 + g], s);
    l += (g == h) ? 0.f : __expf(s - mj);
  }
  red[tid] = l;
  __syncthreads();
  if (half == 0) {
    size_t o = (size_t)b * NP + (size_t)h * 128 + w;
    float lh = red[h] + red[128 + h];
    float mw = MW[o], lw = LW[o];
    float mm = fmaxf(mw, mj);
    float ll = lw * __expf(mw - mm) + lh * __expf(mj - mm);
    MW[o] = mm;
    LW[o] = 1.0f / ll;
  }
}

// ---------------------------------------------------------------------------
// K7: merged out_w + out_h on MFMA (mfma_f32_16x16x32_bf16).
// 2048 blocks = (b,h) x mode x i-half; 128 thr; LDS 22.5 KB -> 7 blocks/CU.
// Scores computed per-lane directly in A-fragment layout (row i = lane&15,
// k-slice j = (lane>>4)*8+e), converted to bf16; As LDS + per-chunk barriers
// eliminated. B-fragments are ds_read_b128 from Vs[c][j] (pad 136 u16).
// D layout: col(lane&15)=channel, row((lane>>4)*4+r)=pixel -> 4-consecutive
// pixel stores per lane (same coalescing as the VALU version).
// ---------------------------------------------------------------------------
__global__ __launch_bounds__(128, 4) void k_av(
    const bf16* __restrict__ Q, const bf16* __restrict__ K,
    const bf16* __restrict__ V, const bf16* __restrict__ QT,
    const bf16* __restrict__ KT, const bf16* __restrict__ VT,
    const float* __restrict__ M, const float* __restrict__ LI,
    float* __restrict__ ACC, bf16* __restrict__ OHT,
    const float* __restrict__ HDR, int scIdx, int accum) {
  int g2 = blockIdx.x;
  int mode = g2 & 1;                 // 0: out_w, 1: out_h
  int halfsel = (g2 >> 1) & 1;       // which pair of 32-pixel chunks
  int bid = g2 >> 2;
  int b = bid >> 7, h = bid & 127;
  const bf16* Qp = mode ? QT : Q;
  const bf16* Kp = mode ? KT : K;
  const bf16* Vp = mode ? VT : V;
  __shared__ __align__(16) u16 qT[128 * 8];    // [p(j)][c]
  __shared__ __align__(16) u16 kT[128 * 8];    // [p(j)][c]
  __shared__ __align__(16) u16 Vs[64 * 136];   // [c][j], pad 136
  __shared__ float Ml[128], Li[128];
  int tid = threadIdx.x;
  {  // q/k rows: 1024 u16 each = one us8 load per thread, scatter to [p][c]
    int c = tid >> 4, vj = tid & 15;
    const us8* qp = (const us8*)(Qp + ((size_t)(b * 8 + c)) * NP + (size_t)h * 128);
    const us8* kp = (const us8*)(Kp + ((size_t)(b * 8 + c)) * NP + (size_t)h * 128);
    us8 qv = qp[vj], kv = kp[vj];
#pragma unroll
    for (int e = 0; e < 8; ++e) {
      int j = vj * 8 + e;
      int p = ((j & 7) << 4) | (j >> 3);
      qT[p * 8 + c] = qv[e];
      kT[p * 8 + c] = kv[e];
    }
  }
  for (int i2 = tid; i2 < 1024; i2 += 128) {  // V: 8192 u16, b128 writes
    int c = i2 >> 4, vj = i2 & 15;
    const us8* vp =
        (const us8*)(Vp + ((size_t)(b * 64 + c)) * NP + (size_t)h * 128);
    us8 vv = vp[vj];
    *(us8*)&Vs[c * 136 + vj * 8] = vv;
  }
  if (mode == 0) {
    Ml[tid] = M[(size_t)b * NP + (size_t)h * 128 + tid];
    Li[tid] = LI[(size_t)b * NP + (size_t)h * 128 + tid];
  } else {
    Ml[tid] = M[(size_t)b * NP + (size_t)tid * 128 + h];
    Li[tid] = LI[(size_t)b * NP + (size_t)tid * 128 + h];
  }
  __syncthreads();
  float sc = HDR[scIdx];
  int lane = tid & 63, w = tid >> 6;
  int il = lane & 15, gq = lane >> 4;
  float* accBase = ACC + (size_t)(b * 64) * NP + (size_t)h * 128;
  bf16* outBase = OHT + (size_t)(b * 64) * NP + (size_t)h * 128;
#pragma unroll
  for (int cc2 = 0; cc2 < 2; ++cc2) {
    int chunk = halfsel * 2 + cc2;
    int ib = chunk * 32 + w * 16;
    int i = ib + il;                 // this lane's A-row
    float mv = Ml[i], li = Li[i];
    int pi = ((i & 7) << 4) | (i >> 3);
    us8 qv = *(const us8*)&qT[pi * 8];
    float qr[8];
#pragma unroll
    for (int c = 0; c < 8; ++c) qr[c] = bfu(qv[c]);
    ss8 afr[4];
#pragma unroll
    for (int ks = 0; ks < 4; ++ks) {
      ss8 af;
#pragma unroll
      for (int e = 0; e < 8; ++e) {
        int j = ks * 32 + gq * 8 + e;
        int pj = ((j & 7) << 4) | (j >> 3);
        us8 kv = *(const us8*)&kT[pj * 8];
        float s = 0.f;
#pragma unroll
        for (int c = 0; c < 8; ++c) s = fmaf(qr[c], bfu(kv[c]), s);
        float ev = __expf(s - mv) * li;
        if (mode && j == i) ev = 0.f;
        af[e] = (short)fbu(ev);
      }
      afr[ks] = af;
    }
#pragma unroll
    for (int ct = 0; ct < 4; ++ct) {
      f32x4 acc = {0.f, 0.f, 0.f, 0.f};
#pragma unroll
      for (int ks = 0; ks < 4; ++ks) {
        ss8 bv = *(const ss8*)&Vs[(ct * 16 + il) * 136 + ks * 32 + gq * 8];
        acc = __builtin_amdgcn_mfma_f32_16x16x32_bf16(afr[ks], bv, acc, 0, 0, 0);
      }
      int cch = ct * 16 + il;        // D col = channel
      int i0 = ib + gq * 4;          // D rows = 4 consecutive pixels
      if (mode == 0) {
#pragma unroll
        for (int r = 0; r < 4; ++r) {
          size_t o = (size_t)cch * NP + (size_t)(i0 + r);
          float val = sc * acc[r];
          accBase[o] = (accum ? accBase[o] : 0.f) + val;
        }
      } else {
#pragma unroll
        for (int r = 0; r < 4; ++r)
          outBase[(size_t)cch * NP + (size_t)(i0 + r)] = f2bf(acc[r]);
      }
    }
  }
}

// ---------------------------------------------------------------------------
// K8b: transpose-add: ACC[b][c][h][w] += sc * OHT[b][c][w][h]. 32x32 LDS.
// ---------------------------------------------------------------------------
__global__ __launch_bounds__(256) void k_merge(const bf16* __restrict__ OHT,
                                               float* __restrict__ ACC,
                                               const float* __restrict__ HDR,
                                               int scIdx) {
  int tileId = blockIdx.x & 15;
  int plane = blockIdx.x >> 4;
  int th = tileId >> 2, tw = tileId & 3;
  __shared__ float t[32][33];
  int lx = threadIdx.x & 31, ly = threadIdx.x >> 5;
  const bf16* ip = OHT + (size_t)plane * NP;
  for (int i = 0; i < 32; i += 8)
    t[ly + i][lx] = bf2f(ip[(size_t)(th * 32 + ly + i) * 128 + tw * 32 + lx]);
  __syncthreads();
  float sc = HDR[scIdx];
  float* op = ACC + (size_t)plane * NP;
  for (int i = 0; i < 32; i += 8) {
    int h = tw * 32 + ly + i, w = th * 32 + lx;
    op[(size_t)h * 128 + w] += sc * t[lx][ly + i];
  }
}

// ---------------------------------------------------------------------------
// K9: partial Gram of y=BN(Y) applied at staging
// ---------------------------------------------------------------------------
__global__ __launch_bounds__(256) void k_gram(const bf16* __restrict__ Y,
                                              const float* __restrict__ SCALE,
                                              const float* __restrict__ SHIFT,
                                              float* __restrict__ GP) {
  int b = blockIdx.x >> 5, ch = blockIdx.x & 31;
  int tid = threadIdx.x;
  __shared__ float fs[64 * 129];
  int cg = tid >> 4, dg = tid & 15;
  float acc[4][4];
#pragma unroll
  for (int i = 0; i < 4; ++i)
#pragma unroll
    for (int jx = 0; jx < 4; ++jx) acc[i][jx] = 0.f;
  const bf16* yb = Y + (size_t)b * 64 * NP + ch * 512;
  for (int t = 0; t < 4; ++t) {
    __syncthreads();
    for (int idx = tid; idx < 8192; idx += 256) {
      int c = idx >> 7, j = idx & 127;
      float v = fmaf(bf2f(yb[(size_t)c * NP + t * 128 + j]), SCALE[c], SHIFT[c]);
      fs[c * 129 + j] = fmaxf(v, 0.f);
    }
    __syncthreads();
    for (int j = 0; j < 128; ++j) {
      float a[4], d[4];
#pragma unroll
      for (int i = 0; i < 4; ++i) a[i] = fs[(cg * 4 + i) * 129 + j];
#pragma unroll
      for (int i = 0; i < 4; ++i) d[i] = fs[(dg * 4 + i) * 129 + j];
#pragma unroll
      for (int i = 0; i < 4; ++i)
#pragma unroll
        for (int jx = 0; jx < 4; ++jx) acc[i][jx] = fmaf(a[i], d[jx], acc[i][jx]);
    }
  }
  float* gp = GP + ((size_t)b * 32 + ch) * 4096;
#pragma unroll
  for (int i = 0; i < 4; ++i)
#pragma unroll
    for (int jx = 0; jx < 4; ++jx)
      gp[(cg * 4 + i) * 64 + dg * 4 + jx] = acc[i][jx];
}

// K10: reduce Gram partials; row softmax of (max-E)
__global__ __launch_bounds__(256) void k_gram_reduce(const float* __restrict__ GP,
                                                     float* __restrict__ CATT) {
  int b = blockIdx.x, tid = threadIdx.x;
  __shared__ float Es[4096];
  for (int e = tid; e < 4096; e += 256) {
    float s = 0.f;
    for (int k = 0; k < 32; ++k) s += GP[((size_t)b * 32 + k) * 4096 + e];
    Es[e] = s;
  }
  __syncthreads();
  int wv = tid >> 6, ln = tid & 63;
  for (int r = wv; r < 64; r += 4) {
    float v = Es[r * 64 + ln];
    float mn = v;
    for (int off = 32; off; off >>= 1) mn = fminf(mn, __shfl_xor(mn, off, 64));
    float e = __expf(mn - v);
    float s = e;
    for (int off = 32; off; off >>= 1) s += __shfl_xor(s, off, 64);
    CATT[((size_t)b * 64 + r) * 64 + ln] = e / s;
  }
}

// ---------------------------------------------------------------------------
// K11: out = (2+pg)*x + pg2*y + ACC + cg*(catt@y). In-place fp32 on d_out.
// ---------------------------------------------------------------------------
__global__ __launch_bounds__(256) void k_final(
    const float* __restrict__ x, const bf16* __restrict__ Y,
    const float* __restrict__ SCALE, const float* __restrict__ SHIFT,
    const float* __restrict__ CATT, const float* __restrict__ HDR,
    float* __restrict__ OUT) {
  __shared__ float attS[64 * 65], Ys[64 * 65];
  int tid = threadIdx.x;
  int b = blockIdx.x >> 8, tile = blockIdx.x & 255;
  int n0 = tile * 64;
  for (int i = tid; i < 4096; i += 256)
    attS[(i >> 6) * 65 + (i & 63)] = CATT[(size_t)b * 4096 + i];
  for (int i = tid; i < 4096; i += 256) {
    int d = i >> 6, px = i & 63;
    float v = fmaf(bf2f(Y[(size_t)(b * 64 + d) * NP + n0 + px]), SCALE[d], SHIFT[d]);
    Ys[d * 65 + px] = fmaxf(v, 0.f);
  }
  __syncthreads();
  int cg = tid >> 4, pgx = tid & 15;
  int c0 = cg * 4, p0 = pgx * 4;
  float acc[4][4];
#pragma unroll
  for (int i = 0; i < 4; ++i)
#pragma unroll
    for (int j = 0; j < 4; ++j) acc[i][j] = 0.f;
  for (int d = 0; d < 64; ++d) {
    float a[4], yv[4];
#pragma unroll
    for (int i = 0; i < 4; ++i) a[i] = attS[(c0 + i) * 65 + d];
#pragma unroll
    for (int j = 0; j < 4; ++j) yv[j] = Ys[d * 65 + p0 + j];
#pragma unroll
    for (int i = 0; i < 4; ++i)
#pragma unroll
      for (int j = 0; j < 4; ++j) acc[i][j] = fmaf(a[i], yv[j], acc[i][j]);
  }
  float c2pg = HDR[3], fpg2 = HDR[4], fcg = HDR[5];
#pragma unroll
  for (int i = 0; i < 4; ++i) {
    size_t base = (size_t)(b * 64 + c0 + i) * NP + n0 + p0;
#pragma unroll
    for (int j = 0; j < 4; ++j) {
      float yv = Ys[(c0 + i) * 65 + p0 + j];
      OUT[base + j] =
          c2pg * x[base + j] + fpg2 * yv + OUT[base + j] + fcg * acc[i][j];
    }
  }
}

// ---------------------------------------------------------------------------
extern "C" void kernel_launch(void* const* d_in, const int* in_sizes, int n_in,
                              void* d_out, int out_size, void* d_ws, size_t ws_size,
                              hipStream_t stream) {
  const float* x = (const float*)d_in[0];
  const float* fbp = (const float*)d_in[1];

  // Workspace: 38,277,120 bytes total (proven extent).
  char* base = (char*)d_ws;
  float* HDR = (float*)base;
  float* SCALE = HDR + 16;
  float* SHIFT = SCALE + 64;
  char* p = base + 4096;
  bf16* Y = (bf16*)p;   p += 8388608;
  bf16* Q = (bf16*)p;   p += 1048576;
  bf16* K = (bf16*)p;   p += 1048576;
  bf16* QT = (bf16*)p;  p += 1048576;
  bf16* KT = (bf16*)p;  p += 1048576;
  bf16* V = (bf16*)p;   p += 8388608;
  bf16* VT = (bf16*)p;  p += 8388608;
  float* MW = (float*)p; p += 262144;   // joint M after combine
  float* LW = (float*)p; p += 262144;   // joint 1/L after combine
  bf16* OHT = (bf16*)p;  p += 8388608;  // out_h in [b][c][w][h] layout
  float* ACC = (float*)d_out;           // fp32, 16 MB
  float* PS = (float*)Q;     // stats partials (4 KB), Q unused until conv80
  float* GP = (float*)Q;     // Gram partials after module loop
  float* CATT = (float*)QT;  // reuses QT

  k_pool_conv<<<1024, 256, 0, stream>>>(fbp, (const float*)d_in[2],
                                        (const float*)d_in[3], Y);
  k_stats_p1<<<512, 256, 0, stream>>>(Y, PS);
  k_stats_p2<<<1, 64, 0, stream>>>(PS, (const float*)d_in[4],
                                   (const float*)d_in[5], SCALE, SHIFT,
                                   (const float*)d_in[12], (const float*)d_in[19],
                                   (const float*)d_in[20], (const float*)d_in[21],
                                   (const float*)d_in[22], HDR);

  for (int m = 0; m < 2; ++m) {
    const float *qw, *qb, *kw, *kb, *vw, *vb;
    if (m == 0) {
      qw = (const float*)d_in[6]; qb = (const float*)d_in[7];
      kw = (const float*)d_in[8]; kb = (const float*)d_in[9];
      vw = (const float*)d_in[10]; vb = (const float*)d_in[11];
    } else {
      qw = (const float*)d_in[13]; qb = (const float*)d_in[14];
      kw = (const float*)d_in[15]; kb = (const float*)d_in[16];
      vw = (const float*)d_in[17]; vb = (const float*)d_in[18];
    }
    if (m == 0)
      k_conv80<false><<<512, 256, 0, stream>>>(x, SCALE, SHIFT, qw, qb, kw, kb,
                                               vw, vb, Q, K, V);
    else
      k_conv80<true><<<512, 256, 0, stream>>>(Y, SCALE, SHIFT, qw, qb, kw, kb,
                                              vw, vb, Q, K, V);
    // Q,K contiguous and QT,KT contiguous: one call transposes both (64 planes)
    k_transpose<<<1024, 256, 0, stream>>>((const u16*)Q, (u16*)QT);
    k_transpose<<<4096, 256, 0, stream>>>((const u16*)V, (u16*)VT);
    k_ew_stats<<<512, 256, 0, stream>>>(Q, K, MW, LW);
    k_eh_combine<<<512, 256, 0, stream>>>(QT, KT, MW, LW);
    // merged out_w + out_h on MFMA: 2048 blocks (mode x i-half split)
    k_av<<<2048, 128, 0, stream>>>(Q, K, V, QT, KT, VT, MW, LW, ACC, OHT,
                                   HDR, 1 + m, m);
    k_merge<<<4096, 256, 0, stream>>>(OHT, ACC, HDR, 1 + m);
  }

  k_gram<<<128, 256, 0, stream>>>(Y, SCALE, SHIFT, GP);
  k_gram_reduce<<<4, 256, 0, stream>>>(GP, CATT);
  k_final<<<1024, 256, 0, stream>>>(x, Y, SCALE, SHIFT, CATT, HDR,
                                    (float*)d_out);
}

// Round 4
// 393.244 us; speedup vs baseline: 1.4476x; 1.0912x over previous
//
#include <hip/hip_runtime.h>
#include <hip/hip_bf16.h>

#define NP 16384   // H*W
#define NB 4

typedef __hip_bfloat16 bf16;
typedef unsigned short u16;
typedef unsigned short us8 __attribute__((ext_vector_type(8)));
typedef short ss8 __attribute__((ext_vector_type(8)));
typedef float f32x4 __attribute__((ext_vector_type(4)));
__device__ __forceinline__ float bf2f(const bf16 v) { return __bfloat162float(v); }
__device__ __forceinline__ bf16 f2bf(float v) { return __float2bfloat16(v); }
__device__ __forceinline__ float bfu(u16 h) {
  return __uint_as_float(((unsigned)h) << 16);
}
__device__ __forceinline__ u16 fbu(float v) {
  bf16 b = f2bf(v);
  return *(u16*)&b;
}

// Inputs/outputs fp32 (reference dtype). Internal tensors bf16, math fp32.

// ---------------------------------------------------------------------------
// K1: maxpool2x2(fb fp32) -> conv1x1+bias -> Y raw (pre-BN, bf16). 64x64 tile.
// ---------------------------------------------------------------------------
__global__ __launch_bounds__(256) void k_pool_conv(
    const float* __restrict__ fb, const float* __restrict__ wconv,
    const float* __restrict__ bconv, bf16* __restrict__ Y) {
  __shared__ float wS[64 * 65], bS[64], Xs[4096];
  int tid = threadIdx.x;
  int b = blockIdx.x >> 8, tile = blockIdx.x & 255;
  int n0 = tile * 64;
  for (int i = tid; i < 4096; i += 256) wS[(i >> 6) * 65 + (i & 63)] = wconv[i];
  if (tid < 64) bS[tid] = bconv[tid];
  for (int i = tid; i < 4096; i += 256) {
    int c = i >> 6, px = i & 63;
    int n = n0 + px, h = n >> 7, w = n & 127;
    size_t fbase = ((size_t)((b * 64 + c) * 256 + 2 * h)) * 256 + 2 * w;
    float2 v01 = *(const float2*)(fb + fbase);
    float2 v23 = *(const float2*)(fb + fbase + 256);
    Xs[i] = fmaxf(fmaxf(v01.x, v01.y), fmaxf(v23.x, v23.y));
  }
  __syncthreads();
  int ty = tid >> 4, tx = tid & 15;
  float acc[4][4];
#pragma unroll
  for (int i = 0; i < 4; ++i) {
    float bv = bS[ty + 16 * i];
#pragma unroll
    for (int j = 0; j < 4; ++j) acc[i][j] = bv;
  }
  for (int c = 0; c < 64; ++c) {
    float xv[4], wv[4];
#pragma unroll
    for (int j = 0; j < 4; ++j) xv[j] = Xs[c * 64 + tx * 4 + j];
#pragma unroll
    for (int i = 0; i < 4; ++i) wv[i] = wS[(ty + 16 * i) * 65 + c];
#pragma unroll
    for (int i = 0; i < 4; ++i)
#pragma unroll
      for (int j = 0; j < 4; ++j) acc[i][j] = fmaf(wv[i], xv[j], acc[i][j]);
  }
#pragma unroll
  for (int i = 0; i < 4; ++i) {
    int ch = ty + 16 * i;
    bf16* yb = Y + (size_t)(b * 64 + ch) * NP + n0 + tx * 4;
#pragma unroll
    for (int j = 0; j < 4; ++j) yb[j] = f2bf(acc[i][j]);
  }
}

// ---------------------------------------------------------------------------
// K2a: stats stage 1.
// ---------------------------------------------------------------------------
__global__ __launch_bounds__(256) void k_stats_p1(const bf16* __restrict__ Y,
                                                  float* __restrict__ PS) {
  int blk = blockIdx.x, tid = threadIdx.x;
  int o = blk >> 3, slab = blk & 7;
  int b = slab >> 1, half = slab & 1;
  const us8* vp =
      (const us8*)(Y + ((size_t)(b * 64 + o)) * NP + half * 8192);
  float s = 0.f, ss = 0.f;
#pragma unroll
  for (int it = 0; it < 4; ++it) {
    us8 v = vp[tid + 256 * it];
#pragma unroll
    for (int e = 0; e < 8; ++e) {
      float f = bfu(v[e]);
      s += f;
      ss = fmaf(f, f, ss);
    }
  }
  for (int off = 32; off > 0; off >>= 1) {
    s += __shfl_down(s, off, 64);
    ss += __shfl_down(ss, off, 64);
  }
  __shared__ float sh[8];
  int wv = tid >> 6, ln = tid & 63;
  if (ln == 0) { sh[wv] = s; sh[4 + wv] = ss; }
  __syncthreads();
  if (tid == 0) {
    PS[blk] = sh[0] + sh[1] + sh[2] + sh[3];
    PS[512 + blk] = sh[4] + sh[5] + sh[6] + sh[7];
  }
}

// K2b: stats stage 2 + BN scale/shift + scalar header (fused)
__global__ __launch_bounds__(64) void k_stats_p2(
    const float* __restrict__ PS, const float* __restrict__ bng,
    const float* __restrict__ bnb, float* __restrict__ SCALE,
    float* __restrict__ SHIFT, const float* xg, const float* fg,
    const float* pg, const float* pg2, const float* cg,
    float* __restrict__ HDR) {
  int o = threadIdx.x;
  float s = 0.f, ss = 0.f;
#pragma unroll
  for (int k = 0; k < 8; ++k) {
    s += PS[o * 8 + k];
    ss += PS[512 + o * 8 + k];
  }
  const float inv = 1.0f / (NB * NP);
  float mu = s * inv;
  float var = ss * inv - mu * mu;
  float r = rsqrtf(var + 1e-5f);
  float sc = r * bng[o];
  SCALE[o] = sc;
  SHIFT[o] = bnb[o] - mu * sc;
  if (o == 0) {
    float vpg = pg[0];
    HDR[1] = vpg * xg[0];
    HDR[2] = pg2[0] * fg[0];
    HDR[3] = 2.0f + vpg;
    HDR[4] = pg2[0];
    HDR[5] = cg[0];
  }
}

// ---------------------------------------------------------------------------
// K4: fused q|k|v conv1x1: 80 out-ch x 128 px, 5x8 thread tile.
// ---------------------------------------------------------------------------
template <bool BN>
__global__ __launch_bounds__(256) void k_conv80(
    const void* __restrict__ inp, const float* __restrict__ SCALE,
    const float* __restrict__ SHIFT,
    const float* __restrict__ qw, const float* __restrict__ qb,
    const float* __restrict__ kw, const float* __restrict__ kb,
    const float* __restrict__ vw, const float* __restrict__ vb,
    bf16* __restrict__ Q, bf16* __restrict__ K, bf16* __restrict__ V) {
  __shared__ float wS[80 * 65], bS[80];
  __shared__ u16 Xs[8192];
  int tid = threadIdx.x;
  int b = blockIdx.x >> 7, tile = blockIdx.x & 127;
  int n0 = tile * 128;
  for (int i = tid; i < 512; i += 256) {
    wS[(i >> 6) * 65 + (i & 63)] = qw[i];
    wS[(8 + (i >> 6)) * 65 + (i & 63)] = kw[i];
  }
  for (int i = tid; i < 4096; i += 256)
    wS[(16 + (i >> 6)) * 65 + (i & 63)] = vw[i];
  if (tid < 8) { bS[tid] = qb[tid]; bS[8 + tid] = kb[tid]; }
  if (tid < 64) bS[16 + tid] = vb[tid];
  for (int i = tid; i < 8192; i += 256) {
    int c = i >> 7, px = i & 127;
    size_t idx = (size_t)(b * 64 + c) * NP + n0 + px;
    float v;
    if (BN) {
      v = bf2f(((const bf16*)inp)[idx]);
      v = fmaf(v, SCALE[c], SHIFT[c]);
      v = fmaxf(v, 0.f);
    } else {
      v = ((const float*)inp)[idx];
    }
    Xs[i] = fbu(v);
  }
  __syncthreads();
  int ty = tid >> 4, tx = tid & 15;
  float acc[5][8];
#pragma unroll
  for (int i = 0; i < 5; ++i) {
    float bv = bS[ty + 16 * i];
#pragma unroll
    for (int j = 0; j < 8; ++j) acc[i][j] = bv;
  }
  for (int c = 0; c < 64; ++c) {
    float xv[8], wv[5];
#pragma unroll
    for (int j = 0; j < 8; ++j) xv[j] = bfu(Xs[c * 128 + tx + 16 * j]);
#pragma unroll
    for (int i = 0; i < 5; ++i) wv[i] = wS[(ty + 16 * i) * 65 + c];
#pragma unroll
    for (int i = 0; i < 5; ++i)
#pragma unroll
      for (int j = 0; j < 8; ++j) acc[i][j] = fmaf(wv[i], xv[j], acc[i][j]);
  }
#pragma unroll
  for (int i = 0; i < 5; ++i) {
    int ch = ty + 16 * i;
    bf16* dst;
    size_t base;
    if (ch < 8) { dst = Q; base = (size_t)(b * 8 + ch) * NP; }
    else if (ch < 16) { dst = K; base = (size_t)(b * 8 + ch - 8) * NP; }
    else { dst = V; base = (size_t)(b * 64 + ch - 16) * NP; }
#pragma unroll
    for (int j = 0; j < 8; ++j) dst[base + n0 + tx + 16 * j] = f2bf(acc[i][j]);
  }
}

// ---------------------------------------------------------------------------
// K5: 128x128 bf16 plane transpose
// ---------------------------------------------------------------------------
__global__ __launch_bounds__(256) void k_transpose(const u16* __restrict__ in,
                                                   u16* __restrict__ out) {
  int tileId = blockIdx.x & 15;
  int plane = blockIdx.x >> 4;
  int th = tileId >> 2, tw = tileId & 3;
  __shared__ u16 t[32][33];
  int lx = threadIdx.x & 31, ly = threadIdx.x >> 5;
  const u16* ip = in + (size_t)plane * NP;
  for (int i = 0; i < 32; i += 8)
    t[ly + i][lx] = ip[(size_t)(th * 32 + ly + i) * 128 + tw * 32 + lx];
  __syncthreads();
  u16* op = out + (size_t)plane * NP;
  for (int i = 0; i < 32; i += 8)
    op[(size_t)(tw * 32 + ly + i) * 128 + th * 32 + lx] = t[lx][ly + i];
}

// ---------------------------------------------------------------------------
// K6a: e_w per-row max/sumexp -> raw stats into MW/LW
// ---------------------------------------------------------------------------
__global__ __launch_bounds__(256) void k_ew_stats(
    const bf16* __restrict__ Q, const bf16* __restrict__ K,
    float* __restrict__ MW, float* __restrict__ LW) {
  int b = blockIdx.x >> 7, h = blockIdx.x & 127;
  __shared__ float qs[1024], ks[1024], red[256];
  int tid = threadIdx.x;
  for (int i = tid; i < 1024; i += 256) {
    int c = i >> 7, j = i & 127;
    size_t idx = (size_t)(b * 8 + c) * NP + (size_t)h * 128 + j;
    qs[i] = bf2f(Q[idx]);
    ks[i] = bf2f(K[idx]);
  }
  __syncthreads();
  int w = tid & 127, half = tid >> 7;
  float qr[8];
#pragma unroll
  for (int c = 0; c < 8; ++c) qr[c] = qs[c * 128 + w];
  float m = -3.0e38f;
  for (int v0 = 0; v0 < 64; ++v0) {
    int v = half * 64 + v0;
    float s = 0.f;
#pragma unroll
    for (int c = 0; c < 8; ++c) s = fmaf(qr[c], ks[c * 128 + v], s);
    m = fmaxf(m, s);
  }
  red[tid] = m;
  __syncthreads();
  float mj = fmaxf(red[w], red[128 + w]);
  __syncthreads();
  float l = 0.f;
  for (int v0 = 0; v0 < 64; ++v0) {
    int v = half * 64 + v0;
    float s = 0.f;
#pragma unroll
    for (int c = 0; c < 8; ++c) s = fmaf(qr[c], ks[c * 128 + v], s);
    l += __expf(s - mj);
  }
  red[tid] = l;
  __syncthreads();
  if (half == 0) {
    size_t o = (size_t)b * NP + (size_t)h * 128 + w;
    MW[o] = mj;
    LW[o] = red[w] + red[128 + w];
  }
}

// ---------------------------------------------------------------------------
// K6b: e_h per-row stats (diag masked) + in-place combine -> MW=M, LW=1/L
// ---------------------------------------------------------------------------
__global__ __launch_bounds__(256) void k_eh_combine(
    const bf16* __restrict__ QT, const bf16* __restrict__ KT,
    float* __restrict__ MW, float* __restrict__ LW) {
  int b = blockIdx.x >> 7, w = blockIdx.x & 127;
  __shared__ float qs[1024], ks[1024], red[256];
  int tid = threadIdx.x;
  for (int i = tid; i < 1024; i += 256) {
    int c = i >> 7, j = i & 127;
    size_t idx = (size_t)(b * 8 + c) * NP + (size_t)w * 128 + j;
    qs[i] = bf2f(QT[idx]);
    ks[i] = bf2f(KT[idx]);
  }
  __syncthreads();
  int h = tid & 127, half = tid >> 7;
  float qr[8];
#pragma unroll
  for (int c = 0; c < 8; ++c) qr[c] = qs[c * 128 + h];
  float m = -3.0e38f;
  for (int g0 = 0; g0 < 64; ++g0) {
    int g = half * 64 + g0;
    float s = 0.f;
#pragma unroll
    for (int c = 0; c < 8; ++c) s = fmaf(qr[c], ks[c * 128 + g], s);
    if (g == h) s = -1.0e30f;
    m = fmaxf(m, s);
  }
  red[tid] = m;
  __syncthreads();
  float mj = fmaxf(red[h], red[128 + h]);
  __syncthreads();
  float l = 0.f;
  for (int g0 = 0; g0 < 64; ++g0) {
    int g = half * 64 + g0;
    float s = 0.f;
#pragma unroll
    for (int c = 0; c < 8; ++c) s = fmaf(qr[c], ks[c * 128 + g], s);
    l += (g == h) ? 0.f : __expf(s - mj);
  }
  red[tid] = l;
  __syncthreads();
  if (half == 0) {
    size_t o = (size_t)b * NP + (size_t)h * 128 + w;
    float lh = red[h] + red[128 + h];
    float mw = MW[o], lw = LW[o];
    float mm = fmaxf(mw, mj);
    float ll = lw * __expf(mw - mm) + lh * __expf(mj - mm);
    MW[o] = mm;
    LW[o] = 1.0f / ll;
  }
}

// ---------------------------------------------------------------------------
// K7: merged out_w + out_h on MFMA. 1024 blocks = (b,h) x mode; 256 thr
// (4 waves, one 32-row chunk each). Single staging per plane (no duplicate
// fetch); LDS 22.5 KB -> grid-capped 4 blocks/CU = 16 waves/CU.
// ---------------------------------------------------------------------------
__global__ __launch_bounds__(256, 4) void k_av(
    const bf16* __restrict__ Q, const bf16* __restrict__ K,
    const bf16* __restrict__ V, const bf16* __restrict__ QT,
    const bf16* __restrict__ KT, const bf16* __restrict__ VT,
    const float* __restrict__ M, const float* __restrict__ LI,
    float* __restrict__ ACC, bf16* __restrict__ OHT,
    const float* __restrict__ HDR, int scIdx, int accum) {
  int mode = blockIdx.x & 1;         // 0: out_w, 1: out_h
  int bid = blockIdx.x >> 1;
  int b = bid >> 7, h = bid & 127;
  const bf16* Qp = mode ? QT : Q;
  const bf16* Kp = mode ? KT : K;
  const bf16* Vp = mode ? VT : V;
  __shared__ __align__(16) u16 qT[128 * 8];    // [p(j)][c]
  __shared__ __align__(16) u16 kT[128 * 8];    // [p(j)][c]
  __shared__ __align__(16) u16 Vs[64 * 136];   // [c][j], pad 136
  __shared__ float Ml[128], Li[128];
  int tid = threadIdx.x;
  {  // q (tid<128) / k (tid>=128): 1024 u16 each, one us8 load per thread
    int c = (tid >> 4) & 7, vj = tid & 15;
    const bf16* src = (tid < 128) ? Qp : Kp;
    u16* dst = (tid < 128) ? qT : kT;
    const us8* sp = (const us8*)(src + ((size_t)(b * 8 + c)) * NP + (size_t)h * 128);
    us8 sv = sp[vj];
#pragma unroll
    for (int e = 0; e < 8; ++e) {
      int j = vj * 8 + e;
      int p = ((j & 7) << 4) | (j >> 3);
      dst[p * 8 + c] = sv[e];
    }
  }
  for (int i2 = tid; i2 < 1024; i2 += 256) {  // V: 8192 u16, b128 writes
    int c = i2 >> 4, vj = i2 & 15;
    const us8* vp =
        (const us8*)(Vp + ((size_t)(b * 64 + c)) * NP + (size_t)h * 128);
    us8 vv = vp[vj];
    *(us8*)&Vs[c * 136 + vj * 8] = vv;
  }
  if (tid < 128) {
    if (mode == 0) {
      Ml[tid] = M[(size_t)b * NP + (size_t)h * 128 + tid];
      Li[tid] = LI[(size_t)b * NP + (size_t)h * 128 + tid];
    } else {
      Ml[tid] = M[(size_t)b * NP + (size_t)tid * 128 + h];
      Li[tid] = LI[(size_t)b * NP + (size_t)tid * 128 + h];
    }
  }
  __syncthreads();
  float sc = HDR[scIdx];
  int lane = tid & 63, wv = tid >> 6;   // wave wv owns rows [wv*32, wv*32+32)
  int il = lane & 15, gq = lane >> 4;
  float* accBase = ACC + (size_t)(b * 64) * NP + (size_t)h * 128;
  bf16* outBase = OHT + (size_t)(b * 64) * NP + (size_t)h * 128;
#pragma unroll
  for (int sub = 0; sub < 2; ++sub) {
    int ib = wv * 32 + sub * 16;
    int i = ib + il;                 // this lane's A-row
    float mv = Ml[i], li = Li[i];
    int pi = ((i & 7) << 4) | (i >> 3);
    us8 qv = *(const us8*)&qT[pi * 8];
    float qr[8];
#pragma unroll
    for (int c = 0; c < 8; ++c) qr[c] = bfu(qv[c]);
    ss8 afr[4];
#pragma unroll
    for (int ks = 0; ks < 4; ++ks) {
      ss8 af;
#pragma unroll
      for (int e = 0; e < 8; ++e) {
        int j = ks * 32 + gq * 8 + e;
        int pj = ((j & 7) << 4) | (j >> 3);
        us8 kv = *(const us8*)&kT[pj * 8];
        float s = 0.f;
#pragma unroll
        for (int c = 0; c < 8; ++c) s = fmaf(qr[c], bfu(kv[c]), s);
        float ev = __expf(s - mv) * li;
        if (mode && j == i) ev = 0.f;
        af[e] = (short)fbu(ev);
      }
      afr[ks] = af;
    }
#pragma unroll
    for (int ct = 0; ct < 4; ++ct) {
      f32x4 acc = {0.f, 0.f, 0.f, 0.f};
#pragma unroll
      for (int ks = 0; ks < 4; ++ks) {
        ss8 bv = *(const ss8*)&Vs[(ct * 16 + il) * 136 + ks * 32 + gq * 8];
        acc = __builtin_amdgcn_mfma_f32_16x16x32_bf16(afr[ks], bv, acc, 0, 0, 0);
      }
      int cch = ct * 16 + il;        // D col = channel
      int i0 = ib + gq * 4;          // D rows = 4 consecutive pixels
      if (mode == 0) {
#pragma unroll
        for (int r = 0; r < 4; ++r) {
          size_t o = (size_t)cch * NP + (size_t)(i0 + r);
          float val = sc * acc[r];
          accBase[o] = (accum ? accBase[o] : 0.f) + val;
        }
      } else {
#pragma unroll
        for (int r = 0; r < 4; ++r)
          outBase[(size_t)cch * NP + (size_t)(i0 + r)] = f2bf(acc[r]);
      }
    }
  }
}

// ---------------------------------------------------------------------------
// K8b: transpose-add: ACC[b][c][h][w] += sc * OHT[b][c][w][h]. 32x32 LDS.
// ---------------------------------------------------------------------------
__global__ __launch_bounds__(256) void k_merge(const bf16* __restrict__ OHT,
                                               float* __restrict__ ACC,
                                               const float* __restrict__ HDR,
                                               int scIdx) {
  int tileId = blockIdx.x & 15;
  int plane = blockIdx.x >> 4;
  int th = tileId >> 2, tw = tileId & 3;
  __shared__ float t[32][33];
  int lx = threadIdx.x & 31, ly = threadIdx.x >> 5;
  const bf16* ip = OHT + (size_t)plane * NP;
  for (int i = 0; i < 32; i += 8)
    t[ly + i][lx] = bf2f(ip[(size_t)(th * 32 + ly + i) * 128 + tw * 32 + lx]);
  __syncthreads();
  float sc = HDR[scIdx];
  float* op = ACC + (size_t)plane * NP;
  for (int i = 0; i < 32; i += 8) {
    int h = tw * 32 + ly + i, w = th * 32 + lx;
    op[(size_t)h * 128 + w] += sc * t[lx][ly + i];
  }
}

// ---------------------------------------------------------------------------
// K9: partial Gram of y=BN(Y). 512 blocks = b x ch x t (t-loop split across
// blocks; was 128 blocks = half the GPU idle). Partials -> GP (OHT region).
// ---------------------------------------------------------------------------
__global__ __launch_bounds__(256) void k_gram(const bf16* __restrict__ Y,
                                              const float* __restrict__ SCALE,
                                              const float* __restrict__ SHIFT,
                                              float* __restrict__ GP) {
  int b = blockIdx.x >> 7, ch = (blockIdx.x >> 2) & 31, t = blockIdx.x & 3;
  int tid = threadIdx.x;
  __shared__ float fs[64 * 129];
  int cg = tid >> 4, dg = tid & 15;
  float acc[4][4];
#pragma unroll
  for (int i = 0; i < 4; ++i)
#pragma unroll
    for (int jx = 0; jx < 4; ++jx) acc[i][jx] = 0.f;
  const bf16* yb = Y + (size_t)b * 64 * NP + ch * 512;
  for (int idx = tid; idx < 8192; idx += 256) {
    int c = idx >> 7, j = idx & 127;
    float v = fmaf(bf2f(yb[(size_t)c * NP + t * 128 + j]), SCALE[c], SHIFT[c]);
    fs[c * 129 + j] = fmaxf(v, 0.f);
  }
  __syncthreads();
  for (int j = 0; j < 128; ++j) {
    float a[4], d[4];
#pragma unroll
    for (int i = 0; i < 4; ++i) a[i] = fs[(cg * 4 + i) * 129 + j];
#pragma unroll
    for (int i = 0; i < 4; ++i) d[i] = fs[(dg * 4 + i) * 129 + j];
#pragma unroll
    for (int i = 0; i < 4; ++i)
#pragma unroll
      for (int jx = 0; jx < 4; ++jx) acc[i][jx] = fmaf(a[i], d[jx], acc[i][jx]);
  }
  float* gp = GP + ((size_t)(b * 128) + ch * 4 + t) * 4096;
#pragma unroll
  for (int i = 0; i < 4; ++i)
#pragma unroll
    for (int jx = 0; jx < 4; ++jx)
      gp[(cg * 4 + i) * 64 + dg * 4 + jx] = acc[i][jx];
}

// K10: reduce 128 Gram partials; row softmax of (max-E). 16 blocks = b x 4
// row-groups, 16 rows each (was 4 blocks pulling 8 MB through 4 CUs).
__global__ __launch_bounds__(256) void k_gram_reduce(const float* __restrict__ GP,
                                                     float* __restrict__ CATT) {
  int b = blockIdx.x >> 2, rg = blockIdx.x & 3;
  int tid = threadIdx.x;
  __shared__ float Es[1024];
  // entries e in [rg*1024, rg*1024+1024): rows rg*16..rg*16+16
  for (int e4 = tid; e4 < 1024; e4 += 256) {
    int e = rg * 1024 + e4;
    float s = 0.f;
    for (int k = 0; k < 128; ++k) s += GP[((size_t)b * 128 + k) * 4096 + e];
    Es[e4] = s;
  }
  __syncthreads();
  int wv = tid >> 6, ln = tid & 63;
  for (int r = wv; r < 16; r += 4) {
    float v = Es[r * 64 + ln];
    float mn = v;
    for (int off = 32; off; off >>= 1) mn = fminf(mn, __shfl_xor(mn, off, 64));
    float e = __expf(mn - v);
    float s = e;
    for (int off = 32; off; off >>= 1) s += __shfl_xor(s, off, 64);
    CATT[((size_t)b * 64 + rg * 16 + r) * 64 + ln] = e / s;
  }
}

// ---------------------------------------------------------------------------
// K11: out = (2+pg)*x + pg2*y + ACC + cg*(catt@y). In-place fp32 on d_out.
// ---------------------------------------------------------------------------
__global__ __launch_bounds__(256) void k_final(
    const float* __restrict__ x, const bf16* __restrict__ Y,
    const float* __restrict__ SCALE, const float* __restrict__ SHIFT,
    const float* __restrict__ CATT, const float* __restrict__ HDR,
    float* __restrict__ OUT) {
  __shared__ float attS[64 * 65], Ys[64 * 65];
  int tid = threadIdx.x;
  int b = blockIdx.x >> 8, tile = blockIdx.x & 255;
  int n0 = tile * 64;
  for (int i = tid; i < 4096; i += 256)
    attS[(i >> 6) * 65 + (i & 63)] = CATT[(size_t)b * 4096 + i];
  for (int i = tid; i < 4096; i += 256) {
    int d = i >> 6, px = i & 63;
    float v = fmaf(bf2f(Y[(size_t)(b * 64 + d) * NP + n0 + px]), SCALE[d], SHIFT[d]);
    Ys[d * 65 + px] = fmaxf(v, 0.f);
  }
  __syncthreads();
  int cg = tid >> 4, pgx = tid & 15;
  int c0 = cg * 4, p0 = pgx * 4;
  float acc[4][4];
#pragma unroll
  for (int i = 0; i < 4; ++i)
#pragma unroll
    for (int j = 0; j < 4; ++j) acc[i][j] = 0.f;
  for (int d = 0; d < 64; ++d) {
    float a[4], yv[4];
#pragma unroll
    for (int i = 0; i < 4; ++i) a[i] = attS[(c0 + i) * 65 + d];
#pragma unroll
    for (int j = 0; j < 4; ++j) yv[j] = Ys[d * 65 + p0 + j];
#pragma unroll
    for (int i = 0; i < 4; ++i)
#pragma unroll
      for (int j = 0; j < 4; ++j) acc[i][j] = fmaf(a[i], yv[j], acc[i][j]);
  }
  float c2pg = HDR[3], fpg2 = HDR[4], fcg = HDR[5];
#pragma unroll
  for (int i = 0; i < 4; ++i) {
    size_t base = (size_t)(b * 64 + c0 + i) * NP + n0 + p0;
#pragma unroll
    for (int j = 0; j < 4; ++j) {
      float yv = Ys[(c0 + i) * 65 + p0 + j];
      OUT[base + j] =
          c2pg * x[base + j] + fpg2 * yv + OUT[base + j] + fcg * acc[i][j];
    }
  }
}

// ---------------------------------------------------------------------------
extern "C" void kernel_launch(void* const* d_in, const int* in_sizes, int n_in,
                              void* d_out, int out_size, void* d_ws, size_t ws_size,
                              hipStream_t stream) {
  const float* x = (const float*)d_in[0];
  const float* fbp = (const float*)d_in[1];

  // Workspace: 38,277,120 bytes total (proven extent).
  char* base = (char*)d_ws;
  float* HDR = (float*)base;
  float* SCALE = HDR + 16;
  float* SHIFT = SCALE + 64;
  char* p = base + 4096;
  bf16* Y = (bf16*)p;   p += 8388608;
  bf16* Q = (bf16*)p;   p += 1048576;
  bf16* K = (bf16*)p;   p += 1048576;
  bf16* QT = (bf16*)p;  p += 1048576;
  bf16* KT = (bf16*)p;  p += 1048576;
  bf16* V = (bf16*)p;   p += 8388608;
  bf16* VT = (bf16*)p;  p += 8388608;
  float* MW = (float*)p; p += 262144;   // joint M after combine
  float* LW = (float*)p; p += 262144;   // joint 1/L after combine
  bf16* OHT = (bf16*)p;  p += 8388608;  // out_h in [b][c][w][h] layout
  float* ACC = (float*)d_out;           // fp32, 16 MB
  float* PS = (float*)Q;     // stats partials (4 KB), Q unused until conv80
  float* GP = (float*)OHT;   // Gram partials (8 MB), OHT free after merges
  float* CATT = (float*)QT;  // reuses QT

  k_pool_conv<<<1024, 256, 0, stream>>>(fbp, (const float*)d_in[2],
                                        (const float*)d_in[3], Y);
  k_stats_p1<<<512, 256, 0, stream>>>(Y, PS);
  k_stats_p2<<<1, 64, 0, stream>>>(PS, (const float*)d_in[4],
                                   (const float*)d_in[5], SCALE, SHIFT,
                                   (const float*)d_in[12], (const float*)d_in[19],
                                   (const float*)d_in[20], (const float*)d_in[21],
                                   (const float*)d_in[22], HDR);

  for (int m = 0; m < 2; ++m) {
    const float *qw, *qb, *kw, *kb, *vw, *vb;
    if (m == 0) {
      qw = (const float*)d_in[6]; qb = (const float*)d_in[7];
      kw = (const float*)d_in[8]; kb = (const float*)d_in[9];
      vw = (const float*)d_in[10]; vb = (const float*)d_in[11];
    } else {
      qw = (const float*)d_in[13]; qb = (const float*)d_in[14];
      kw = (const float*)d_in[15]; kb = (const float*)d_in[16];
      vw = (const float*)d_in[17]; vb = (const float*)d_in[18];
    }
    if (m == 0)
      k_conv80<false><<<512, 256, 0, stream>>>(x, SCALE, SHIFT, qw, qb, kw, kb,
                                               vw, vb, Q, K, V);
    else
      k_conv80<true><<<512, 256, 0, stream>>>(Y, SCALE, SHIFT, qw, qb, kw, kb,
                                              vw, vb, Q, K, V);
    // Q,K contiguous and QT,KT contiguous: one call transposes both (64 planes)
    k_transpose<<<1024, 256, 0, stream>>>((const u16*)Q, (u16*)QT);
    k_transpose<<<4096, 256, 0, stream>>>((const u16*)V, (u16*)VT);
    k_ew_stats<<<512, 256, 0, stream>>>(Q, K, MW, LW);
    k_eh_combine<<<512, 256, 0, stream>>>(QT, KT, MW, LW);
    // merged out_w + out_h on MFMA: 1024 blocks x 256 thr (4 waves/chunk)
    k_av<<<1024, 256, 0, stream>>>(Q, K, V, QT, KT, VT, MW, LW, ACC, OHT,
                                   HDR, 1 + m, m);
    k_merge<<<4096, 256, 0, stream>>>(OHT, ACC, HDR, 1 + m);
  }

  k_gram<<<512, 256, 0, stream>>>(Y, SCALE, SHIFT, GP);
  k_gram_reduce<<<16, 256, 0, stream>>>(GP, CATT);
  k_final<<<1024, 256, 0, stream>>>(x, Y, SCALE, SHIFT, CATT, HDR,
                                    (float*)d_out);
}

// Round 5
// 358.125 us; speedup vs baseline: 1.5896x; 1.0981x over previous
//
#include <hip/hip_runtime.h>
#include <hip/hip_bf16.h>

#define NP 16384   // H*W
#define NB 4

typedef __hip_bfloat16 bf16;
typedef unsigned short u16;
typedef unsigned short us8 __attribute__((ext_vector_type(8)));
typedef short ss8 __attribute__((ext_vector_type(8)));
typedef float f32x4 __attribute__((ext_vector_type(4)));
__device__ __forceinline__ float bf2f(const bf16 v) { return __bfloat162float(v); }
__device__ __forceinline__ bf16 f2bf(float v) { return __float2bfloat16(v); }
__device__ __forceinline__ float bfu(u16 h) {
  return __uint_as_float(((unsigned)h) << 16);
}
__device__ __forceinline__ u16 fbu(float v) {
  bf16 b = f2bf(v);
  return *(u16*)&b;
}

// Inputs/outputs fp32 (reference dtype). Internal tensors bf16, math fp32.

// ---------------------------------------------------------------------------
// K1: maxpool2x2(fb fp32) -> conv1x1+bias -> Y raw (pre-BN, bf16). 64x64 tile.
// ---------------------------------------------------------------------------
__global__ __launch_bounds__(256) void k_pool_conv(
    const float* __restrict__ fb, const float* __restrict__ wconv,
    const float* __restrict__ bconv, bf16* __restrict__ Y) {
  __shared__ float wS[64 * 65], bS[64], Xs[4096];
  int tid = threadIdx.x;
  int b = blockIdx.x >> 8, tile = blockIdx.x & 255;
  int n0 = tile * 64;
  for (int i = tid; i < 4096; i += 256) wS[(i >> 6) * 65 + (i & 63)] = wconv[i];
  if (tid < 64) bS[tid] = bconv[tid];
  for (int i = tid; i < 4096; i += 256) {
    int c = i >> 6, px = i & 63;
    int n = n0 + px, h = n >> 7, w = n & 127;
    size_t fbase = ((size_t)((b * 64 + c) * 256 + 2 * h)) * 256 + 2 * w;
    float2 v01 = *(const float2*)(fb + fbase);
    float2 v23 = *(const float2*)(fb + fbase + 256);
    Xs[i] = fmaxf(fmaxf(v01.x, v01.y), fmaxf(v23.x, v23.y));
  }
  __syncthreads();
  int ty = tid >> 4, tx = tid & 15;
  float acc[4][4];
#pragma unroll
  for (int i = 0; i < 4; ++i) {
    float bv = bS[ty + 16 * i];
#pragma unroll
    for (int j = 0; j < 4; ++j) acc[i][j] = bv;
  }
  for (int c = 0; c < 64; ++c) {
    float xv[4], wv[4];
#pragma unroll
    for (int j = 0; j < 4; ++j) xv[j] = Xs[c * 64 + tx * 4 + j];
#pragma unroll
    for (int i = 0; i < 4; ++i) wv[i] = wS[(ty + 16 * i) * 65 + c];
#pragma unroll
    for (int i = 0; i < 4; ++i)
#pragma unroll
      for (int j = 0; j < 4; ++j) acc[i][j] = fmaf(wv[i], xv[j], acc[i][j]);
  }
#pragma unroll
  for (int i = 0; i < 4; ++i) {
    int ch = ty + 16 * i;
    bf16* yb = Y + (size_t)(b * 64 + ch) * NP + n0 + tx * 4;
#pragma unroll
    for (int j = 0; j < 4; ++j) yb[j] = f2bf(acc[i][j]);
  }
}

// ---------------------------------------------------------------------------
// K2a: stats stage 1.
// ---------------------------------------------------------------------------
__global__ __launch_bounds__(256) void k_stats_p1(const bf16* __restrict__ Y,
                                                  float* __restrict__ PS) {
  int blk = blockIdx.x, tid = threadIdx.x;
  int o = blk >> 3, slab = blk & 7;
  int b = slab >> 1, half = slab & 1;
  const us8* vp =
      (const us8*)(Y + ((size_t)(b * 64 + o)) * NP + half * 8192);
  float s = 0.f, ss = 0.f;
#pragma unroll
  for (int it = 0; it < 4; ++it) {
    us8 v = vp[tid + 256 * it];
#pragma unroll
    for (int e = 0; e < 8; ++e) {
      float f = bfu(v[e]);
      s += f;
      ss = fmaf(f, f, ss);
    }
  }
  for (int off = 32; off > 0; off >>= 1) {
    s += __shfl_down(s, off, 64);
    ss += __shfl_down(ss, off, 64);
  }
  __shared__ float sh[8];
  int wv = tid >> 6, ln = tid & 63;
  if (ln == 0) { sh[wv] = s; sh[4 + wv] = ss; }
  __syncthreads();
  if (tid == 0) {
    PS[blk] = sh[0] + sh[1] + sh[2] + sh[3];
    PS[512 + blk] = sh[4] + sh[5] + sh[6] + sh[7];
  }
}

// K2b: stats stage 2 + BN scale/shift + scalar header (fused)
__global__ __launch_bounds__(64) void k_stats_p2(
    const float* __restrict__ PS, const float* __restrict__ bng,
    const float* __restrict__ bnb, float* __restrict__ SCALE,
    float* __restrict__ SHIFT, const float* xg, const float* fg,
    const float* pg, const float* pg2, const float* cg,
    float* __restrict__ HDR) {
  int o = threadIdx.x;
  float s = 0.f, ss = 0.f;
#pragma unroll
  for (int k = 0; k < 8; ++k) {
    s += PS[o * 8 + k];
    ss += PS[512 + o * 8 + k];
  }
  const float inv = 1.0f / (NB * NP);
  float mu = s * inv;
  float var = ss * inv - mu * mu;
  float r = rsqrtf(var + 1e-5f);
  float sc = r * bng[o];
  SCALE[o] = sc;
  SHIFT[o] = bnb[o] - mu * sc;
  if (o == 0) {
    float vpg = pg[0];
    HDR[1] = vpg * xg[0];
    HDR[2] = pg2[0] * fg[0];
    HDR[3] = 2.0f + vpg;
    HDR[4] = pg2[0];
    HDR[5] = cg[0];
  }
}

// ---------------------------------------------------------------------------
// K4: fused q|k|v conv1x1: 80 out-ch x 64 px, 5x4 thread tile. 1024 blocks
// (was 512 x 128px): LDS 29 KB -> 4 blocks/CU (was 2) for latency hiding.
// ---------------------------------------------------------------------------
template <bool BN>
__global__ __launch_bounds__(256) void k_conv80(
    const void* __restrict__ inp, const float* __restrict__ SCALE,
    const float* __restrict__ SHIFT,
    const float* __restrict__ qw, const float* __restrict__ qb,
    const float* __restrict__ kw, const float* __restrict__ kb,
    const float* __restrict__ vw, const float* __restrict__ vb,
    bf16* __restrict__ Q, bf16* __restrict__ K, bf16* __restrict__ V) {
  __shared__ float wS[80 * 65], bS[80];
  __shared__ u16 Xs[4096];
  int tid = threadIdx.x;
  int b = blockIdx.x >> 8, tile = blockIdx.x & 255;
  int n0 = tile * 64;
  for (int i = tid; i < 512; i += 256) {
    wS[(i >> 6) * 65 + (i & 63)] = qw[i];
    wS[(8 + (i >> 6)) * 65 + (i & 63)] = kw[i];
  }
  for (int i = tid; i < 4096; i += 256)
    wS[(16 + (i >> 6)) * 65 + (i & 63)] = vw[i];
  if (tid < 8) { bS[tid] = qb[tid]; bS[8 + tid] = kb[tid]; }
  if (tid < 64) bS[16 + tid] = vb[tid];
  for (int i = tid; i < 4096; i += 256) {
    int c = i >> 6, px = i & 63;
    size_t idx = (size_t)(b * 64 + c) * NP + n0 + px;
    float v;
    if (BN) {
      v = bf2f(((const bf16*)inp)[idx]);
      v = fmaf(v, SCALE[c], SHIFT[c]);
      v = fmaxf(v, 0.f);
    } else {
      v = ((const float*)inp)[idx];
    }
    Xs[i] = fbu(v);
  }
  __syncthreads();
  int ty = tid >> 4, tx = tid & 15;
  float acc[5][4];
#pragma unroll
  for (int i = 0; i < 5; ++i) {
    float bv = bS[ty + 16 * i];
#pragma unroll
    for (int j = 0; j < 4; ++j) acc[i][j] = bv;
  }
  for (int c = 0; c < 64; ++c) {
    float xv[4], wv[5];
#pragma unroll
    for (int j = 0; j < 4; ++j) xv[j] = bfu(Xs[c * 64 + tx * 4 + j]);
#pragma unroll
    for (int i = 0; i < 5; ++i) wv[i] = wS[(ty + 16 * i) * 65 + c];
#pragma unroll
    for (int i = 0; i < 5; ++i)
#pragma unroll
      for (int j = 0; j < 4; ++j) acc[i][j] = fmaf(wv[i], xv[j], acc[i][j]);
  }
#pragma unroll
  for (int i = 0; i < 5; ++i) {
    int ch = ty + 16 * i;
    bf16* dst;
    size_t base;
    if (ch < 8) { dst = Q; base = (size_t)(b * 8 + ch) * NP; }
    else if (ch < 16) { dst = K; base = (size_t)(b * 8 + ch - 8) * NP; }
    else { dst = V; base = (size_t)(b * 64 + ch - 16) * NP; }
#pragma unroll
    for (int j = 0; j < 4; ++j) dst[base + n0 + tx * 4 + j] = f2bf(acc[i][j]);
  }
}

// ---------------------------------------------------------------------------
// K5: 128x128 bf16 plane transpose over two tensor pairs in one dispatch.
// planes [0,nA) : inA->outA ; [nA, nA+nB) : inB->outB.
// ---------------------------------------------------------------------------
__global__ __launch_bounds__(256) void k_transpose2(
    const u16* __restrict__ inA, u16* __restrict__ outA,
    const u16* __restrict__ inB, u16* __restrict__ outB, int nA) {
  int tileId = blockIdx.x & 15;
  int plane = blockIdx.x >> 4;
  const u16* ip;
  u16* op;
  if (plane < nA) {
    ip = inA + (size_t)plane * NP;
    op = outA + (size_t)plane * NP;
  } else {
    ip = inB + (size_t)(plane - nA) * NP;
    op = outB + (size_t)(plane - nA) * NP;
  }
  int th = tileId >> 2, tw = tileId & 3;
  __shared__ u16 t[32][33];
  int lx = threadIdx.x & 31, ly = threadIdx.x >> 5;
  for (int i = 0; i < 32; i += 8)
    t[ly + i][lx] = ip[(size_t)(th * 32 + ly + i) * 128 + tw * 32 + lx];
  __syncthreads();
  for (int i = 0; i < 32; i += 8)
    op[(size_t)(tw * 32 + ly + i) * 128 + th * 32 + lx] = t[lx][ly + i];
}

// ---------------------------------------------------------------------------
// K6: per-direction softmax stats, mode-split in one dispatch (1024 blocks).
// mode 0: e_w rows (no mask) -> MW/LW raw (m, sumexp).
// mode 1: e_h rows (diag masked) -> MH/LH raw.
// The cross-direction combine happens in k_av's prologue.
// ---------------------------------------------------------------------------
__global__ __launch_bounds__(256) void k_qk_stats(
    const bf16* __restrict__ Q, const bf16* __restrict__ K,
    const bf16* __restrict__ QT, const bf16* __restrict__ KT,
    float* __restrict__ MW, float* __restrict__ LW,
    float* __restrict__ MH, float* __restrict__ LH) {
  int mode = blockIdx.x & 1;
  int bid = blockIdx.x >> 1;
  int b = bid >> 7, pl = bid & 127;
  const bf16* Qp = mode ? QT : Q;
  const bf16* Kp = mode ? KT : K;
  float* Mo = mode ? MH : MW;
  float* Lo = mode ? LH : LW;
  __shared__ float qs[1024], ks[1024], red[256];
  int tid = threadIdx.x;
  for (int i = tid; i < 1024; i += 256) {
    int c = i >> 7, j = i & 127;
    size_t idx = (size_t)(b * 8 + c) * NP + (size_t)pl * 128 + j;
    qs[i] = bf2f(Qp[idx]);
    ks[i] = bf2f(Kp[idx]);
  }
  __syncthreads();
  int w = tid & 127, half = tid >> 7;
  float qr[8];
#pragma unroll
  for (int c = 0; c < 8; ++c) qr[c] = qs[c * 128 + w];
  float m = -3.0e38f;
  for (int v0 = 0; v0 < 64; ++v0) {
    int v = half * 64 + v0;
    float s = 0.f;
#pragma unroll
    for (int c = 0; c < 8; ++c) s = fmaf(qr[c], ks[c * 128 + v], s);
    if (mode && v == w) s = -1.0e30f;
    m = fmaxf(m, s);
  }
  red[tid] = m;
  __syncthreads();
  float mj = fmaxf(red[w], red[128 + w]);
  __syncthreads();
  float l = 0.f;
  for (int v0 = 0; v0 < 64; ++v0) {
    int v = half * 64 + v0;
    float s = 0.f;
#pragma unroll
    for (int c = 0; c < 8; ++c) s = fmaf(qr[c], ks[c * 128 + v], s);
    l += (mode && v == w) ? 0.f : __expf(s - mj);
  }
  red[tid] = l;
  __syncthreads();
  if (half == 0) {
    size_t o = (size_t)b * NP + (size_t)pl * 128 + w;
    Mo[o] = mj;
    Lo[o] = red[w] + red[128 + w];
  }
}

// ---------------------------------------------------------------------------
// K7: merged out_w + out_h on MFMA. 1024 blocks = (b,h) x mode; 256 thr.
// Prologue combines per-direction stats (2 exp / pixel).
// ---------------------------------------------------------------------------
__global__ __launch_bounds__(256, 4) void k_av(
    const bf16* __restrict__ Q, const bf16* __restrict__ K,
    const bf16* __restrict__ V, const bf16* __restrict__ QT,
    const bf16* __restrict__ KT, const bf16* __restrict__ VT,
    const float* __restrict__ MW, const float* __restrict__ LW,
    const float* __restrict__ MH, const float* __restrict__ LH,
    float* __restrict__ ACC, bf16* __restrict__ OHT,
    const float* __restrict__ HDR, int scIdx, int accum) {
  int mode = blockIdx.x & 1;         // 0: out_w, 1: out_h
  int bid = blockIdx.x >> 1;
  int b = bid >> 7, h = bid & 127;
  const bf16* Qp = mode ? QT : Q;
  const bf16* Kp = mode ? KT : K;
  const bf16* Vp = mode ? VT : V;
  __shared__ __align__(16) u16 qT[128 * 8];    // [p(j)][c]
  __shared__ __align__(16) u16 kT[128 * 8];    // [p(j)][c]
  __shared__ __align__(16) u16 Vs[64 * 136];   // [c][j], pad 136
  __shared__ float Ml[128], Li[128];
  int tid = threadIdx.x;
  {  // q (tid<128) / k (tid>=128): 1024 u16 each, one us8 load per thread
    int c = (tid >> 4) & 7, vj = tid & 15;
    const bf16* src = (tid < 128) ? Qp : Kp;
    u16* dst = (tid < 128) ? qT : kT;
    const us8* sp = (const us8*)(src + ((size_t)(b * 8 + c)) * NP + (size_t)h * 128);
    us8 sv = sp[vj];
#pragma unroll
    for (int e = 0; e < 8; ++e) {
      int j = vj * 8 + e;
      int p = ((j & 7) << 4) | (j >> 3);
      dst[p * 8 + c] = sv[e];
    }
  }
  for (int i2 = tid; i2 < 1024; i2 += 256) {  // V: 8192 u16, b128 writes
    int c = i2 >> 4, vj = i2 & 15;
    const us8* vp =
        (const us8*)(Vp + ((size_t)(b * 64 + c)) * NP + (size_t)h * 128);
    us8 vv = vp[vj];
    *(us8*)&Vs[c * 136 + vj * 8] = vv;
  }
  if (tid < 128) {  // combine the two direction stats for this plane's pixels
    float mw, lw, mh, lh;
    if (mode == 0) {
      size_t oc = (size_t)b * NP + (size_t)h * 128 + tid;    // contiguous
      size_t os = (size_t)b * NP + (size_t)tid * 128 + h;    // strided
      mw = MW[oc]; lw = LW[oc];
      mh = MH[os]; lh = LH[os];
    } else {
      size_t oc = (size_t)b * NP + (size_t)h * 128 + tid;
      size_t os = (size_t)b * NP + (size_t)tid * 128 + h;
      mh = MH[oc]; lh = LH[oc];
      mw = MW[os]; lw = LW[os];
    }
    float mm = fmaxf(mw, mh);
    float ll = lw * __expf(mw - mm) + lh * __expf(mh - mm);
    Ml[tid] = mm;
    Li[tid] = 1.0f / ll;
  }
  __syncthreads();
  float sc = HDR[scIdx];
  int lane = tid & 63, wv = tid >> 6;   // wave wv owns rows [wv*32, wv*32+32)
  int il = lane & 15, gq = lane >> 4;
  float* accBase = ACC + (size_t)(b * 64) * NP + (size_t)h * 128;
  bf16* outBase = OHT + (size_t)(b * 64) * NP + (size_t)h * 128;
#pragma unroll
  for (int sub = 0; sub < 2; ++sub) {
    int ib = wv * 32 + sub * 16;
    int i = ib + il;                 // this lane's A-row
    float mv = Ml[i], li = Li[i];
    int pi = ((i & 7) << 4) | (i >> 3);
    us8 qv = *(const us8*)&qT[pi * 8];
    float qr[8];
#pragma unroll
    for (int c = 0; c < 8; ++c) qr[c] = bfu(qv[c]);
    ss8 afr[4];
#pragma unroll
    for (int ks = 0; ks < 4; ++ks) {
      ss8 af;
#pragma unroll
      for (int e = 0; e < 8; ++e) {
        int j = ks * 32 + gq * 8 + e;
        int pj = ((j & 7) << 4) | (j >> 3);
        us8 kv = *(const us8*)&kT[pj * 8];
        float s = 0.f;
#pragma unroll
        for (int c = 0; c < 8; ++c) s = fmaf(qr[c], bfu(kv[c]), s);
        float ev = __expf(s - mv) * li;
        if (mode && j == i) ev = 0.f;
        af[e] = (short)fbu(ev);
      }
      afr[ks] = af;
    }
#pragma unroll
    for (int ct = 0; ct < 4; ++ct) {
      f32x4 acc = {0.f, 0.f, 0.f, 0.f};
#pragma unroll
      for (int ks = 0; ks < 4; ++ks) {
        ss8 bv = *(const ss8*)&Vs[(ct * 16 + il) * 136 + ks * 32 + gq * 8];
        acc = __builtin_amdgcn_mfma_f32_16x16x32_bf16(afr[ks], bv, acc, 0, 0, 0);
      }
      int cch = ct * 16 + il;        // D col = channel
      int i0 = ib + gq * 4;          // D rows = 4 consecutive pixels
      if (mode == 0) {
#pragma unroll
        for (int r = 0; r < 4; ++r) {
          size_t o = (size_t)cch * NP + (size_t)(i0 + r);
          float val = sc * acc[r];
          accBase[o] = (accum ? accBase[o] : 0.f) + val;
        }
      } else {
#pragma unroll
        for (int r = 0; r < 4; ++r)
          outBase[(size_t)cch * NP + (size_t)(i0 + r)] = f2bf(acc[r]);
      }
    }
  }
}

// ---------------------------------------------------------------------------
// K8b: transpose-add: ACC[b][c][h][w] += sc * OHT[b][c][w][h]. 32x32 LDS.
// ---------------------------------------------------------------------------
__global__ __launch_bounds__(256) void k_merge(const bf16* __restrict__ OHT,
                                               float* __restrict__ ACC,
                                               const float* __restrict__ HDR,
                                               int scIdx) {
  int tileId = blockIdx.x & 15;
  int plane = blockIdx.x >> 4;
  int th = tileId >> 2, tw = tileId & 3;
  __shared__ float t[32][33];
  int lx = threadIdx.x & 31, ly = threadIdx.x >> 5;
  const bf16* ip = OHT + (size_t)plane * NP;
  for (int i = 0; i < 32; i += 8)
    t[ly + i][lx] = bf2f(ip[(size_t)(th * 32 + ly + i) * 128 + tw * 32 + lx]);
  __syncthreads();
  float sc = HDR[scIdx];
  float* op = ACC + (size_t)plane * NP;
  for (int i = 0; i < 32; i += 8) {
    int h = tw * 32 + ly + i, w = th * 32 + lx;
    op[(size_t)h * 128 + w] += sc * t[lx][ly + i];
  }
}

// ---------------------------------------------------------------------------
// K9: partial Gram of y=BN(Y). 512 blocks = b x ch x t.
// ---------------------------------------------------------------------------
__global__ __launch_bounds__(256) void k_gram(const bf16* __restrict__ Y,
                                              const float* __restrict__ SCALE,
                                              const float* __restrict__ SHIFT,
                                              float* __restrict__ GP) {
  int b = blockIdx.x >> 7, ch = (blockIdx.x >> 2) & 31, t = blockIdx.x & 3;
  int tid = threadIdx.x;
  __shared__ float fs[64 * 129];
  int cg = tid >> 4, dg = tid & 15;
  float acc[4][4];
#pragma unroll
  for (int i = 0; i < 4; ++i)
#pragma unroll
    for (int jx = 0; jx < 4; ++jx) acc[i][jx] = 0.f;
  const bf16* yb = Y + (size_t)b * 64 * NP + ch * 512;
  for (int idx = tid; idx < 8192; idx += 256) {
    int c = idx >> 7, j = idx & 127;
    float v = fmaf(bf2f(yb[(size_t)c * NP + t * 128 + j]), SCALE[c], SHIFT[c]);
    fs[c * 129 + j] = fmaxf(v, 0.f);
  }
  __syncthreads();
  for (int j = 0; j < 128; ++j) {
    float a[4], d[4];
#pragma unroll
    for (int i = 0; i < 4; ++i) a[i] = fs[(cg * 4 + i) * 129 + j];
#pragma unroll
    for (int i = 0; i < 4; ++i) d[i] = fs[(dg * 4 + i) * 129 + j];
#pragma unroll
    for (int i = 0; i < 4; ++i)
#pragma unroll
      for (int jx = 0; jx < 4; ++jx) acc[i][jx] = fmaf(a[i], d[jx], acc[i][jx]);
  }
  float* gp = GP + ((size_t)(b * 128) + ch * 4 + t) * 4096;
#pragma unroll
  for (int i = 0; i < 4; ++i)
#pragma unroll
    for (int jx = 0; jx < 4; ++jx)
      gp[(cg * 4 + i) * 64 + dg * 4 + jx] = acc[i][jx];
}

// K10: reduce 128 Gram partials; row softmax of (max-E). 64 blocks =
// b x 16 groups of 4 rows; coalesced 1 KB lines per k-step.
__global__ __launch_bounds__(256) void k_gram_reduce(const float* __restrict__ GP,
                                                     float* __restrict__ CATT) {
  int b = blockIdx.x >> 4, rg = blockIdx.x & 15;
  int tid = threadIdx.x;
  __shared__ float Es[256];
  int e = rg * 256 + tid;
  float s = 0.f;
  for (int k = 0; k < 128; ++k) s += GP[((size_t)b * 128 + k) * 4096 + e];
  Es[tid] = s;
  __syncthreads();
  int wv = tid >> 6, ln = tid & 63;
  float v = Es[wv * 64 + ln];
  float mn = v;
  for (int off = 32; off; off >>= 1) mn = fminf(mn, __shfl_xor(mn, off, 64));
  float ev = __expf(mn - v);
  float ssum = ev;
  for (int off = 32; off; off >>= 1) ssum += __shfl_xor(ssum, off, 64);
  CATT[((size_t)b * 64 + rg * 4 + wv) * 64 + ln] = ev / ssum;
}

// ---------------------------------------------------------------------------
// K11: out = (2+pg)*x + pg2*y + ACC + cg*(catt@y). In-place fp32 on d_out.
// ---------------------------------------------------------------------------
__global__ __launch_bounds__(256) void k_final(
    const float* __restrict__ x, const bf16* __restrict__ Y,
    const float* __restrict__ SCALE, const float* __restrict__ SHIFT,
    const float* __restrict__ CATT, const float* __restrict__ HDR,
    float* __restrict__ OUT) {
  __shared__ float attS[64 * 65], Ys[64 * 65];
  int tid = threadIdx.x;
  int b = blockIdx.x >> 8, tile = blockIdx.x & 255;
  int n0 = tile * 64;
  for (int i = tid; i < 4096; i += 256)
    attS[(i >> 6) * 65 + (i & 63)] = CATT[(size_t)b * 4096 + i];
  for (int i = tid; i < 4096; i += 256) {
    int d = i >> 6, px = i & 63;
    float v = fmaf(bf2f(Y[(size_t)(b * 64 + d) * NP + n0 + px]), SCALE[d], SHIFT[d]);
    Ys[d * 65 + px] = fmaxf(v, 0.f);
  }
  __syncthreads();
  int cg = tid >> 4, pgx = tid & 15;
  int c0 = cg * 4, p0 = pgx * 4;
  float acc[4][4];
#pragma unroll
  for (int i = 0; i < 4; ++i)
#pragma unroll
    for (int j = 0; j < 4; ++j) acc[i][j] = 0.f;
  for (int d = 0; d < 64; ++d) {
    float a[4], yv[4];
#pragma unroll
    for (int i = 0; i < 4; ++i) a[i] = attS[(c0 + i) * 65 + d];
#pragma unroll
    for (int j = 0; j < 4; ++j) yv[j] = Ys[d * 65 + p0 + j];
#pragma unroll
    for (int i = 0; i < 4; ++i)
#pragma unroll
      for (int j = 0; j < 4; ++j) acc[i][j] = fmaf(a[i], yv[j], acc[i][j]);
  }
  float c2pg = HDR[3], fpg2 = HDR[4], fcg = HDR[5];
#pragma unroll
  for (int i = 0; i < 4; ++i) {
    size_t base = (size_t)(b * 64 + c0 + i) * NP + n0 + p0;
#pragma unroll
    for (int j = 0; j < 4; ++j) {
      float yv = Ys[(c0 + i) * 65 + p0 + j];
      OUT[base + j] =
          c2pg * x[base + j] + fpg2 * yv + OUT[base + j] + fcg * acc[i][j];
    }
  }
}

// ---------------------------------------------------------------------------
extern "C" void kernel_launch(void* const* d_in, const int* in_sizes, int n_in,
                              void* d_out, int out_size, void* d_ws, size_t ws_size,
                              hipStream_t stream) {
  const float* x = (const float*)d_in[0];
  const float* fbp = (const float*)d_in[1];

  // Workspace: ~38.8 MB used (ws is 256 MiB per harness fill size).
  char* base = (char*)d_ws;
  float* HDR = (float*)base;
  float* SCALE = HDR + 16;
  float* SHIFT = SCALE + 64;
  char* p = base + 4096;
  bf16* Y = (bf16*)p;   p += 8388608;
  bf16* Q = (bf16*)p;   p += 1048576;
  bf16* K = (bf16*)p;   p += 1048576;
  bf16* QT = (bf16*)p;  p += 1048576;
  bf16* KT = (bf16*)p;  p += 1048576;
  bf16* V = (bf16*)p;   p += 8388608;
  bf16* VT = (bf16*)p;  p += 8388608;
  float* MW = (float*)p; p += 262144;   // raw w-dir max
  float* LW = (float*)p; p += 262144;   // raw w-dir sumexp
  float* MH = (float*)p; p += 262144;   // raw h-dir max
  float* LH = (float*)p; p += 262144;   // raw h-dir sumexp
  bf16* OHT = (bf16*)p;  p += 8388608;  // out_h in [b][c][w][h] layout
  float* ACC = (float*)d_out;           // fp32, 16 MB
  float* PS = (float*)Q;     // stats partials (4 KB), Q unused until conv80
  float* GP = (float*)OHT;   // Gram partials (8 MB), OHT free after merges
  float* CATT = (float*)QT;  // reuses QT

  k_pool_conv<<<1024, 256, 0, stream>>>(fbp, (const float*)d_in[2],
                                        (const float*)d_in[3], Y);
  k_stats_p1<<<512, 256, 0, stream>>>(Y, PS);
  k_stats_p2<<<1, 64, 0, stream>>>(PS, (const float*)d_in[4],
                                   (const float*)d_in[5], SCALE, SHIFT,
                                   (const float*)d_in[12], (const float*)d_in[19],
                                   (const float*)d_in[20], (const float*)d_in[21],
                                   (const float*)d_in[22], HDR);

  for (int m = 0; m < 2; ++m) {
    const float *qw, *qb, *kw, *kb, *vw, *vb;
    if (m == 0) {
      qw = (const float*)d_in[6]; qb = (const float*)d_in[7];
      kw = (const float*)d_in[8]; kb = (const float*)d_in[9];
      vw = (const float*)d_in[10]; vb = (const float*)d_in[11];
    } else {
      qw = (const float*)d_in[13]; qb = (const float*)d_in[14];
      kw = (const float*)d_in[15]; kb = (const float*)d_in[16];
      vw = (const float*)d_in[17]; vb = (const float*)d_in[18];
    }
    if (m == 0)
      k_conv80<false><<<1024, 256, 0, stream>>>(x, SCALE, SHIFT, qw, qb, kw, kb,
                                                vw, vb, Q, K, V);
    else
      k_conv80<true><<<1024, 256, 0, stream>>>(Y, SCALE, SHIFT, qw, qb, kw, kb,
                                               vw, vb, Q, K, V);
    // one dispatch transposes Q+K (64 planes, contiguous out) and V (256)
    k_transpose2<<<5120, 256, 0, stream>>>((const u16*)Q, (u16*)QT,
                                           (const u16*)V, (u16*)VT, 64);
    // per-direction stats in one mode-split dispatch (1024 blocks)
    k_qk_stats<<<1024, 256, 0, stream>>>(Q, K, QT, KT, MW, LW, MH, LH);
    // merged out_w + out_h on MFMA (combine in prologue)
    k_av<<<1024, 256, 0, stream>>>(Q, K, V, QT, KT, VT, MW, LW, MH, LH,
                                   ACC, OHT, HDR, 1 + m, m);
    k_merge<<<4096, 256, 0, stream>>>(OHT, ACC, HDR, 1 + m);
  }

  k_gram<<<512, 256, 0, stream>>>(Y, SCALE, SHIFT, GP);
  k_gram_reduce<<<64, 256, 0, stream>>>(GP, CATT);
  k_final<<<1024, 256, 0, stream>>>(x, Y, SCALE, SHIFT, CATT, HDR,
                                    (float*)d_out);
}

// Round 6
// 311.585 us; speedup vs baseline: 1.8270x; 1.1494x over previous
//
#include <hip/hip_runtime.h>
#include <hip/hip_bf16.h>

#define NP 16384   // H*W
#define NB 4

typedef __hip_bfloat16 bf16;
typedef unsigned short u16;
typedef unsigned short us8 __attribute__((ext_vector_type(8)));
typedef short ss8 __attribute__((ext_vector_type(8)));
typedef float f32x4 __attribute__((ext_vector_type(4)));
__device__ __forceinline__ float bf2f(const bf16 v) { return __bfloat162float(v); }
__device__ __forceinline__ bf16 f2bf(float v) { return __float2bfloat16(v); }
__device__ __forceinline__ float bfu(u16 h) {
  return __uint_as_float(((unsigned)h) << 16);
}
__device__ __forceinline__ u16 fbu(float v) {
  bf16 b = f2bf(v);
  return *(u16*)&b;
}

// Inputs/outputs fp32 (reference dtype). Internal tensors bf16, math fp32.
// Workspace layout uses ~107 MB of the 256 MiB d_ws (fill size observed in
// rocprof: WRITE_SIZE = 262144 KB per re-poison).

// ---------------------------------------------------------------------------
// K1: maxpool2x2(fb fp32) -> conv1x1+bias -> Y raw (pre-BN, bf16). 64x64 tile.
// ---------------------------------------------------------------------------
__global__ __launch_bounds__(256) void k_pool_conv(
    const float* __restrict__ fb, const float* __restrict__ wconv,
    const float* __restrict__ bconv, bf16* __restrict__ Y) {
  __shared__ float wS[64 * 65], bS[64], Xs[4096];
  int tid = threadIdx.x;
  int b = blockIdx.x >> 8, tile = blockIdx.x & 255;
  int n0 = tile * 64;
  for (int i = tid; i < 4096; i += 256) wS[(i >> 6) * 65 + (i & 63)] = wconv[i];
  if (tid < 64) bS[tid] = bconv[tid];
  for (int i = tid; i < 4096; i += 256) {
    int c = i >> 6, px = i & 63;
    int n = n0 + px, h = n >> 7, w = n & 127;
    size_t fbase = ((size_t)((b * 64 + c) * 256 + 2 * h)) * 256 + 2 * w;
    float2 v01 = *(const float2*)(fb + fbase);
    float2 v23 = *(const float2*)(fb + fbase + 256);
    Xs[i] = fmaxf(fmaxf(v01.x, v01.y), fmaxf(v23.x, v23.y));
  }
  __syncthreads();
  int ty = tid >> 4, tx = tid & 15;
  float acc[4][4];
#pragma unroll
  for (int i = 0; i < 4; ++i) {
    float bv = bS[ty + 16 * i];
#pragma unroll
    for (int j = 0; j < 4; ++j) acc[i][j] = bv;
  }
  for (int c = 0; c < 64; ++c) {
    float xv[4], wv[4];
#pragma unroll
    for (int j = 0; j < 4; ++j) xv[j] = Xs[c * 64 + tx * 4 + j];
#pragma unroll
    for (int i = 0; i < 4; ++i) wv[i] = wS[(ty + 16 * i) * 65 + c];
#pragma unroll
    for (int i = 0; i < 4; ++i)
#pragma unroll
      for (int j = 0; j < 4; ++j) acc[i][j] = fmaf(wv[i], xv[j], acc[i][j]);
  }
#pragma unroll
  for (int i = 0; i < 4; ++i) {
    int ch = ty + 16 * i;
    bf16* yb = Y + (size_t)(b * 64 + ch) * NP + n0 + tx * 4;
#pragma unroll
    for (int j = 0; j < 4; ++j) yb[j] = f2bf(acc[i][j]);
  }
}

// ---------------------------------------------------------------------------
// K2a: stats stage 1.
// ---------------------------------------------------------------------------
__global__ __launch_bounds__(256) void k_stats_p1(const bf16* __restrict__ Y,
                                                  float* __restrict__ PS) {
  int blk = blockIdx.x, tid = threadIdx.x;
  int o = blk >> 3, slab = blk & 7;
  int b = slab >> 1, half = slab & 1;
  const us8* vp =
      (const us8*)(Y + ((size_t)(b * 64 + o)) * NP + half * 8192);
  float s = 0.f, ss = 0.f;
#pragma unroll
  for (int it = 0; it < 4; ++it) {
    us8 v = vp[tid + 256 * it];
#pragma unroll
    for (int e = 0; e < 8; ++e) {
      float f = bfu(v[e]);
      s += f;
      ss = fmaf(f, f, ss);
    }
  }
  for (int off = 32; off > 0; off >>= 1) {
    s += __shfl_down(s, off, 64);
    ss += __shfl_down(ss, off, 64);
  }
  __shared__ float sh[8];
  int wv = tid >> 6, ln = tid & 63;
  if (ln == 0) { sh[wv] = s; sh[4 + wv] = ss; }
  __syncthreads();
  if (tid == 0) {
    PS[blk] = sh[0] + sh[1] + sh[2] + sh[3];
    PS[512 + blk] = sh[4] + sh[5] + sh[6] + sh[7];
  }
}

// K2b: stats stage 2 + BN scale/shift + scalar header (fused)
__global__ __launch_bounds__(64) void k_stats_p2(
    const float* __restrict__ PS, const float* __restrict__ bng,
    const float* __restrict__ bnb, float* __restrict__ SCALE,
    float* __restrict__ SHIFT, const float* xg, const float* fg,
    const float* pg, const float* pg2, const float* cg,
    float* __restrict__ HDR) {
  int o = threadIdx.x;
  float s = 0.f, ss = 0.f;
#pragma unroll
  for (int k = 0; k < 8; ++k) {
    s += PS[o * 8 + k];
    ss += PS[512 + o * 8 + k];
  }
  const float inv = 1.0f / (NB * NP);
  float mu = s * inv;
  float var = ss * inv - mu * mu;
  float r = rsqrtf(var + 1e-5f);
  float sc = r * bng[o];
  SCALE[o] = sc;
  SHIFT[o] = bnb[o] - mu * sc;
  if (o == 0) {
    float vpg = pg[0];
    HDR[1] = vpg * xg[0];
    HDR[2] = pg2[0] * fg[0];
    HDR[3] = 2.0f + vpg;
    HDR[4] = pg2[0];
    HDR[5] = cg[0];
  }
}

// ---------------------------------------------------------------------------
// K4: both modules' q|k|v conv1x1 in one dispatch. 2048 blocks =
// m(2) x b(4) x tile(256); 80 out-ch x 64 px, 5x4 thread tile.
// QK layout: [m][q/k][b][c8][NP] (128 planes). V: [m][b][c64][NP] (512).
// ---------------------------------------------------------------------------
__global__ __launch_bounds__(256) void k_conv80x2(
    const float* __restrict__ xin, const bf16* __restrict__ Yin,
    const float* __restrict__ SCALE, const float* __restrict__ SHIFT,
    const float* __restrict__ qw0, const float* __restrict__ qb0,
    const float* __restrict__ kw0, const float* __restrict__ kb0,
    const float* __restrict__ vw0, const float* __restrict__ vb0,
    const float* __restrict__ qw1, const float* __restrict__ qb1,
    const float* __restrict__ kw1, const float* __restrict__ kb1,
    const float* __restrict__ vw1, const float* __restrict__ vb1,
    bf16* __restrict__ QK, bf16* __restrict__ V) {
  __shared__ float wS[80 * 65], bS[80];
  __shared__ u16 Xs[4096];
  int tid = threadIdx.x;
  int m = blockIdx.x >> 10;
  int rest = blockIdx.x & 1023;
  int b = rest >> 8, tile = rest & 255;
  int n0 = tile * 64;
  const float* qw = m ? qw1 : qw0;
  const float* qb = m ? qb1 : qb0;
  const float* kw = m ? kw1 : kw0;
  const float* kb = m ? kb1 : kb0;
  const float* vw = m ? vw1 : vw0;
  const float* vb = m ? vb1 : vb0;
  for (int i = tid; i < 512; i += 256) {
    wS[(i >> 6) * 65 + (i & 63)] = qw[i];
    wS[(8 + (i >> 6)) * 65 + (i & 63)] = kw[i];
  }
  for (int i = tid; i < 4096; i += 256)
    wS[(16 + (i >> 6)) * 65 + (i & 63)] = vw[i];
  if (tid < 8) { bS[tid] = qb[tid]; bS[8 + tid] = kb[tid]; }
  if (tid < 64) bS[16 + tid] = vb[tid];
  for (int i = tid; i < 4096; i += 256) {
    int c = i >> 6, px = i & 63;
    size_t idx = (size_t)(b * 64 + c) * NP + n0 + px;
    float v;
    if (m) {
      v = bf2f(Yin[idx]);
      v = fmaf(v, SCALE[c], SHIFT[c]);
      v = fmaxf(v, 0.f);
    } else {
      v = xin[idx];
    }
    Xs[i] = fbu(v);
  }
  __syncthreads();
  int ty = tid >> 4, tx = tid & 15;
  float acc[5][4];
#pragma unroll
  for (int i = 0; i < 5; ++i) {
    float bv = bS[ty + 16 * i];
#pragma unroll
    for (int j = 0; j < 4; ++j) acc[i][j] = bv;
  }
  for (int c = 0; c < 64; ++c) {
    float xv[4], wv[5];
#pragma unroll
    for (int j = 0; j < 4; ++j) xv[j] = bfu(Xs[c * 64 + tx * 4 + j]);
#pragma unroll
    for (int i = 0; i < 5; ++i) wv[i] = wS[(ty + 16 * i) * 65 + c];
#pragma unroll
    for (int i = 0; i < 5; ++i)
#pragma unroll
      for (int j = 0; j < 4; ++j) acc[i][j] = fmaf(wv[i], xv[j], acc[i][j]);
  }
#pragma unroll
  for (int i = 0; i < 5; ++i) {
    int ch = ty + 16 * i;
    bf16* dst;
    size_t base;
    if (ch < 8) {
      dst = QK; base = (size_t)(((m * 2 + 0) * 4 + b) * 8 + ch) * NP;
    } else if (ch < 16) {
      dst = QK; base = (size_t)(((m * 2 + 1) * 4 + b) * 8 + (ch - 8)) * NP;
    } else {
      dst = V; base = (size_t)((m * 4 + b) * 64 + (ch - 16)) * NP;
    }
#pragma unroll
    for (int j = 0; j < 4; ++j) dst[base + n0 + tx * 4 + j] = f2bf(acc[i][j]);
  }
}

// ---------------------------------------------------------------------------
// K5: 128x128 bf16 plane transpose over two tensor pairs in one dispatch.
// planes [0,nA) : inA->outA ; [nA, ...) : inB->outB.
// ---------------------------------------------------------------------------
__global__ __launch_bounds__(256) void k_transpose2(
    const u16* __restrict__ inA, u16* __restrict__ outA,
    const u16* __restrict__ inB, u16* __restrict__ outB, int nA) {
  int tileId = blockIdx.x & 15;
  int plane = blockIdx.x >> 4;
  const u16* ip;
  u16* op;
  if (plane < nA) {
    ip = inA + (size_t)plane * NP;
    op = outA + (size_t)plane * NP;
  } else {
    ip = inB + (size_t)(plane - nA) * NP;
    op = outB + (size_t)(plane - nA) * NP;
  }
  int th = tileId >> 2, tw = tileId & 3;
  __shared__ u16 t[32][33];
  int lx = threadIdx.x & 31, ly = threadIdx.x >> 5;
  for (int i = 0; i < 32; i += 8)
    t[ly + i][lx] = ip[(size_t)(th * 32 + ly + i) * 128 + tw * 32 + lx];
  __syncthreads();
  for (int i = 0; i < 32; i += 8)
    op[(size_t)(tw * 32 + ly + i) * 128 + th * 32 + lx] = t[lx][ly + i];
}

// ---------------------------------------------------------------------------
// K6: per-direction softmax stats, both modules + modes in one dispatch
// (2048 blocks). Scores register-cached (scr[64], fully unrolled) so the
// sumexp pass reuses them instead of recomputing the 8-FMA dots.
// mode0: e_w rows (no mask) -> MW/LW ; mode1: e_h rows (diag mask) -> MH/LH.
// ---------------------------------------------------------------------------
__global__ __launch_bounds__(256) void k_qk_stats(
    const bf16* __restrict__ QK, const bf16* __restrict__ QKT,
    float* __restrict__ MW, float* __restrict__ LW,
    float* __restrict__ MH, float* __restrict__ LH) {
  int blk = blockIdx.x;
  int m = blk & 1, mode = (blk >> 1) & 1;
  int bid = blk >> 2;
  int b = bid >> 7, pl = bid & 127;
  const bf16* basep = mode ? QKT : QK;
  const bf16* Qp = basep + (size_t)(((m * 2 + 0) * 4 + b) * 8) * NP;
  const bf16* Kp = basep + (size_t)(((m * 2 + 1) * 4 + b) * 8) * NP;
  float* Mo = (mode ? MH : MW) + (size_t)(m * 4 + b) * NP;
  float* Lo = (mode ? LH : LW) + (size_t)(m * 4 + b) * NP;
  __shared__ float qs[1024], ks[1024], red[256];
  int tid = threadIdx.x;
  for (int i = tid; i < 1024; i += 256) {
    int c = i >> 7, j = i & 127;
    qs[i] = bf2f(Qp[(size_t)c * NP + (size_t)pl * 128 + j]);
    ks[i] = bf2f(Kp[(size_t)c * NP + (size_t)pl * 128 + j]);
  }
  __syncthreads();
  int w = tid & 127, half = tid >> 7;
  float qr[8];
#pragma unroll
  for (int c = 0; c < 8; ++c) qr[c] = qs[c * 128 + w];
  float scr[64];
  float mx = -3.0e38f;
#pragma unroll
  for (int v0 = 0; v0 < 64; ++v0) {
    int v = half * 64 + v0;
    float s = 0.f;
#pragma unroll
    for (int c = 0; c < 8; ++c) s = fmaf(qr[c], ks[c * 128 + v], s);
    if (mode && v == w) s = -1.0e30f;
    scr[v0] = s;
    mx = fmaxf(mx, s);
  }
  red[tid] = mx;
  __syncthreads();
  float mj = fmaxf(red[w], red[128 + w]);
  __syncthreads();
  float l = 0.f;
#pragma unroll
  for (int v0 = 0; v0 < 64; ++v0) l += __expf(scr[v0] - mj);
  red[tid] = l;
  __syncthreads();
  if (half == 0) {
    Mo[(size_t)pl * 128 + w] = mj;
    Lo[(size_t)pl * 128 + w] = red[w] + red[128 + w];
  }
}

// ---------------------------------------------------------------------------
// K7: out_w + out_h, both modules, on MFMA. 2048 blocks = (b,h) x mode x m;
// 256 thr. Prologue combines per-direction stats. Outputs are pure stores:
// mode0 -> OW[m] (fp32, [c][h][w] contiguous), mode1 -> OHT[m] (bf16,
// [c][w][h]). No ACC RMW; scaling deferred to k_merge2/k_final.
// ---------------------------------------------------------------------------
__global__ __launch_bounds__(256, 4) void k_av(
    const bf16* __restrict__ QK, const bf16* __restrict__ QKT,
    const bf16* __restrict__ V, const bf16* __restrict__ VT,
    const float* __restrict__ MW, const float* __restrict__ LW,
    const float* __restrict__ MH, const float* __restrict__ LH,
    float* __restrict__ OW, bf16* __restrict__ OHT) {
  int blk = blockIdx.x;
  int m = blk & 1, mode = (blk >> 1) & 1;
  int bid = blk >> 2;
  int b = bid >> 7, h = bid & 127;
  const bf16* qkbase = mode ? QKT : QK;
  const bf16* Qp = qkbase + (size_t)(((m * 2 + 0) * 4 + b) * 8) * NP;
  const bf16* Kp = qkbase + (size_t)(((m * 2 + 1) * 4 + b) * 8) * NP;
  const bf16* Vp = (mode ? VT : V) + (size_t)((m * 4 + b) * 64) * NP;
  __shared__ __align__(16) u16 qT[128 * 8];    // [p(j)][c]
  __shared__ __align__(16) u16 kT[128 * 8];    // [p(j)][c]
  __shared__ __align__(16) u16 Vs[64 * 136];   // [c][j], pad 136
  __shared__ float Ml[128], Li[128];
  int tid = threadIdx.x;
  {  // q (tid<128) / k (tid>=128): 1024 u16 each, one us8 load per thread
    int c = (tid >> 4) & 7, vj = tid & 15;
    const bf16* src = (tid < 128) ? Qp : Kp;
    u16* dst = (tid < 128) ? qT : kT;
    const us8* sp = (const us8*)(src + (size_t)c * NP + (size_t)h * 128);
    us8 sv = sp[vj];
#pragma unroll
    for (int e = 0; e < 8; ++e) {
      int j = vj * 8 + e;
      int p = ((j & 7) << 4) | (j >> 3);
      dst[p * 8 + c] = sv[e];
    }
  }
  for (int i2 = tid; i2 < 1024; i2 += 256) {  // V: 8192 u16, b128 writes
    int c = i2 >> 4, vj = i2 & 15;
    const us8* vp = (const us8*)(Vp + (size_t)c * NP + (size_t)h * 128);
    us8 vv = vp[vj];
    *(us8*)&Vs[c * 136 + vj * 8] = vv;
  }
  if (tid < 128) {  // combine the two direction stats for this plane's pixels
    size_t sb = (size_t)(m * 4 + b) * NP;
    const float* Mc = mode ? MH : MW;   // this plane's direction (contiguous)
    const float* Lc = mode ? LH : LW;
    const float* Ms = mode ? MW : MH;   // other direction (strided)
    const float* Ls = mode ? LW : LH;
    float mc = Mc[sb + (size_t)h * 128 + tid];
    float lc = Lc[sb + (size_t)h * 128 + tid];
    float ms = Ms[sb + (size_t)tid * 128 + h];
    float ls = Ls[sb + (size_t)tid * 128 + h];
    float mm = fmaxf(mc, ms);
    float ll = lc * __expf(mc - mm) + ls * __expf(ms - mm);
    Ml[tid] = mm;
    Li[tid] = 1.0f / ll;
  }
  __syncthreads();
  int lane = tid & 63, wv = tid >> 6;   // wave wv owns rows [wv*32, wv*32+32)
  int il = lane & 15, gq = lane >> 4;
  float* owBase = OW + (size_t)((m * 4 + b) * 64) * NP + (size_t)h * 128;
  bf16* ohBase = OHT + (size_t)((m * 4 + b) * 64) * NP + (size_t)h * 128;
#pragma unroll
  for (int sub = 0; sub < 2; ++sub) {
    int ib = wv * 32 + sub * 16;
    int i = ib + il;                 // this lane's A-row
    float mv = Ml[i], li = Li[i];
    int pi = ((i & 7) << 4) | (i >> 3);
    us8 qv = *(const us8*)&qT[pi * 8];
    float qr[8];
#pragma unroll
    for (int c = 0; c < 8; ++c) qr[c] = bfu(qv[c]);
    ss8 afr[4];
#pragma unroll
    for (int ks = 0; ks < 4; ++ks) {
      ss8 af;
#pragma unroll
      for (int e = 0; e < 8; ++e) {
        int j = ks * 32 + gq * 8 + e;
        int pj = ((j & 7) << 4) | (j >> 3);
        us8 kv = *(const us8*)&kT[pj * 8];
        float s = 0.f;
#pragma unroll
        for (int c = 0; c < 8; ++c) s = fmaf(qr[c], bfu(kv[c]), s);
        float ev = __expf(s - mv) * li;
        if (mode && j == i) ev = 0.f;
        af[e] = (short)fbu(ev);
      }
      afr[ks] = af;
    }
#pragma unroll
    for (int ct = 0; ct < 4; ++ct) {
      f32x4 acc = {0.f, 0.f, 0.f, 0.f};
#pragma unroll
      for (int ks = 0; ks < 4; ++ks) {
        ss8 bv = *(const ss8*)&Vs[(ct * 16 + il) * 136 + ks * 32 + gq * 8];
        acc = __builtin_amdgcn_mfma_f32_16x16x32_bf16(afr[ks], bv, acc, 0, 0, 0);
      }
      int cch = ct * 16 + il;        // D col = channel
      int i0 = ib + gq * 4;          // D rows = 4 consecutive pixels
      if (mode == 0) {
#pragma unroll
        for (int r = 0; r < 4; ++r)
          owBase[(size_t)cch * NP + (size_t)(i0 + r)] = acc[r];
      } else {
#pragma unroll
        for (int r = 0; r < 4; ++r)
          ohBase[(size_t)cch * NP + (size_t)(i0 + r)] = f2bf(acc[r]);
      }
    }
  }
}

// ---------------------------------------------------------------------------
// K8: dual transpose-store: ACC[b][c][h][w] = sc0*OHT0^T + sc1*OHT1^T.
// Pure store (replaces two RMW merge passes). 4096 blocks.
// ---------------------------------------------------------------------------
__global__ __launch_bounds__(256) void k_merge2(const bf16* __restrict__ OHT,
                                                float* __restrict__ ACC,
                                                const float* __restrict__ HDR) {
  int tileId = blockIdx.x & 15;
  int plane = blockIdx.x >> 4;      // 0..255 = b*64+c
  int th = tileId >> 2, tw = tileId & 3;
  __shared__ float t0[32][33], t1[32][33];
  int lx = threadIdx.x & 31, ly = threadIdx.x >> 5;
  const bf16* ip0 = OHT + (size_t)plane * NP;
  const bf16* ip1 = OHT + (size_t)(256 + plane) * NP;
  for (int i = 0; i < 32; i += 8) {
    size_t idx = (size_t)(th * 32 + ly + i) * 128 + tw * 32 + lx;
    t0[ly + i][lx] = bf2f(ip0[idx]);
    t1[ly + i][lx] = bf2f(ip1[idx]);
  }
  __syncthreads();
  float sc0 = HDR[1], sc1 = HDR[2];
  float* op = ACC + (size_t)plane * NP;
  for (int i = 0; i < 32; i += 8) {
    int h = tw * 32 + ly + i, w = th * 32 + lx;
    op[(size_t)h * 128 + w] = sc0 * t0[lx][ly + i] + sc1 * t1[lx][ly + i];
  }
}

// ---------------------------------------------------------------------------
// K9: partial Gram of y=BN(Y). 512 blocks = b x ch x t.
// ---------------------------------------------------------------------------
__global__ __launch_bounds__(256) void k_gram(const bf16* __restrict__ Y,
                                              const float* __restrict__ SCALE,
                                              const float* __restrict__ SHIFT,
                                              float* __restrict__ GP) {
  int b = blockIdx.x >> 7, ch = (blockIdx.x >> 2) & 31, t = blockIdx.x & 3;
  int tid = threadIdx.x;
  __shared__ float fs[64 * 129];
  int cg = tid >> 4, dg = tid & 15;
  float acc[4][4];
#pragma unroll
  for (int i = 0; i < 4; ++i)
#pragma unroll
    for (int jx = 0; jx < 4; ++jx) acc[i][jx] = 0.f;
  const bf16* yb = Y + (size_t)b * 64 * NP + ch * 512;
  for (int idx = tid; idx < 8192; idx += 256) {
    int c = idx >> 7, j = idx & 127;
    float v = fmaf(bf2f(yb[(size_t)c * NP + t * 128 + j]), SCALE[c], SHIFT[c]);
    fs[c * 129 + j] = fmaxf(v, 0.f);
  }
  __syncthreads();
  for (int j = 0; j < 128; ++j) {
    float a[4], d[4];
#pragma unroll
    for (int i = 0; i < 4; ++i) a[i] = fs[(cg * 4 + i) * 129 + j];
#pragma unroll
    for (int i = 0; i < 4; ++i) d[i] = fs[(dg * 4 + i) * 129 + j];
#pragma unroll
    for (int i = 0; i < 4; ++i)
#pragma unroll
      for (int jx = 0; jx < 4; ++jx) acc[i][jx] = fmaf(a[i], d[jx], acc[i][jx]);
  }
  float* gp = GP + ((size_t)(b * 128) + ch * 4 + t) * 4096;
#pragma unroll
  for (int i = 0; i < 4; ++i)
#pragma unroll
    for (int jx = 0; jx < 4; ++jx)
      gp[(cg * 4 + i) * 64 + dg * 4 + jx] = acc[i][jx];
}

// K10: reduce 128 Gram partials; row softmax of (max-E). 64 blocks.
__global__ __launch_bounds__(256) void k_gram_reduce(const float* __restrict__ GP,
                                                     float* __restrict__ CATT) {
  int b = blockIdx.x >> 4, rg = blockIdx.x & 15;
  int tid = threadIdx.x;
  __shared__ float Es[256];
  int e = rg * 256 + tid;
  float s = 0.f;
  for (int k = 0; k < 128; ++k) s += GP[((size_t)b * 128 + k) * 4096 + e];
  Es[tid] = s;
  __syncthreads();
  int wv = tid >> 6, ln = tid & 63;
  float v = Es[wv * 64 + ln];
  float mn = v;
  for (int off = 32; off; off >>= 1) mn = fminf(mn, __shfl_xor(mn, off, 64));
  float ev = __expf(mn - v);
  float ssum = ev;
  for (int off = 32; off; off >>= 1) ssum += __shfl_xor(ssum, off, 64);
  CATT[((size_t)b * 64 + rg * 4 + wv) * 64 + ln] = ev / ssum;
}

// ---------------------------------------------------------------------------
// K11: out = (2+pg)*x + pg2*y + ACC + sc0*OW0 + sc1*OW1 + cg*(catt@y).
// ACC (= d_out) holds the merged OHT contributions; in-place RMW.
// ---------------------------------------------------------------------------
__global__ __launch_bounds__(256) void k_final(
    const float* __restrict__ x, const bf16* __restrict__ Y,
    const float* __restrict__ SCALE, const float* __restrict__ SHIFT,
    const float* __restrict__ CATT, const float* __restrict__ OW,
    const float* __restrict__ HDR, float* __restrict__ OUT) {
  __shared__ float attS[64 * 65], Ys[64 * 65];
  int tid = threadIdx.x;
  int b = blockIdx.x >> 8, tile = blockIdx.x & 255;
  int n0 = tile * 64;
  for (int i = tid; i < 4096; i += 256)
    attS[(i >> 6) * 65 + (i & 63)] = CATT[(size_t)b * 4096 + i];
  for (int i = tid; i < 4096; i += 256) {
    int d = i >> 6, px = i & 63;
    float v = fmaf(bf2f(Y[(size_t)(b * 64 + d) * NP + n0 + px]), SCALE[d], SHIFT[d]);
    Ys[d * 65 + px] = fmaxf(v, 0.f);
  }
  __syncthreads();
  int cg = tid >> 4, pgx = tid & 15;
  int c0 = cg * 4, p0 = pgx * 4;
  float acc[4][4];
#pragma unroll
  for (int i = 0; i < 4; ++i)
#pragma unroll
    for (int j = 0; j < 4; ++j) acc[i][j] = 0.f;
  for (int d = 0; d < 64; ++d) {
    float a[4], yv[4];
#pragma unroll
    for (int i = 0; i < 4; ++i) a[i] = attS[(c0 + i) * 65 + d];
#pragma unroll
    for (int j = 0; j < 4; ++j) yv[j] = Ys[d * 65 + p0 + j];
#pragma unroll
    for (int i = 0; i < 4; ++i)
#pragma unroll
      for (int j = 0; j < 4; ++j) acc[i][j] = fmaf(a[i], yv[j], acc[i][j]);
  }
  float c2pg = HDR[3], fpg2 = HDR[4], fcg = HDR[5];
  float sc0 = HDR[1], sc1 = HDR[2];
#pragma unroll
  for (int i = 0; i < 4; ++i) {
    size_t base = (size_t)(b * 64 + c0 + i) * NP + n0 + p0;
    const float* ow0 = OW + base;
    const float* ow1 = OW + (size_t)256 * NP + base;
#pragma unroll
    for (int j = 0; j < 4; ++j) {
      float yv = Ys[(c0 + i) * 65 + p0 + j];
      OUT[base + j] = c2pg * x[base + j] + fpg2 * yv + OUT[base + j] +
                      fcg * acc[i][j] + sc0 * ow0[j] + sc1 * ow1[j];
    }
  }
}

// ---------------------------------------------------------------------------
extern "C" void kernel_launch(void* const* d_in, const int* in_sizes, int n_in,
                              void* d_out, int out_size, void* d_ws, size_t ws_size,
                              hipStream_t stream) {
  const float* x = (const float*)d_in[0];
  const float* fbp = (const float*)d_in[1];

  // ~107 MB of the 256 MiB workspace.
  char* base = (char*)d_ws;
  float* HDR = (float*)base;
  float* SCALE = HDR + 16;
  float* SHIFT = SCALE + 64;
  char* p = base + 4096;
  bf16* Y = (bf16*)p;    p += 8388608;   // [4][64][NP]
  bf16* QK = (bf16*)p;   p += 4194304;   // [m][q/k][4][8][NP] = 128 planes
  bf16* QKT = (bf16*)p;  p += 4194304;
  bf16* V = (bf16*)p;    p += 16777216;  // [m][4][64][NP] = 512 planes
  bf16* VT = (bf16*)p;   p += 16777216;
  float* MW = (float*)p; p += 524288;    // [m][4][NP]
  float* LW = (float*)p; p += 524288;
  float* MH = (float*)p; p += 524288;
  float* LH = (float*)p; p += 524288;
  bf16* OHT = (bf16*)p;  p += 16777216;  // [m][4][64][NP] (out_h, [c][w][h])
  float* OW = (float*)p; p += 33554432;  // [m][4][64][NP] fp32 (out_w)
  float* GP = (float*)p; p += 8388608;   // Gram partials
  float* CATT = (float*)p; p += 1048576;
  float* ACC = (float*)d_out;
  float* PS = (float*)QK;  // stats partials (4 KB), QK unused until conv

  k_pool_conv<<<1024, 256, 0, stream>>>(fbp, (const float*)d_in[2],
                                        (const float*)d_in[3], Y);
  k_stats_p1<<<512, 256, 0, stream>>>(Y, PS);
  k_stats_p2<<<1, 64, 0, stream>>>(PS, (const float*)d_in[4],
                                   (const float*)d_in[5], SCALE, SHIFT,
                                   (const float*)d_in[12], (const float*)d_in[19],
                                   (const float*)d_in[20], (const float*)d_in[21],
                                   (const float*)d_in[22], HDR);

  // both modules in each dispatch
  k_conv80x2<<<2048, 256, 0, stream>>>(
      x, Y, SCALE, SHIFT,
      (const float*)d_in[6], (const float*)d_in[7], (const float*)d_in[8],
      (const float*)d_in[9], (const float*)d_in[10], (const float*)d_in[11],
      (const float*)d_in[13], (const float*)d_in[14], (const float*)d_in[15],
      (const float*)d_in[16], (const float*)d_in[17], (const float*)d_in[18],
      QK, V);
  k_transpose2<<<10240, 256, 0, stream>>>((const u16*)QK, (u16*)QKT,
                                          (const u16*)V, (u16*)VT, 128);
  k_qk_stats<<<2048, 256, 0, stream>>>(QK, QKT, MW, LW, MH, LH);
  k_av<<<2048, 256, 0, stream>>>(QK, QKT, V, VT, MW, LW, MH, LH, OW, OHT);
  k_merge2<<<4096, 256, 0, stream>>>(OHT, ACC, HDR);

  k_gram<<<512, 256, 0, stream>>>(Y, SCALE, SHIFT, GP);
  k_gram_reduce<<<64, 256, 0, stream>>>(GP, CATT);
  k_final<<<1024, 256, 0, stream>>>(x, Y, SCALE, SHIFT, CATT, OW, HDR,
                                    (float*)d_out);
}

// Round 7
// 301.315 us; speedup vs baseline: 1.8893x; 1.0341x over previous
//
#include <hip/hip_runtime.h>
#include <hip/hip_bf16.h>

#define NP 16384   // H*W
#define NB 4

typedef __hip_bfloat16 bf16;
typedef unsigned short u16;
typedef unsigned short us8 __attribute__((ext_vector_type(8)));
typedef short ss8 __attribute__((ext_vector_type(8)));
typedef float f32x4 __attribute__((ext_vector_type(4)));
__device__ __forceinline__ float bf2f(const bf16 v) { return __bfloat162float(v); }
__device__ __forceinline__ bf16 f2bf(float v) { return __float2bfloat16(v); }
__device__ __forceinline__ float bfu(u16 h) {
  return __uint_as_float(((unsigned)h) << 16);
}
__device__ __forceinline__ u16 fbu(float v) {
  bf16 b = f2bf(v);
  return *(u16*)&b;
}

// Inputs/outputs fp32 (reference dtype). Internal tensors bf16, math fp32.
// Flash-style decomposition: each direction computes its own (m, l) stats and
// unnormalized output; k_merge2 combines with alpha/beta rescaling (exact).

// ---------------------------------------------------------------------------
// K1: maxpool2x2(fb fp32) -> conv1x1+bias -> Y raw (pre-BN, bf16). 64x64 tile.
// ---------------------------------------------------------------------------
__global__ __launch_bounds__(256) void k_pool_conv(
    const float* __restrict__ fb, const float* __restrict__ wconv,
    const float* __restrict__ bconv, bf16* __restrict__ Y) {
  __shared__ float wS[64 * 65], bS[64], Xs[4096];
  int tid = threadIdx.x;
  int b = blockIdx.x >> 8, tile = blockIdx.x & 255;
  int n0 = tile * 64;
  for (int i = tid; i < 4096; i += 256) wS[(i >> 6) * 65 + (i & 63)] = wconv[i];
  if (tid < 64) bS[tid] = bconv[tid];
  for (int i = tid; i < 4096; i += 256) {
    int c = i >> 6, px = i & 63;
    int n = n0 + px, h = n >> 7, w = n & 127;
    size_t fbase = ((size_t)((b * 64 + c) * 256 + 2 * h)) * 256 + 2 * w;
    float2 v01 = *(const float2*)(fb + fbase);
    float2 v23 = *(const float2*)(fb + fbase + 256);
    Xs[i] = fmaxf(fmaxf(v01.x, v01.y), fmaxf(v23.x, v23.y));
  }
  __syncthreads();
  int ty = tid >> 4, tx = tid & 15;
  float acc[4][4];
#pragma unroll
  for (int i = 0; i < 4; ++i) {
    float bv = bS[ty + 16 * i];
#pragma unroll
    for (int j = 0; j < 4; ++j) acc[i][j] = bv;
  }
  for (int c = 0; c < 64; ++c) {
    float xv[4], wv[4];
#pragma unroll
    for (int j = 0; j < 4; ++j) xv[j] = Xs[c * 64 + tx * 4 + j];
#pragma unroll
    for (int i = 0; i < 4; ++i) wv[i] = wS[(ty + 16 * i) * 65 + c];
#pragma unroll
    for (int i = 0; i < 4; ++i)
#pragma unroll
      for (int j = 0; j < 4; ++j) acc[i][j] = fmaf(wv[i], xv[j], acc[i][j]);
  }
#pragma unroll
  for (int i = 0; i < 4; ++i) {
    int ch = ty + 16 * i;
    bf16* yb = Y + (size_t)(b * 64 + ch) * NP + n0 + tx * 4;
#pragma unroll
    for (int j = 0; j < 4; ++j) yb[j] = f2bf(acc[i][j]);
  }
}

// ---------------------------------------------------------------------------
// K2a: stats stage 1.
// ---------------------------------------------------------------------------
__global__ __launch_bounds__(256) void k_stats_p1(const bf16* __restrict__ Y,
                                                  float* __restrict__ PS) {
  int blk = blockIdx.x, tid = threadIdx.x;
  int o = blk >> 3, slab = blk & 7;
  int b = slab >> 1, half = slab & 1;
  const us8* vp =
      (const us8*)(Y + ((size_t)(b * 64 + o)) * NP + half * 8192);
  float s = 0.f, ss = 0.f;
#pragma unroll
  for (int it = 0; it < 4; ++it) {
    us8 v = vp[tid + 256 * it];
#pragma unroll
    for (int e = 0; e < 8; ++e) {
      float f = bfu(v[e]);
      s += f;
      ss = fmaf(f, f, ss);
    }
  }
  for (int off = 32; off > 0; off >>= 1) {
    s += __shfl_down(s, off, 64);
    ss += __shfl_down(ss, off, 64);
  }
  __shared__ float sh[8];
  int wv = tid >> 6, ln = tid & 63;
  if (ln == 0) { sh[wv] = s; sh[4 + wv] = ss; }
  __syncthreads();
  if (tid == 0) {
    PS[blk] = sh[0] + sh[1] + sh[2] + sh[3];
    PS[512 + blk] = sh[4] + sh[5] + sh[6] + sh[7];
  }
}

// K2b: stats stage 2 + BN scale/shift + scalar header (fused)
__global__ __launch_bounds__(64) void k_stats_p2(
    const float* __restrict__ PS, const float* __restrict__ bng,
    const float* __restrict__ bnb, float* __restrict__ SCALE,
    float* __restrict__ SHIFT, const float* xg, const float* fg,
    const float* pg, const float* pg2, const float* cg,
    float* __restrict__ HDR) {
  int o = threadIdx.x;
  float s = 0.f, ss = 0.f;
#pragma unroll
  for (int k = 0; k < 8; ++k) {
    s += PS[o * 8 + k];
    ss += PS[512 + o * 8 + k];
  }
  const float inv = 1.0f / (NB * NP);
  float mu = s * inv;
  float var = ss * inv - mu * mu;
  float r = rsqrtf(var + 1e-5f);
  float sc = r * bng[o];
  SCALE[o] = sc;
  SHIFT[o] = bnb[o] - mu * sc;
  if (o == 0) {
    float vpg = pg[0];
    HDR[1] = vpg * xg[0];
    HDR[2] = pg2[0] * fg[0];
    HDR[3] = 2.0f + vpg;
    HDR[4] = pg2[0];
    HDR[5] = cg[0];
  }
}

// ---------------------------------------------------------------------------
// K4: both modules' q|k|v conv1x1 in one dispatch. 2048 blocks =
// m(2) x b(4) x tile(256); 80 out-ch x 64 px, 5x4 thread tile.
// QK layout: [m][q/k][b][c8][NP] (128 planes). V: [m][b][c64][NP] (512).
// ---------------------------------------------------------------------------
__global__ __launch_bounds__(256) void k_conv80x2(
    const float* __restrict__ xin, const bf16* __restrict__ Yin,
    const float* __restrict__ SCALE, const float* __restrict__ SHIFT,
    const float* __restrict__ qw0, const float* __restrict__ qb0,
    const float* __restrict__ kw0, const float* __restrict__ kb0,
    const float* __restrict__ vw0, const float* __restrict__ vb0,
    const float* __restrict__ qw1, const float* __restrict__ qb1,
    const float* __restrict__ kw1, const float* __restrict__ kb1,
    const float* __restrict__ vw1, const float* __restrict__ vb1,
    bf16* __restrict__ QK, bf16* __restrict__ V) {
  __shared__ float wS[80 * 65], bS[80];
  __shared__ u16 Xs[4096];
  int tid = threadIdx.x;
  int m = blockIdx.x >> 10;
  int rest = blockIdx.x & 1023;
  int b = rest >> 8, tile = rest & 255;
  int n0 = tile * 64;
  const float* qw = m ? qw1 : qw0;
  const float* qb = m ? qb1 : qb0;
  const float* kw = m ? kw1 : kw0;
  const float* kb = m ? kb1 : kb0;
  const float* vw = m ? vw1 : vw0;
  const float* vb = m ? vb1 : vb0;
  for (int i = tid; i < 512; i += 256) {
    wS[(i >> 6) * 65 + (i & 63)] = qw[i];
    wS[(8 + (i >> 6)) * 65 + (i & 63)] = kw[i];
  }
  for (int i = tid; i < 4096; i += 256)
    wS[(16 + (i >> 6)) * 65 + (i & 63)] = vw[i];
  if (tid < 8) { bS[tid] = qb[tid]; bS[8 + tid] = kb[tid]; }
  if (tid < 64) bS[16 + tid] = vb[tid];
  for (int i = tid; i < 4096; i += 256) {
    int c = i >> 6, px = i & 63;
    size_t idx = (size_t)(b * 64 + c) * NP + n0 + px;
    float v;
    if (m) {
      v = bf2f(Yin[idx]);
      v = fmaf(v, SCALE[c], SHIFT[c]);
      v = fmaxf(v, 0.f);
    } else {
      v = xin[idx];
    }
    Xs[i] = fbu(v);
  }
  __syncthreads();
  int ty = tid >> 4, tx = tid & 15;
  float acc[5][4];
#pragma unroll
  for (int i = 0; i < 5; ++i) {
    float bv = bS[ty + 16 * i];
#pragma unroll
    for (int j = 0; j < 4; ++j) acc[i][j] = bv;
  }
  for (int c = 0; c < 64; ++c) {
    float xv[4], wv[5];
#pragma unroll
    for (int j = 0; j < 4; ++j) xv[j] = bfu(Xs[c * 64 + tx * 4 + j]);
#pragma unroll
    for (int i = 0; i < 5; ++i) wv[i] = wS[(ty + 16 * i) * 65 + c];
#pragma unroll
    for (int i = 0; i < 5; ++i)
#pragma unroll
      for (int j = 0; j < 4; ++j) acc[i][j] = fmaf(wv[i], xv[j], acc[i][j]);
  }
#pragma unroll
  for (int i = 0; i < 5; ++i) {
    int ch = ty + 16 * i;
    bf16* dst;
    size_t base;
    if (ch < 8) {
      dst = QK; base = (size_t)(((m * 2 + 0) * 4 + b) * 8 + ch) * NP;
    } else if (ch < 16) {
      dst = QK; base = (size_t)(((m * 2 + 1) * 4 + b) * 8 + (ch - 8)) * NP;
    } else {
      dst = V; base = (size_t)((m * 4 + b) * 64 + (ch - 16)) * NP;
    }
#pragma unroll
    for (int j = 0; j < 4; ++j) dst[base + n0 + tx * 4 + j] = f2bf(acc[i][j]);
  }
}

// ---------------------------------------------------------------------------
// K5: 128x128 bf16 plane transpose over two tensor pairs in one dispatch.
// ---------------------------------------------------------------------------
__global__ __launch_bounds__(256) void k_transpose2(
    const u16* __restrict__ inA, u16* __restrict__ outA,
    const u16* __restrict__ inB, u16* __restrict__ outB, int nA) {
  int tileId = blockIdx.x & 15;
  int plane = blockIdx.x >> 4;
  const u16* ip;
  u16* op;
  if (plane < nA) {
    ip = inA + (size_t)plane * NP;
    op = outA + (size_t)plane * NP;
  } else {
    ip = inB + (size_t)(plane - nA) * NP;
    op = outB + (size_t)(plane - nA) * NP;
  }
  int th = tileId >> 2, tw = tileId & 3;
  __shared__ u16 t[32][33];
  int lx = threadIdx.x & 31, ly = threadIdx.x >> 5;
  for (int i = 0; i < 32; i += 8)
    t[ly + i][lx] = ip[(size_t)(th * 32 + ly + i) * 128 + tw * 32 + lx];
  __syncthreads();
  for (int i = 0; i < 32; i += 8)
    op[(size_t)(tw * 32 + ly + i) * 128 + th * 32 + lx] = t[lx][ly + i];
}

// ---------------------------------------------------------------------------
// K7: out_w + out_h, both modules, on MFMA, flash-style. 2048 blocks =
// (b,h) x mode x m; 256 thr. Scores computed ONCE into registers; per-row
// max/sumexp via shfl_xor across the 4 gq-sibling lanes (xor 16/32).
// Outputs UNNORMALIZED: mode0 -> OW (fp32 [c][h][w]) + MWp/LWp stats,
// mode1 -> OHT (bf16 [c][w][h]) + MHp/LHp stats (stored [h][w]-oriented).
// No stats pre-pass, no normalization here -> k_merge2 combines exactly.
// ---------------------------------------------------------------------------
__global__ __launch_bounds__(256, 4) void k_av(
    const bf16* __restrict__ QK, const bf16* __restrict__ QKT,
    const bf16* __restrict__ V, const bf16* __restrict__ VT,
    float* __restrict__ MWp, float* __restrict__ LWp,
    float* __restrict__ MHp, float* __restrict__ LHp,
    float* __restrict__ OW, bf16* __restrict__ OHT) {
  int blk = blockIdx.x;
  int m = blk & 1, mode = (blk >> 1) & 1;
  int bid = blk >> 2;
  int b = bid >> 7, h = bid & 127;
  const bf16* qkbase = mode ? QKT : QK;
  const bf16* Qp = qkbase + (size_t)(((m * 2 + 0) * 4 + b) * 8) * NP;
  const bf16* Kp = qkbase + (size_t)(((m * 2 + 1) * 4 + b) * 8) * NP;
  const bf16* Vp = (mode ? VT : V) + (size_t)((m * 4 + b) * 64) * NP;
  __shared__ __align__(16) u16 qT[128 * 8];    // [p(j)][c]
  __shared__ __align__(16) u16 kT[128 * 8];    // [p(j)][c]
  __shared__ __align__(16) u16 Vs[64 * 136];   // [c][j], pad 136
  int tid = threadIdx.x;
  {  // q (tid<128) / k (tid>=128): 1024 u16 each, one us8 load per thread
    int c = (tid >> 4) & 7, vj = tid & 15;
    const bf16* src = (tid < 128) ? Qp : Kp;
    u16* dst = (tid < 128) ? qT : kT;
    const us8* sp = (const us8*)(src + (size_t)c * NP + (size_t)h * 128);
    us8 sv = sp[vj];
#pragma unroll
    for (int e = 0; e < 8; ++e) {
      int j = vj * 8 + e;
      int p = ((j & 7) << 4) | (j >> 3);
      dst[p * 8 + c] = sv[e];
    }
  }
  for (int i2 = tid; i2 < 1024; i2 += 256) {  // V: 8192 u16, b128 writes
    int c = i2 >> 4, vj = i2 & 15;
    const us8* vp = (const us8*)(Vp + (size_t)c * NP + (size_t)h * 128);
    us8 vv = vp[vj];
    *(us8*)&Vs[c * 136 + vj * 8] = vv;
  }
  __syncthreads();
  int lane = tid & 63, wv = tid >> 6;   // wave wv owns rows [wv*32, wv*32+32)
  int il = lane & 15, gq = lane >> 4;
  size_t sb = (size_t)(m * 4 + b) * NP;
  float* owBase = OW + (size_t)((m * 4 + b) * 64) * NP + (size_t)h * 128;
  bf16* ohBase = OHT + (size_t)((m * 4 + b) * 64) * NP + (size_t)h * 128;
#pragma unroll
  for (int sub = 0; sub < 2; ++sub) {
    int ib = wv * 32 + sub * 16;
    int i = ib + il;                 // this lane's A-row (pixel index)
    int pi = ((i & 7) << 4) | (i >> 3);
    us8 qv = *(const us8*)&qT[pi * 8];
    float qr[8];
#pragma unroll
    for (int c = 0; c < 8; ++c) qr[c] = bfu(qv[c]);
    float scr[4][8];
    float mrow = -3.0e38f;
#pragma unroll
    for (int ks = 0; ks < 4; ++ks) {
#pragma unroll
      for (int e = 0; e < 8; ++e) {
        int j = ks * 32 + gq * 8 + e;
        int pj = ((j & 7) << 4) | (j >> 3);
        us8 kv = *(const us8*)&kT[pj * 8];
        float s = 0.f;
#pragma unroll
        for (int c = 0; c < 8; ++c) s = fmaf(qr[c], bfu(kv[c]), s);
        if (mode && j == i) s = -1.0e30f;   // diag mask (exp underflows to 0)
        scr[ks][e] = s;
        mrow = fmaxf(mrow, s);
      }
    }
    // row-reduce across the 4 gq siblings (lanes il, il+16, il+32, il+48)
    mrow = fmaxf(mrow, __shfl_xor(mrow, 16, 64));
    mrow = fmaxf(mrow, __shfl_xor(mrow, 32, 64));
    float l = 0.f;
    ss8 afr[4];
#pragma unroll
    for (int ks = 0; ks < 4; ++ks) {
      ss8 af;
#pragma unroll
      for (int e = 0; e < 8; ++e) {
        float ev = __expf(scr[ks][e] - mrow);
        l += ev;
        af[e] = (short)fbu(ev);
      }
      afr[ks] = af;
    }
    l += __shfl_xor(l, 16, 64);
    l += __shfl_xor(l, 32, 64);
    if (gq == 0) {
      if (mode == 0) {
        MWp[sb + (size_t)h * 128 + i] = mrow;
        LWp[sb + (size_t)h * 128 + i] = l;
      } else {  // store [h][w]-oriented: row i is the h coordinate
        MHp[sb + (size_t)i * 128 + h] = mrow;
        LHp[sb + (size_t)i * 128 + h] = l;
      }
    }
#pragma unroll
    for (int ct = 0; ct < 4; ++ct) {
      f32x4 acc = {0.f, 0.f, 0.f, 0.f};
#pragma unroll
      for (int ks = 0; ks < 4; ++ks) {
        ss8 bv = *(const ss8*)&Vs[(ct * 16 + il) * 136 + ks * 32 + gq * 8];
        acc = __builtin_amdgcn_mfma_f32_16x16x32_bf16(afr[ks], bv, acc, 0, 0, 0);
      }
      int cch = ct * 16 + il;        // D col = channel
      int i0 = ib + gq * 4;          // D rows = 4 consecutive pixels
      if (mode == 0) {
#pragma unroll
        for (int r = 0; r < 4; ++r)
          owBase[(size_t)cch * NP + (size_t)(i0 + r)] = acc[r];
      } else {
#pragma unroll
        for (int r = 0; r < 4; ++r)
          ohBase[(size_t)cch * NP + (size_t)(i0 + r)] = f2bf(acc[r]);
      }
    }
  }
}

// ---------------------------------------------------------------------------
// K8: combine: ACC[b][c][h][w] = sum_m sc_m * (a_m*OW_m + b_m*OHT_m^T)
// where a=e^{mw-M}/L, b=e^{mh-M}/L, M=max(mw,mh), L=lw*e^{mw-M}+lh*e^{mh-M}.
// Pure store. Stats (2 MB) are b-dependent only -> L2-served across c.
// ---------------------------------------------------------------------------
__global__ __launch_bounds__(256) void k_merge2(
    const bf16* __restrict__ OHT, const float* __restrict__ OW,
    const float* __restrict__ MWp, const float* __restrict__ LWp,
    const float* __restrict__ MHp, const float* __restrict__ LHp,
    const float* __restrict__ HDR, float* __restrict__ ACC) {
  int tileId = blockIdx.x & 15;
  int plane = blockIdx.x >> 4;      // 0..255 = b*64+c
  int b = plane >> 6;
  int th = tileId >> 2, tw = tileId & 3;
  __shared__ float t0[32][33], t1[32][33];
  int lx = threadIdx.x & 31, ly = threadIdx.x >> 5;
  const bf16* ip0 = OHT + (size_t)plane * NP;
  const bf16* ip1 = OHT + (size_t)(256 + plane) * NP;
  for (int i = 0; i < 32; i += 8) {
    size_t idx = (size_t)(th * 32 + ly + i) * 128 + tw * 32 + lx;
    t0[ly + i][lx] = bf2f(ip0[idx]);
    t1[ly + i][lx] = bf2f(ip1[idx]);
  }
  __syncthreads();
  float sc0 = HDR[1], sc1 = HDR[2];
  float* op = ACC + (size_t)plane * NP;
  const float* ow0 = OW + (size_t)plane * NP;
  const float* ow1 = OW + (size_t)(256 + plane) * NP;
  size_t s0 = (size_t)b * NP, s1 = (size_t)(4 + b) * NP;
  for (int i = 0; i < 32; i += 8) {
    int hh = tw * 32 + ly + i, ww = th * 32 + lx;
    size_t idx = (size_t)hh * 128 + ww;
    float mw0 = MWp[s0 + idx], mh0 = MHp[s0 + idx];
    float M0 = fmaxf(mw0, mh0);
    float ea0 = __expf(mw0 - M0), eb0 = __expf(mh0 - M0);
    float inv0 = 1.0f / (LWp[s0 + idx] * ea0 + LHp[s0 + idx] * eb0);
    float v0 = (ea0 * ow0[idx] + eb0 * t0[lx][ly + i]) * inv0;
    float mw1 = MWp[s1 + idx], mh1 = MHp[s1 + idx];
    float M1 = fmaxf(mw1, mh1);
    float ea1 = __expf(mw1 - M1), eb1 = __expf(mh1 - M1);
    float inv1 = 1.0f / (LWp[s1 + idx] * ea1 + LHp[s1 + idx] * eb1);
    float v1 = (ea1 * ow1[idx] + eb1 * t1[lx][ly + i]) * inv1;
    op[idx] = sc0 * v0 + sc1 * v1;
  }
}

// ---------------------------------------------------------------------------
// K9: partial Gram of y=BN(Y). 512 blocks = b x ch x t.
// ---------------------------------------------------------------------------
__global__ __launch_bounds__(256) void k_gram(const bf16* __restrict__ Y,
                                              const float* __restrict__ SCALE,
                                              const float* __restrict__ SHIFT,
                                              float* __restrict__ GP) {
  int b = blockIdx.x >> 7, ch = (blockIdx.x >> 2) & 31, t = blockIdx.x & 3;
  int tid = threadIdx.x;
  __shared__ float fs[64 * 129];
  int cg = tid >> 4, dg = tid & 15;
  float acc[4][4];
#pragma unroll
  for (int i = 0; i < 4; ++i)
#pragma unroll
    for (int jx = 0; jx < 4; ++jx) acc[i][jx] = 0.f;
  const bf16* yb = Y + (size_t)b * 64 * NP + ch * 512;
  for (int idx = tid; idx < 8192; idx += 256) {
    int c = idx >> 7, j = idx & 127;
    float v = fmaf(bf2f(yb[(size_t)c * NP + t * 128 + j]), SCALE[c], SHIFT[c]);
    fs[c * 129 + j] = fmaxf(v, 0.f);
  }
  __syncthreads();
  for (int j = 0; j < 128; ++j) {
    float a[4], d[4];
#pragma unroll
    for (int i = 0; i < 4; ++i) a[i] = fs[(cg * 4 + i) * 129 + j];
#pragma unroll
    for (int i = 0; i < 4; ++i) d[i] = fs[(dg * 4 + i) * 129 + j];
#pragma unroll
    for (int i = 0; i < 4; ++i)
#pragma unroll
      for (int jx = 0; jx < 4; ++jx) acc[i][jx] = fmaf(a[i], d[jx], acc[i][jx]);
  }
  float* gp = GP + ((size_t)(b * 128) + ch * 4 + t) * 4096;
#pragma unroll
  for (int i = 0; i < 4; ++i)
#pragma unroll
    for (int jx = 0; jx < 4; ++jx)
      gp[(cg * 4 + i) * 64 + dg * 4 + jx] = acc[i][jx];
}

// K10: reduce 128 Gram partials; row softmax of (max-E). 64 blocks.
__global__ __launch_bounds__(256) void k_gram_reduce(const float* __restrict__ GP,
                                                     float* __restrict__ CATT) {
  int b = blockIdx.x >> 4, rg = blockIdx.x & 15;
  int tid = threadIdx.x;
  __shared__ float Es[256];
  int e = rg * 256 + tid;
  float s = 0.f;
  for (int k = 0; k < 128; ++k) s += GP[((size_t)b * 128 + k) * 4096 + e];
  Es[tid] = s;
  __syncthreads();
  int wv = tid >> 6, ln = tid & 63;
  float v = Es[wv * 64 + ln];
  float mn = v;
  for (int off = 32; off; off >>= 1) mn = fminf(mn, __shfl_xor(mn, off, 64));
  float ev = __expf(mn - v);
  float ssum = ev;
  for (int off = 32; off; off >>= 1) ssum += __shfl_xor(ssum, off, 64);
  CATT[((size_t)b * 64 + rg * 4 + wv) * 64 + ln] = ev / ssum;
}

// ---------------------------------------------------------------------------
// K11: out = (2+pg)*x + pg2*y + ACC + cg*(catt@y). In-place fp32 on d_out.
// ---------------------------------------------------------------------------
__global__ __launch_bounds__(256) void k_final(
    const float* __restrict__ x, const bf16* __restrict__ Y,
    const float* __restrict__ SCALE, const float* __restrict__ SHIFT,
    const float* __restrict__ CATT, const float* __restrict__ HDR,
    float* __restrict__ OUT) {
  __shared__ float attS[64 * 65], Ys[64 * 65];
  int tid = threadIdx.x;
  int b = blockIdx.x >> 8, tile = blockIdx.x & 255;
  int n0 = tile * 64;
  for (int i = tid; i < 4096; i += 256)
    attS[(i >> 6) * 65 + (i & 63)] = CATT[(size_t)b * 4096 + i];
  for (int i = tid; i < 4096; i += 256) {
    int d = i >> 6, px = i & 63;
    float v = fmaf(bf2f(Y[(size_t)(b * 64 + d) * NP + n0 + px]), SCALE[d], SHIFT[d]);
    Ys[d * 65 + px] = fmaxf(v, 0.f);
  }
  __syncthreads();
  int cg = tid >> 4, pgx = tid & 15;
  int c0 = cg * 4, p0 = pgx * 4;
  float acc[4][4];
#pragma unroll
  for (int i = 0; i < 4; ++i)
#pragma unroll
    for (int j = 0; j < 4; ++j) acc[i][j] = 0.f;
  for (int d = 0; d < 64; ++d) {
    float a[4], yv[4];
#pragma unroll
    for (int i = 0; i < 4; ++i) a[i] = attS[(c0 + i) * 65 + d];
#pragma unroll
    for (int j = 0; j < 4; ++j) yv[j] = Ys[d * 65 + p0 + j];
#pragma unroll
    for (int i = 0; i < 4; ++i)
#pragma unroll
      for (int j = 0; j < 4; ++j) acc[i][j] = fmaf(a[i], yv[j], acc[i][j]);
  }
  float c2pg = HDR[3], fpg2 = HDR[4], fcg = HDR[5];
#pragma unroll
  for (int i = 0; i < 4; ++i) {
    size_t base = (size_t)(b * 64 + c0 + i) * NP + n0 + p0;
#pragma unroll
    for (int j = 0; j < 4; ++j) {
      float yv = Ys[(c0 + i) * 65 + p0 + j];
      OUT[base + j] =
          c2pg * x[base + j] + fpg2 * yv + OUT[base + j] + fcg * acc[i][j];
    }
  }
}

// ---------------------------------------------------------------------------
extern "C" void kernel_launch(void* const* d_in, const int* in_sizes, int n_in,
                              void* d_out, int out_size, void* d_ws, size_t ws_size,
                              hipStream_t stream) {
  const float* x = (const float*)d_in[0];
  const float* fbp = (const float*)d_in[1];

  // ~107 MB of the 256 MiB workspace.
  char* base = (char*)d_ws;
  float* HDR = (float*)base;
  float* SCALE = HDR + 16;
  float* SHIFT = SCALE + 64;
  char* p = base + 4096;
  bf16* Y = (bf16*)p;    p += 8388608;   // [4][64][NP]
  bf16* QK = (bf16*)p;   p += 4194304;   // [m][q/k][4][8][NP] = 128 planes
  bf16* QKT = (bf16*)p;  p += 4194304;
  bf16* V = (bf16*)p;    p += 16777216;  // [m][4][64][NP] = 512 planes
  bf16* VT = (bf16*)p;   p += 16777216;
  float* MWp = (float*)p; p += 524288;   // [m][4][NP] raw w-dir max ([h][w])
  float* LWp = (float*)p; p += 524288;   // raw w-dir sumexp
  float* MHp = (float*)p; p += 524288;   // raw h-dir max ([h][w]-oriented)
  float* LHp = (float*)p; p += 524288;   // raw h-dir sumexp
  bf16* OHT = (bf16*)p;  p += 16777216;  // [m][4][64][NP] raw out_h [c][w][h]
  float* OW = (float*)p; p += 33554432;  // [m][4][64][NP] fp32 raw out_w
  float* GP = (float*)p; p += 8388608;   // Gram partials
  float* CATT = (float*)p; p += 1048576;
  float* ACC = (float*)d_out;
  float* PS = (float*)QK;  // stats partials (4 KB), QK unused until conv

  k_pool_conv<<<1024, 256, 0, stream>>>(fbp, (const float*)d_in[2],
                                        (const float*)d_in[3], Y);
  k_stats_p1<<<512, 256, 0, stream>>>(Y, PS);
  k_stats_p2<<<1, 64, 0, stream>>>(PS, (const float*)d_in[4],
                                   (const float*)d_in[5], SCALE, SHIFT,
                                   (const float*)d_in[12], (const float*)d_in[19],
                                   (const float*)d_in[20], (const float*)d_in[21],
                                   (const float*)d_in[22], HDR);

  // both modules in each dispatch
  k_conv80x2<<<2048, 256, 0, stream>>>(
      x, Y, SCALE, SHIFT,
      (const float*)d_in[6], (const float*)d_in[7], (const float*)d_in[8],
      (const float*)d_in[9], (const float*)d_in[10], (const float*)d_in[11],
      (const float*)d_in[13], (const float*)d_in[14], (const float*)d_in[15],
      (const float*)d_in[16], (const float*)d_in[17], (const float*)d_in[18],
      QK, V);
  k_transpose2<<<10240, 256, 0, stream>>>((const u16*)QK, (u16*)QKT,
                                          (const u16*)V, (u16*)VT, 128);
  // flash-style attention: stats + unnormalized outputs in one pass
  k_av<<<2048, 256, 0, stream>>>(QK, QKT, V, VT, MWp, LWp, MHp, LHp, OW, OHT);
  // exact combine of both directions and both modules -> ACC (pure store)
  k_merge2<<<4096, 256, 0, stream>>>(OHT, OW, MWp, LWp, MHp, LHp, HDR, ACC);

  k_gram<<<512, 256, 0, stream>>>(Y, SCALE, SHIFT, GP);
  k_gram_reduce<<<64, 256, 0, stream>>>(GP, CATT);
  k_final<<<1024, 256, 0, stream>>>(x, Y, SCALE, SHIFT, CATT, HDR,
                                    (float*)d_out);
}

// Round 8
// 282.769 us; speedup vs baseline: 2.0132x; 1.0656x over previous
//
#include <hip/hip_runtime.h>
#include <hip/hip_bf16.h>

#define NP 16384   // H*W
#define NB 4

typedef __hip_bfloat16 bf16;
typedef unsigned short u16;
typedef unsigned short us8 __attribute__((ext_vector_type(8)));
typedef unsigned short us4 __attribute__((ext_vector_type(4)));
typedef short ss8 __attribute__((ext_vector_type(8)));
typedef float f32x4 __attribute__((ext_vector_type(4)));
__device__ __forceinline__ float bf2f(const bf16 v) { return __bfloat162float(v); }
__device__ __forceinline__ bf16 f2bf(float v) { return __float2bfloat16(v); }
__device__ __forceinline__ float bfu(u16 h) {
  return __uint_as_float(((unsigned)h) << 16);
}
__device__ __forceinline__ u16 fbu(float v) {
  bf16 b = f2bf(v);
  return *(u16*)&b;
}

// Inputs/outputs fp32 (reference dtype). Internal tensors bf16, math fp32.
// Flash-style decomposition for the dual-direction softmax; MFMA for both
// the attention PV step and the QKV conv (weights split hi+lo bf16 so the
// conv keeps ~fp32 weight precision).

// ---------------------------------------------------------------------------
// K1: maxpool2x2(fb fp32) -> conv1x1+bias -> Y raw (pre-BN, bf16). 64x64 tile.
// ---------------------------------------------------------------------------
__global__ __launch_bounds__(256) void k_pool_conv(
    const float* __restrict__ fb, const float* __restrict__ wconv,
    const float* __restrict__ bconv, bf16* __restrict__ Y) {
  __shared__ float wS[64 * 65], bS[64], Xs[4096];
  int tid = threadIdx.x;
  int b = blockIdx.x >> 8, tile = blockIdx.x & 255;
  int n0 = tile * 64;
  for (int i = tid; i < 4096; i += 256) wS[(i >> 6) * 65 + (i & 63)] = wconv[i];
  if (tid < 64) bS[tid] = bconv[tid];
  for (int i = tid; i < 4096; i += 256) {
    int c = i >> 6, px = i & 63;
    int n = n0 + px, h = n >> 7, w = n & 127;
    size_t fbase = ((size_t)((b * 64 + c) * 256 + 2 * h)) * 256 + 2 * w;
    float2 v01 = *(const float2*)(fb + fbase);
    float2 v23 = *(const float2*)(fb + fbase + 256);
    Xs[i] = fmaxf(fmaxf(v01.x, v01.y), fmaxf(v23.x, v23.y));
  }
  __syncthreads();
  int ty = tid >> 4, tx = tid & 15;
  float acc[4][4];
#pragma unroll
  for (int i = 0; i < 4; ++i) {
    float bv = bS[ty + 16 * i];
#pragma unroll
    for (int j = 0; j < 4; ++j) acc[i][j] = bv;
  }
  for (int c = 0; c < 64; ++c) {
    float xv[4], wv[4];
#pragma unroll
    for (int j = 0; j < 4; ++j) xv[j] = Xs[c * 64 + tx * 4 + j];
#pragma unroll
    for (int i = 0; i < 4; ++i) wv[i] = wS[(ty + 16 * i) * 65 + c];
#pragma unroll
    for (int i = 0; i < 4; ++i)
#pragma unroll
      for (int j = 0; j < 4; ++j) acc[i][j] = fmaf(wv[i], xv[j], acc[i][j]);
  }
#pragma unroll
  for (int i = 0; i < 4; ++i) {
    int ch = ty + 16 * i;
    bf16* yb = Y + (size_t)(b * 64 + ch) * NP + n0 + tx * 4;
#pragma unroll
    for (int j = 0; j < 4; ++j) yb[j] = f2bf(acc[i][j]);
  }
}

// ---------------------------------------------------------------------------
// K2a: stats stage 1.
// ---------------------------------------------------------------------------
__global__ __launch_bounds__(256) void k_stats_p1(const bf16* __restrict__ Y,
                                                  float* __restrict__ PS) {
  int blk = blockIdx.x, tid = threadIdx.x;
  int o = blk >> 3, slab = blk & 7;
  int b = slab >> 1, half = slab & 1;
  const us8* vp =
      (const us8*)(Y + ((size_t)(b * 64 + o)) * NP + half * 8192);
  float s = 0.f, ss = 0.f;
#pragma unroll
  for (int it = 0; it < 4; ++it) {
    us8 v = vp[tid + 256 * it];
#pragma unroll
    for (int e = 0; e < 8; ++e) {
      float f = bfu(v[e]);
      s += f;
      ss = fmaf(f, f, ss);
    }
  }
  for (int off = 32; off > 0; off >>= 1) {
    s += __shfl_down(s, off, 64);
    ss += __shfl_down(ss, off, 64);
  }
  __shared__ float sh[8];
  int wv = tid >> 6, ln = tid & 63;
  if (ln == 0) { sh[wv] = s; sh[4 + wv] = ss; }
  __syncthreads();
  if (tid == 0) {
    PS[blk] = sh[0] + sh[1] + sh[2] + sh[3];
    PS[512 + blk] = sh[4] + sh[5] + sh[6] + sh[7];
  }
}

// K2b: stats stage 2 + BN scale/shift + scalar header (fused)
__global__ __launch_bounds__(64) void k_stats_p2(
    const float* __restrict__ PS, const float* __restrict__ bng,
    const float* __restrict__ bnb, float* __restrict__ SCALE,
    float* __restrict__ SHIFT, const float* xg, const float* fg,
    const float* pg, const float* pg2, const float* cg,
    float* __restrict__ HDR) {
  int o = threadIdx.x;
  float s = 0.f, ss = 0.f;
#pragma unroll
  for (int k = 0; k < 8; ++k) {
    s += PS[o * 8 + k];
    ss += PS[512 + o * 8 + k];
  }
  const float inv = 1.0f / (NB * NP);
  float mu = s * inv;
  float var = ss * inv - mu * mu;
  float r = rsqrtf(var + 1e-5f);
  float sc = r * bng[o];
  SCALE[o] = sc;
  SHIFT[o] = bnb[o] - mu * sc;
  if (o == 0) {
    float vpg = pg[0];
    HDR[1] = vpg * xg[0];
    HDR[2] = pg2[0] * fg[0];
    HDR[3] = 2.0f + vpg;
    HDR[4] = pg2[0];
    HDR[5] = cg[0];
  }
}

// ---------------------------------------------------------------------------
// K4: QKV conv1x1 on MFMA, both modules. 1024 blocks = m(2) x b(4) x 128-px
// tile; 256 thr (4 waves x 32 px). Weights split w = hi + lo (2x bf16, ~17
// mantissa bits -> >= fp32-weight precision given X is bf16 anyway).
// LDS: Xs [px][c] and W [oc][c], both XOR-swizzled for conflict-free
// ds_read_b128 MFMA fragments. Per wave: 4 A-frags, 20 W-frags, 40 MFMA.
// ---------------------------------------------------------------------------
__global__ __launch_bounds__(256, 4) void k_conv_mfma(
    const float* __restrict__ xin, const bf16* __restrict__ Yin,
    const float* __restrict__ SCALE, const float* __restrict__ SHIFT,
    const float* __restrict__ qw0, const float* __restrict__ qb0,
    const float* __restrict__ kw0, const float* __restrict__ kb0,
    const float* __restrict__ vw0, const float* __restrict__ vb0,
    const float* __restrict__ qw1, const float* __restrict__ qb1,
    const float* __restrict__ kw1, const float* __restrict__ kb1,
    const float* __restrict__ vw1, const float* __restrict__ vb1,
    bf16* __restrict__ QK, bf16* __restrict__ V) {
  __shared__ __align__(16) u16 Xs[128 * 64];            // [px][c], swizzled
  __shared__ __align__(16) u16 wHi[80 * 64], wLo[80 * 64];  // [oc][c], swz
  __shared__ float bS[80];
  int tid = threadIdx.x;
  int m = blockIdx.x >> 9;
  int b = (blockIdx.x >> 7) & 3;
  int tile = blockIdx.x & 127;
  int n0 = tile * 128;
  const float* qw = m ? qw1 : qw0;
  const float* qb = m ? qb1 : qb0;
  const float* kw = m ? kw1 : kw0;
  const float* kb = m ? kb1 : kb0;
  const float* vw = m ? vw1 : vw0;
  const float* vb = m ? vb1 : vb0;
  // stage weights as hi+lo bf16, swizzle (oc&7)<<3 (u16 units)
  for (int i = tid; i < 5120; i += 256) {
    int oc = i >> 6, c = i & 63;
    float w;
    if (oc < 8) w = qw[oc * 64 + c];
    else if (oc < 16) w = kw[(oc - 8) * 64 + c];
    else w = vw[(oc - 16) * 64 + c];
    u16 hb = fbu(w);
    u16 lb = fbu(w - bfu(hb));
    int idx = (oc * 64 + c) ^ ((oc & 7) << 3);
    wHi[idx] = hb;
    wLo[idx] = lb;
  }
  if (tid < 80)
    bS[tid] = (tid < 8) ? qb[tid] : (tid < 16) ? kb[tid - 8] : vb[tid - 16];
  // stage X: [px][c], swizzle ((px&7)^((px>>3)&7))<<3
  if (m) {
    for (int i2 = tid; i2 < 1024; i2 += 256) {
      int c = i2 >> 4, vj = i2 & 15;
      us8 v = *(const us8*)(Yin + (size_t)(b * 64 + c) * NP + n0 + vj * 8);
      float sc = SCALE[c], sh = SHIFT[c];
#pragma unroll
      for (int e = 0; e < 8; ++e) {
        int px = vj * 8 + e;
        float f = fmaxf(fmaf(bfu(v[e]), sc, sh), 0.f);
        Xs[(px * 64 + c) ^ ((((px & 7) ^ ((px >> 3) & 7))) << 3)] = fbu(f);
      }
    }
  } else {
    for (int i2 = tid; i2 < 2048; i2 += 256) {
      int c = i2 >> 5, vj = i2 & 31;
      float4 v = *(const float4*)(xin + (size_t)(b * 64 + c) * NP + n0 + vj * 4);
      float vv[4] = {v.x, v.y, v.z, v.w};
#pragma unroll
      for (int r = 0; r < 4; ++r) {
        int px = vj * 4 + r;
        Xs[(px * 64 + c) ^ ((((px & 7) ^ ((px >> 3) & 7))) << 3)] = fbu(vv[r]);
      }
    }
  }
  __syncthreads();
  int lane = tid & 63, wv = tid >> 6;
  int il = lane & 15, gq = lane >> 4;
  int pxb = wv * 32;
  // A-fragments: X rows = px (lane il), K = c
  ss8 afr[2][2];
#pragma unroll
  for (int sub = 0; sub < 2; ++sub)
#pragma unroll
    for (int ks = 0; ks < 2; ++ks) {
      int px = pxb + sub * 16 + il;
      int idx =
          (px * 64 + ks * 32 + gq * 8) ^ ((((px & 7) ^ ((px >> 3) & 7))) << 3);
      afr[sub][ks] = *(const ss8*)&Xs[idx];
    }
#pragma unroll
  for (int oct = 0; oct < 5; ++oct) {
    int oc = oct * 16 + il;   // B-col = out-channel
    ss8 wh[2], wl[2];
#pragma unroll
    for (int ks = 0; ks < 2; ++ks) {
      int idx = (oc * 64 + ks * 32 + gq * 8) ^ ((oc & 7) << 3);
      wh[ks] = *(const ss8*)&wHi[idx];
      wl[ks] = *(const ss8*)&wLo[idx];
    }
    float bv = bS[oc];
    bf16* dst;
    size_t basep;
    if (oc < 8) { dst = QK; basep = (size_t)(((m * 2 + 0) * 4 + b) * 8 + oc) * NP; }
    else if (oc < 16) { dst = QK; basep = (size_t)(((m * 2 + 1) * 4 + b) * 8 + (oc - 8)) * NP; }
    else { dst = V; basep = (size_t)((m * 4 + b) * 64 + (oc - 16)) * NP; }
#pragma unroll
    for (int sub = 0; sub < 2; ++sub) {
      f32x4 acc = {bv, bv, bv, bv};
#pragma unroll
      for (int ks = 0; ks < 2; ++ks) {
        acc = __builtin_amdgcn_mfma_f32_16x16x32_bf16(afr[sub][ks], wh[ks], acc, 0, 0, 0);
        acc = __builtin_amdgcn_mfma_f32_16x16x32_bf16(afr[sub][ks], wl[ks], acc, 0, 0, 0);
      }
      int px0 = pxb + sub * 16 + gq * 4;   // D rows = 4 consecutive px
      us4 ov;
#pragma unroll
      for (int r = 0; r < 4; ++r) ov[r] = fbu(acc[r]);
      *(us4*)(dst + basep + n0 + px0) = ov;
    }
  }
}

// ---------------------------------------------------------------------------
// K5: 128x128 bf16 plane transpose over two tensor pairs in one dispatch.
// ---------------------------------------------------------------------------
__global__ __launch_bounds__(256) void k_transpose2(
    const u16* __restrict__ inA, u16* __restrict__ outA,
    const u16* __restrict__ inB, u16* __restrict__ outB, int nA) {
  int tileId = blockIdx.x & 15;
  int plane = blockIdx.x >> 4;
  const u16* ip;
  u16* op;
  if (plane < nA) {
    ip = inA + (size_t)plane * NP;
    op = outA + (size_t)plane * NP;
  } else {
    ip = inB + (size_t)(plane - nA) * NP;
    op = outB + (size_t)(plane - nA) * NP;
  }
  int th = tileId >> 2, tw = tileId & 3;
  __shared__ u16 t[32][33];
  int lx = threadIdx.x & 31, ly = threadIdx.x >> 5;
  for (int i = 0; i < 32; i += 8)
    t[ly + i][lx] = ip[(size_t)(th * 32 + ly + i) * 128 + tw * 32 + lx];
  __syncthreads();
  for (int i = 0; i < 32; i += 8)
    op[(size_t)(tw * 32 + ly + i) * 128 + th * 32 + lx] = t[lx][ly + i];
}

// ---------------------------------------------------------------------------
// K7: out_w + out_h, both modules, on MFMA, flash-style. 2048 blocks =
// (b,h) x mode x m; 256 thr. Scores computed ONCE into registers; per-row
// max/sumexp via shfl_xor across the 4 gq-sibling lanes (xor 16/32).
// Outputs UNNORMALIZED: mode0 -> OW (fp32 [c][h][w]) + MWp/LWp stats,
// mode1 -> OHT (bf16 [c][w][h]) + MHp/LHp stats (stored [h][w]-oriented).
// ---------------------------------------------------------------------------
__global__ __launch_bounds__(256, 4) void k_av(
    const bf16* __restrict__ QK, const bf16* __restrict__ QKT,
    const bf16* __restrict__ V, const bf16* __restrict__ VT,
    float* __restrict__ MWp, float* __restrict__ LWp,
    float* __restrict__ MHp, float* __restrict__ LHp,
    float* __restrict__ OW, bf16* __restrict__ OHT) {
  int blk = blockIdx.x;
  int m = blk & 1, mode = (blk >> 1) & 1;
  int bid = blk >> 2;
  int b = bid >> 7, h = bid & 127;
  const bf16* qkbase = mode ? QKT : QK;
  const bf16* Qp = qkbase + (size_t)(((m * 2 + 0) * 4 + b) * 8) * NP;
  const bf16* Kp = qkbase + (size_t)(((m * 2 + 1) * 4 + b) * 8) * NP;
  const bf16* Vp = (mode ? VT : V) + (size_t)((m * 4 + b) * 64) * NP;
  __shared__ __align__(16) u16 qT[128 * 8];    // [p(j)][c]
  __shared__ __align__(16) u16 kT[128 * 8];    // [p(j)][c]
  __shared__ __align__(16) u16 Vs[64 * 136];   // [c][j], pad 136
  int tid = threadIdx.x;
  {  // q (tid<128) / k (tid>=128): 1024 u16 each, one us8 load per thread
    int c = (tid >> 4) & 7, vj = tid & 15;
    const bf16* src = (tid < 128) ? Qp : Kp;
    u16* dst = (tid < 128) ? qT : kT;
    const us8* sp = (const us8*)(src + (size_t)c * NP + (size_t)h * 128);
    us8 sv = sp[vj];
#pragma unroll
    for (int e = 0; e < 8; ++e) {
      int j = vj * 8 + e;
      int p = ((j & 7) << 4) | (j >> 3);
      dst[p * 8 + c] = sv[e];
    }
  }
  for (int i2 = tid; i2 < 1024; i2 += 256) {  // V: 8192 u16, b128 writes
    int c = i2 >> 4, vj = i2 & 15;
    const us8* vp = (const us8*)(Vp + (size_t)c * NP + (size_t)h * 128);
    us8 vv = vp[vj];
    *(us8*)&Vs[c * 136 + vj * 8] = vv;
  }
  __syncthreads();
  int lane = tid & 63, wv = tid >> 6;   // wave wv owns rows [wv*32, wv*32+32)
  int il = lane & 15, gq = lane >> 4;
  size_t sb = (size_t)(m * 4 + b) * NP;
  float* owBase = OW + (size_t)((m * 4 + b) * 64) * NP + (size_t)h * 128;
  bf16* ohBase = OHT + (size_t)((m * 4 + b) * 64) * NP + (size_t)h * 128;
#pragma unroll
  for (int sub = 0; sub < 2; ++sub) {
    int ib = wv * 32 + sub * 16;
    int i = ib + il;                 // this lane's A-row (pixel index)
    int pi = ((i & 7) << 4) | (i >> 3);
    us8 qv = *(const us8*)&qT[pi * 8];
    float qr[8];
#pragma unroll
    for (int c = 0; c < 8; ++c) qr[c] = bfu(qv[c]);
    float scr[4][8];
    float mrow = -3.0e38f;
#pragma unroll
    for (int ks = 0; ks < 4; ++ks) {
#pragma unroll
      for (int e = 0; e < 8; ++e) {
        int j = ks * 32 + gq * 8 + e;
        int pj = ((j & 7) << 4) | (j >> 3);
        us8 kv = *(const us8*)&kT[pj * 8];
        float s = 0.f;
#pragma unroll
        for (int c = 0; c < 8; ++c) s = fmaf(qr[c], bfu(kv[c]), s);
        if (mode && j == i) s = -1.0e30f;   // diag mask (exp underflows to 0)
        scr[ks][e] = s;
        mrow = fmaxf(mrow, s);
      }
    }
    mrow = fmaxf(mrow, __shfl_xor(mrow, 16, 64));
    mrow = fmaxf(mrow, __shfl_xor(mrow, 32, 64));
    float l = 0.f;
    ss8 afr[4];
#pragma unroll
    for (int ks = 0; ks < 4; ++ks) {
      ss8 af;
#pragma unroll
      for (int e = 0; e < 8; ++e) {
        float ev = __expf(scr[ks][e] - mrow);
        l += ev;
        af[e] = (short)fbu(ev);
      }
      afr[ks] = af;
    }
    l += __shfl_xor(l, 16, 64);
    l += __shfl_xor(l, 32, 64);
    if (gq == 0) {
      if (mode == 0) {
        MWp[sb + (size_t)h * 128 + i] = mrow;
        LWp[sb + (size_t)h * 128 + i] = l;
      } else {  // store [h][w]-oriented: row i is the h coordinate
        MHp[sb + (size_t)i * 128 + h] = mrow;
        LHp[sb + (size_t)i * 128 + h] = l;
      }
    }
#pragma unroll
    for (int ct = 0; ct < 4; ++ct) {
      f32x4 acc = {0.f, 0.f, 0.f, 0.f};
#pragma unroll
      for (int ks = 0; ks < 4; ++ks) {
        ss8 bv = *(const ss8*)&Vs[(ct * 16 + il) * 136 + ks * 32 + gq * 8];
        acc = __builtin_amdgcn_mfma_f32_16x16x32_bf16(afr[ks], bv, acc, 0, 0, 0);
      }
      int cch = ct * 16 + il;        // D col = channel
      int i0 = ib + gq * 4;          // D rows = 4 consecutive pixels
      if (mode == 0) {
#pragma unroll
        for (int r = 0; r < 4; ++r)
          owBase[(size_t)cch * NP + (size_t)(i0 + r)] = acc[r];
      } else {
#pragma unroll
        for (int r = 0; r < 4; ++r)
          ohBase[(size_t)cch * NP + (size_t)(i0 + r)] = f2bf(acc[r]);
      }
    }
  }
}

// ---------------------------------------------------------------------------
// K8: combine: ACC[b][c][h][w] = sum_m sc_m * (a_m*OW_m + b_m*OHT_m^T)
// where a=e^{mw-M}/L, b=e^{mh-M}/L, M=max(mw,mh), L=lw*e^{mw-M}+lh*e^{mh-M}.
// ---------------------------------------------------------------------------
__global__ __launch_bounds__(256) void k_merge2(
    const bf16* __restrict__ OHT, const float* __restrict__ OW,
    const float* __restrict__ MWp, const float* __restrict__ LWp,
    const float* __restrict__ MHp, const float* __restrict__ LHp,
    const float* __restrict__ HDR, float* __restrict__ ACC) {
  int tileId = blockIdx.x & 15;
  int plane = blockIdx.x >> 4;      // 0..255 = b*64+c
  int b = plane >> 6;
  int th = tileId >> 2, tw = tileId & 3;
  __shared__ float t0[32][33], t1[32][33];
  int lx = threadIdx.x & 31, ly = threadIdx.x >> 5;
  const bf16* ip0 = OHT + (size_t)plane * NP;
  const bf16* ip1 = OHT + (size_t)(256 + plane) * NP;
  for (int i = 0; i < 32; i += 8) {
    size_t idx = (size_t)(th * 32 + ly + i) * 128 + tw * 32 + lx;
    t0[ly + i][lx] = bf2f(ip0[idx]);
    t1[ly + i][lx] = bf2f(ip1[idx]);
  }
  __syncthreads();
  float sc0 = HDR[1], sc1 = HDR[2];
  float* op = ACC + (size_t)plane * NP;
  const float* ow0 = OW + (size_t)plane * NP;
  const float* ow1 = OW + (size_t)(256 + plane) * NP;
  size_t s0 = (size_t)b * NP, s1 = (size_t)(4 + b) * NP;
  for (int i = 0; i < 32; i += 8) {
    int hh = tw * 32 + ly + i, ww = th * 32 + lx;
    size_t idx = (size_t)hh * 128 + ww;
    float mw0 = MWp[s0 + idx], mh0 = MHp[s0 + idx];
    float M0 = fmaxf(mw0, mh0);
    float ea0 = __expf(mw0 - M0), eb0 = __expf(mh0 - M0);
    float inv0 = 1.0f / (LWp[s0 + idx] * ea0 + LHp[s0 + idx] * eb0);
    float v0 = (ea0 * ow0[idx] + eb0 * t0[lx][ly + i]) * inv0;
    float mw1 = MWp[s1 + idx], mh1 = MHp[s1 + idx];
    float M1 = fmaxf(mw1, mh1);
    float ea1 = __expf(mw1 - M1), eb1 = __expf(mh1 - M1);
    float inv1 = 1.0f / (LWp[s1 + idx] * ea1 + LHp[s1 + idx] * eb1);
    float v1 = (ea1 * ow1[idx] + eb1 * t1[lx][ly + i]) * inv1;
    op[idx] = sc0 * v0 + sc1 * v1;
  }
}

// ---------------------------------------------------------------------------
// K9: partial Gram of y=BN(Y). 512 blocks = b x ch x t.
// ---------------------------------------------------------------------------
__global__ __launch_bounds__(256) void k_gram(const bf16* __restrict__ Y,
                                              const float* __restrict__ SCALE,
                                              const float* __restrict__ SHIFT,
                                              float* __restrict__ GP) {
  int b = blockIdx.x >> 7, ch = (blockIdx.x >> 2) & 31, t = blockIdx.x & 3;
  int tid = threadIdx.x;
  __shared__ float fs[64 * 129];
  int cg = tid >> 4, dg = tid & 15;
  float acc[4][4];
#pragma unroll
  for (int i = 0; i < 4; ++i)
#pragma unroll
    for (int jx = 0; jx < 4; ++jx) acc[i][jx] = 0.f;
  const bf16* yb = Y + (size_t)b * 64 * NP + ch * 512;
  for (int idx = tid; idx < 8192; idx += 256) {
    int c = idx >> 7, j = idx & 127;
    float v = fmaf(bf2f(yb[(size_t)c * NP + t * 128 + j]), SCALE[c], SHIFT[c]);
    fs[c * 129 + j] = fmaxf(v, 0.f);
  }
  __syncthreads();
  for (int j = 0; j < 128; ++j) {
    float a[4], d[4];
#pragma unroll
    for (int i = 0; i < 4; ++i) a[i] = fs[(cg * 4 + i) * 129 + j];
#pragma unroll
    for (int i = 0; i < 4; ++i) d[i] = fs[(dg * 4 + i) * 129 + j];
#pragma unroll
    for (int i = 0; i < 4; ++i)
#pragma unroll
      for (int jx = 0; jx < 4; ++jx) acc[i][jx] = fmaf(a[i], d[jx], acc[i][jx]);
  }
  float* gp = GP + ((size_t)(b * 128) + ch * 4 + t) * 4096;
#pragma unroll
  for (int i = 0; i < 4; ++i)
#pragma unroll
    for (int jx = 0; jx < 4; ++jx)
      gp[(cg * 4 + i) * 64 + dg * 4 + jx] = acc[i][jx];
}

// K10: reduce 128 Gram partials; row softmax of (max-E). 64 blocks.
__global__ __launch_bounds__(256) void k_gram_reduce(const float* __restrict__ GP,
                                                     float* __restrict__ CATT) {
  int b = blockIdx.x >> 4, rg = blockIdx.x & 15;
  int tid = threadIdx.x;
  __shared__ float Es[256];
  int e = rg * 256 + tid;
  float s = 0.f;
  for (int k = 0; k < 128; ++k) s += GP[((size_t)b * 128 + k) * 4096 + e];
  Es[tid] = s;
  __syncthreads();
  int wv = tid >> 6, ln = tid & 63;
  float v = Es[wv * 64 + ln];
  float mn = v;
  for (int off = 32; off; off >>= 1) mn = fminf(mn, __shfl_xor(mn, off, 64));
  float ev = __expf(mn - v);
  float ssum = ev;
  for (int off = 32; off; off >>= 1) ssum += __shfl_xor(ssum, off, 64);
  CATT[((size_t)b * 64 + rg * 4 + wv) * 64 + ln] = ev / ssum;
}

// ---------------------------------------------------------------------------
// K11: out = (2+pg)*x + pg2*y + ACC + cg*(catt@y). In-place fp32 on d_out.
// ---------------------------------------------------------------------------
__global__ __launch_bounds__(256) void k_final(
    const float* __restrict__ x, const bf16* __restrict__ Y,
    const float* __restrict__ SCALE, const float* __restrict__ SHIFT,
    const float* __restrict__ CATT, const float* __restrict__ HDR,
    float* __restrict__ OUT) {
  __shared__ float attS[64 * 65], Ys[64 * 65];
  int tid = threadIdx.x;
  int b = blockIdx.x >> 8, tile = blockIdx.x & 255;
  int n0 = tile * 64;
  for (int i = tid; i < 4096; i += 256)
    attS[(i >> 6) * 65 + (i & 63)] = CATT[(size_t)b * 4096 + i];
  for (int i = tid; i < 4096; i += 256) {
    int d = i >> 6, px = i & 63;
    float v = fmaf(bf2f(Y[(size_t)(b * 64 + d) * NP + n0 + px]), SCALE[d], SHIFT[d]);
    Ys[d * 65 + px] = fmaxf(v, 0.f);
  }
  __syncthreads();
  int cg = tid >> 4, pgx = tid & 15;
  int c0 = cg * 4, p0 = pgx * 4;
  float acc[4][4];
#pragma unroll
  for (int i = 0; i < 4; ++i)
#pragma unroll
    for (int j = 0; j < 4; ++j) acc[i][j] = 0.f;
  for (int d = 0; d < 64; ++d) {
    float a[4], yv[4];
#pragma unroll
    for (int i = 0; i < 4; ++i) a[i] = attS[(c0 + i) * 65 + d];
#pragma unroll
    for (int j = 0; j < 4; ++j) yv[j] = Ys[d * 65 + p0 + j];
#pragma unroll
    for (int i = 0; i < 4; ++i)
#pragma unroll
      for (int j = 0; j < 4; ++j) acc[i][j] = fmaf(a[i], yv[j], acc[i][j]);
  }
  float c2pg = HDR[3], fpg2 = HDR[4], fcg = HDR[5];
#pragma unroll
  for (int i = 0; i < 4; ++i) {
    size_t base = (size_t)(b * 64 + c0 + i) * NP + n0 + p0;
#pragma unroll
    for (int j = 0; j < 4; ++j) {
      float yv = Ys[(c0 + i) * 65 + p0 + j];
      OUT[base + j] =
          c2pg * x[base + j] + fpg2 * yv + OUT[base + j] + fcg * acc[i][j];
    }
  }
}

// ---------------------------------------------------------------------------
extern "C" void kernel_launch(void* const* d_in, const int* in_sizes, int n_in,
                              void* d_out, int out_size, void* d_ws, size_t ws_size,
                              hipStream_t stream) {
  const float* x = (const float*)d_in[0];
  const float* fbp = (const float*)d_in[1];

  // ~107 MB of the 256 MiB workspace.
  char* base = (char*)d_ws;
  float* HDR = (float*)base;
  float* SCALE = HDR + 16;
  float* SHIFT = SCALE + 64;
  char* p = base + 4096;
  bf16* Y = (bf16*)p;    p += 8388608;   // [4][64][NP]
  bf16* QK = (bf16*)p;   p += 4194304;   // [m][q/k][4][8][NP] = 128 planes
  bf16* QKT = (bf16*)p;  p += 4194304;
  bf16* V = (bf16*)p;    p += 16777216;  // [m][4][64][NP] = 512 planes
  bf16* VT = (bf16*)p;   p += 16777216;
  float* MWp = (float*)p; p += 524288;   // [m][4][NP] raw w-dir max ([h][w])
  float* LWp = (float*)p; p += 524288;   // raw w-dir sumexp
  float* MHp = (float*)p; p += 524288;   // raw h-dir max ([h][w]-oriented)
  float* LHp = (float*)p; p += 524288;   // raw h-dir sumexp
  bf16* OHT = (bf16*)p;  p += 16777216;  // [m][4][64][NP] raw out_h [c][w][h]
  float* OW = (float*)p; p += 33554432;  // [m][4][64][NP] fp32 raw out_w
  float* GP = (float*)p; p += 8388608;   // Gram partials
  float* CATT = (float*)p; p += 1048576;
  float* ACC = (float*)d_out;
  float* PS = (float*)QK;  // stats partials (4 KB), QK unused until conv

  k_pool_conv<<<1024, 256, 0, stream>>>(fbp, (const float*)d_in[2],
                                        (const float*)d_in[3], Y);
  k_stats_p1<<<512, 256, 0, stream>>>(Y, PS);
  k_stats_p2<<<1, 64, 0, stream>>>(PS, (const float*)d_in[4],
                                   (const float*)d_in[5], SCALE, SHIFT,
                                   (const float*)d_in[12], (const float*)d_in[19],
                                   (const float*)d_in[20], (const float*)d_in[21],
                                   (const float*)d_in[22], HDR);

  // QKV conv on MFMA, both modules (1024 blocks = m x b x 128-px tile)
  k_conv_mfma<<<1024, 256, 0, stream>>>(
      x, Y, SCALE, SHIFT,
      (const float*)d_in[6], (const float*)d_in[7], (const float*)d_in[8],
      (const float*)d_in[9], (const float*)d_in[10], (const float*)d_in[11],
      (const float*)d_in[13], (const float*)d_in[14], (const float*)d_in[15],
      (const float*)d_in[16], (const float*)d_in[17], (const float*)d_in[18],
      QK, V);
  k_transpose2<<<10240, 256, 0, stream>>>((const u16*)QK, (u16*)QKT,
                                          (const u16*)V, (u16*)VT, 128);
  // flash-style attention: stats + unnormalized outputs in one pass
  k_av<<<2048, 256, 0, stream>>>(QK, QKT, V, VT, MWp, LWp, MHp, LHp, OW, OHT);
  // exact combine of both directions and both modules -> ACC (pure store)
  k_merge2<<<4096, 256, 0, stream>>>(OHT, OW, MWp, LWp, MHp, LHp, HDR, ACC);

  k_gram<<<512, 256, 0, stream>>>(Y, SCALE, SHIFT, GP);
  k_gram_reduce<<<64, 256, 0, stream>>>(GP, CATT);
  k_final<<<1024, 256, 0, stream>>>(x, Y, SCALE, SHIFT, CATT, HDR,
                                    (float*)d_out);
}

// Round 9
// 277.422 us; speedup vs baseline: 2.0520x; 1.0193x over previous
//
#include <hip/hip_runtime.h>
#include <hip/hip_bf16.h>

#define NP 16384   // H*W
#define NB 4

typedef __hip_bfloat16 bf16;
typedef unsigned short u16;
typedef unsigned short us8 __attribute__((ext_vector_type(8)));
typedef unsigned short us4 __attribute__((ext_vector_type(4)));
typedef short ss8 __attribute__((ext_vector_type(8)));
typedef float f32x4 __attribute__((ext_vector_type(4)));
__device__ __forceinline__ float bf2f(const bf16 v) { return __bfloat162float(v); }
__device__ __forceinline__ bf16 f2bf(float v) { return __float2bfloat16(v); }
__device__ __forceinline__ float bfu(u16 h) {
  return __uint_as_float(((unsigned)h) << 16);
}
__device__ __forceinline__ u16 fbu(float v) {
  bf16 b = f2bf(v);
  return *(u16*)&b;
}

// Inputs/outputs fp32 (reference dtype). Internal tensors bf16, math fp32.
// All three matmul-shaped ops (pool-conv, QKV conv, attention PV) on MFMA;
// fp32 weights preserved via hi+lo bf16 split; flash-style dual-direction
// softmax with exact combine.

// ---------------------------------------------------------------------------
// K1: maxpool2x2(fb) + conv1x1 on MFMA. 1024 blocks = b(4) x 64-px tile(256);
// 256 thr (4 waves x 16 px). float4 pool loads (16B/lane); X bf16 swizzled;
// weights hi+lo bf16 (~fp32 precision). LDS 24.3 KB.
// ---------------------------------------------------------------------------
__global__ __launch_bounds__(256, 4) void k_pool_conv(
    const float* __restrict__ fb, const float* __restrict__ wconv,
    const float* __restrict__ bconv, bf16* __restrict__ Y) {
  __shared__ __align__(16) u16 Xs[64 * 64];               // [px][c], swizzled
  __shared__ __align__(16) u16 wHi[64 * 64], wLo[64 * 64];  // [oc][c], swz
  __shared__ float bS[64];
  int tid = threadIdx.x;
  int b = blockIdx.x >> 8, tile = blockIdx.x & 255;
  int n0 = tile * 64;
  int h = n0 >> 7, w0 = n0 & 127;
  // stage weights hi+lo, swizzle (oc&7)<<3 (u16 units)
  for (int i = tid; i < 4096; i += 256) {
    int oc = i >> 6, c = i & 63;
    float wv = wconv[oc * 64 + c];
    u16 hb = fbu(wv);
    u16 lb = fbu(wv - bfu(hb));
    int idx = i ^ ((oc & 7) << 3);
    wHi[idx] = hb;
    wLo[idx] = lb;
  }
  if (tid < 64) bS[tid] = bconv[tid];
  // pool: thread handles (c, px-pair); 2x float4 = rows 2h, 2h+1
  for (int i2 = tid; i2 < 2048; i2 += 256) {
    int c = i2 >> 5, pp = i2 & 31;
    const float* r0 =
        fb + ((size_t)((b * 64 + c) * 256 + 2 * h)) * 256 + 2 * w0 + 4 * pp;
    float4 v0 = *(const float4*)r0;
    float4 v1 = *(const float4*)(r0 + 256);
    int px = 2 * pp;
    float a0 = fmaxf(fmaxf(v0.x, v0.y), fmaxf(v1.x, v1.y));
    float a1 = fmaxf(fmaxf(v0.z, v0.w), fmaxf(v1.z, v1.w));
    Xs[(px * 64 + c) ^ ((((px & 7) ^ ((px >> 3) & 7))) << 3)] = fbu(a0);
    px++;
    Xs[(px * 64 + c) ^ ((((px & 7) ^ ((px >> 3) & 7))) << 3)] = fbu(a1);
  }
  __syncthreads();
  int lane = tid & 63, wv = tid >> 6;
  int il = lane & 15, gq = lane >> 4;
  int pxb = wv * 16;                 // wave owns 16 px
  ss8 afr[2];
#pragma unroll
  for (int ks = 0; ks < 2; ++ks) {
    int px = pxb + il;
    int idx =
        (px * 64 + ks * 32 + gq * 8) ^ ((((px & 7) ^ ((px >> 3) & 7))) << 3);
    afr[ks] = *(const ss8*)&Xs[idx];
  }
#pragma unroll
  for (int oct = 0; oct < 4; ++oct) {
    int oc = oct * 16 + il;          // B-col = out-channel
    ss8 wh[2], wl[2];
#pragma unroll
    for (int ks = 0; ks < 2; ++ks) {
      int idx = (oc * 64 + ks * 32 + gq * 8) ^ ((oc & 7) << 3);
      wh[ks] = *(const ss8*)&wHi[idx];
      wl[ks] = *(const ss8*)&wLo[idx];
    }
    float bv = bS[oc];
    f32x4 acc = {bv, bv, bv, bv};
#pragma unroll
    for (int ks = 0; ks < 2; ++ks) {
      acc = __builtin_amdgcn_mfma_f32_16x16x32_bf16(afr[ks], wh[ks], acc, 0, 0, 0);
      acc = __builtin_amdgcn_mfma_f32_16x16x32_bf16(afr[ks], wl[ks], acc, 0, 0, 0);
    }
    int px0 = pxb + gq * 4;          // D rows = 4 consecutive px
    us4 ov;
#pragma unroll
    for (int r = 0; r < 4; ++r) ov[r] = fbu(acc[r]);
    *(us4*)(Y + (size_t)(b * 64 + oc) * NP + n0 + px0) = ov;
  }
}

// ---------------------------------------------------------------------------
// K2a: stats stage 1.
// ---------------------------------------------------------------------------
__global__ __launch_bounds__(256) void k_stats_p1(const bf16* __restrict__ Y,
                                                  float* __restrict__ PS) {
  int blk = blockIdx.x, tid = threadIdx.x;
  int o = blk >> 3, slab = blk & 7;
  int b = slab >> 1, half = slab & 1;
  const us8* vp =
      (const us8*)(Y + ((size_t)(b * 64 + o)) * NP + half * 8192);
  float s = 0.f, ss = 0.f;
#pragma unroll
  for (int it = 0; it < 4; ++it) {
    us8 v = vp[tid + 256 * it];
#pragma unroll
    for (int e = 0; e < 8; ++e) {
      float f = bfu(v[e]);
      s += f;
      ss = fmaf(f, f, ss);
    }
  }
  for (int off = 32; off > 0; off >>= 1) {
    s += __shfl_down(s, off, 64);
    ss += __shfl_down(ss, off, 64);
  }
  __shared__ float sh[8];
  int wv = tid >> 6, ln = tid & 63;
  if (ln == 0) { sh[wv] = s; sh[4 + wv] = ss; }
  __syncthreads();
  if (tid == 0) {
    PS[blk] = sh[0] + sh[1] + sh[2] + sh[3];
    PS[512 + blk] = sh[4] + sh[5] + sh[6] + sh[7];
  }
}

// K2b: stats stage 2 + BN scale/shift + scalar header (fused)
__global__ __launch_bounds__(64) void k_stats_p2(
    const float* __restrict__ PS, const float* __restrict__ bng,
    const float* __restrict__ bnb, float* __restrict__ SCALE,
    float* __restrict__ SHIFT, const float* xg, const float* fg,
    const float* pg, const float* pg2, const float* cg,
    float* __restrict__ HDR) {
  int o = threadIdx.x;
  float s = 0.f, ss = 0.f;
#pragma unroll
  for (int k = 0; k < 8; ++k) {
    s += PS[o * 8 + k];
    ss += PS[512 + o * 8 + k];
  }
  const float inv = 1.0f / (NB * NP);
  float mu = s * inv;
  float var = ss * inv - mu * mu;
  float r = rsqrtf(var + 1e-5f);
  float sc = r * bng[o];
  SCALE[o] = sc;
  SHIFT[o] = bnb[o] - mu * sc;
  if (o == 0) {
    float vpg = pg[0];
    HDR[1] = vpg * xg[0];
    HDR[2] = pg2[0] * fg[0];
    HDR[3] = 2.0f + vpg;
    HDR[4] = pg2[0];
    HDR[5] = cg[0];
  }
}

// ---------------------------------------------------------------------------
// K4: QKV conv1x1 on MFMA, both modules. 1024 blocks = m(2) x b(4) x 128-px
// tile; weights hi+lo bf16.
// ---------------------------------------------------------------------------
__global__ __launch_bounds__(256, 4) void k_conv_mfma(
    const float* __restrict__ xin, const bf16* __restrict__ Yin,
    const float* __restrict__ SCALE, const float* __restrict__ SHIFT,
    const float* __restrict__ qw0, const float* __restrict__ qb0,
    const float* __restrict__ kw0, const float* __restrict__ kb0,
    const float* __restrict__ vw0, const float* __restrict__ vb0,
    const float* __restrict__ qw1, const float* __restrict__ qb1,
    const float* __restrict__ kw1, const float* __restrict__ kb1,
    const float* __restrict__ vw1, const float* __restrict__ vb1,
    bf16* __restrict__ QK, bf16* __restrict__ V) {
  __shared__ __align__(16) u16 Xs[128 * 64];            // [px][c], swizzled
  __shared__ __align__(16) u16 wHi[80 * 64], wLo[80 * 64];  // [oc][c], swz
  __shared__ float bS[80];
  int tid = threadIdx.x;
  int m = blockIdx.x >> 9;
  int b = (blockIdx.x >> 7) & 3;
  int tile = blockIdx.x & 127;
  int n0 = tile * 128;
  const float* qw = m ? qw1 : qw0;
  const float* qb = m ? qb1 : qb0;
  const float* kw = m ? kw1 : kw0;
  const float* kb = m ? kb1 : kb0;
  const float* vw = m ? vw1 : vw0;
  const float* vb = m ? vb1 : vb0;
  for (int i = tid; i < 5120; i += 256) {
    int oc = i >> 6, c = i & 63;
    float w;
    if (oc < 8) w = qw[oc * 64 + c];
    else if (oc < 16) w = kw[(oc - 8) * 64 + c];
    else w = vw[(oc - 16) * 64 + c];
    u16 hb = fbu(w);
    u16 lb = fbu(w - bfu(hb));
    int idx = (oc * 64 + c) ^ ((oc & 7) << 3);
    wHi[idx] = hb;
    wLo[idx] = lb;
  }
  if (tid < 80)
    bS[tid] = (tid < 8) ? qb[tid] : (tid < 16) ? kb[tid - 8] : vb[tid - 16];
  if (m) {
    for (int i2 = tid; i2 < 1024; i2 += 256) {
      int c = i2 >> 4, vj = i2 & 15;
      us8 v = *(const us8*)(Yin + (size_t)(b * 64 + c) * NP + n0 + vj * 8);
      float sc = SCALE[c], sh = SHIFT[c];
#pragma unroll
      for (int e = 0; e < 8; ++e) {
        int px = vj * 8 + e;
        float f = fmaxf(fmaf(bfu(v[e]), sc, sh), 0.f);
        Xs[(px * 64 + c) ^ ((((px & 7) ^ ((px >> 3) & 7))) << 3)] = fbu(f);
      }
    }
  } else {
    for (int i2 = tid; i2 < 2048; i2 += 256) {
      int c = i2 >> 5, vj = i2 & 31;
      float4 v = *(const float4*)(xin + (size_t)(b * 64 + c) * NP + n0 + vj * 4);
      float vv[4] = {v.x, v.y, v.z, v.w};
#pragma unroll
      for (int r = 0; r < 4; ++r) {
        int px = vj * 4 + r;
        Xs[(px * 64 + c) ^ ((((px & 7) ^ ((px >> 3) & 7))) << 3)] = fbu(vv[r]);
      }
    }
  }
  __syncthreads();
  int lane = tid & 63, wv = tid >> 6;
  int il = lane & 15, gq = lane >> 4;
  int pxb = wv * 32;
  ss8 afr[2][2];
#pragma unroll
  for (int sub = 0; sub < 2; ++sub)
#pragma unroll
    for (int ks = 0; ks < 2; ++ks) {
      int px = pxb + sub * 16 + il;
      int idx =
          (px * 64 + ks * 32 + gq * 8) ^ ((((px & 7) ^ ((px >> 3) & 7))) << 3);
      afr[sub][ks] = *(const ss8*)&Xs[idx];
    }
#pragma unroll
  for (int oct = 0; oct < 5; ++oct) {
    int oc = oct * 16 + il;   // B-col = out-channel
    ss8 wh[2], wl[2];
#pragma unroll
    for (int ks = 0; ks < 2; ++ks) {
      int idx = (oc * 64 + ks * 32 + gq * 8) ^ ((oc & 7) << 3);
      wh[ks] = *(const ss8*)&wHi[idx];
      wl[ks] = *(const ss8*)&wLo[idx];
    }
    float bv = bS[oc];
    bf16* dst;
    size_t basep;
    if (oc < 8) { dst = QK; basep = (size_t)(((m * 2 + 0) * 4 + b) * 8 + oc) * NP; }
    else if (oc < 16) { dst = QK; basep = (size_t)(((m * 2 + 1) * 4 + b) * 8 + (oc - 8)) * NP; }
    else { dst = V; basep = (size_t)((m * 4 + b) * 64 + (oc - 16)) * NP; }
#pragma unroll
    for (int sub = 0; sub < 2; ++sub) {
      f32x4 acc = {bv, bv, bv, bv};
#pragma unroll
      for (int ks = 0; ks < 2; ++ks) {
        acc = __builtin_amdgcn_mfma_f32_16x16x32_bf16(afr[sub][ks], wh[ks], acc, 0, 0, 0);
        acc = __builtin_amdgcn_mfma_f32_16x16x32_bf16(afr[sub][ks], wl[ks], acc, 0, 0, 0);
      }
      int px0 = pxb + sub * 16 + gq * 4;   // D rows = 4 consecutive px
      us4 ov;
#pragma unroll
      for (int r = 0; r < 4; ++r) ov[r] = fbu(acc[r]);
      *(us4*)(dst + basep + n0 + px0) = ov;
    }
  }
}

// ---------------------------------------------------------------------------
// K5: 128x128 bf16 plane transpose over two tensor pairs in one dispatch.
// ---------------------------------------------------------------------------
__global__ __launch_bounds__(256) void k_transpose2(
    const u16* __restrict__ inA, u16* __restrict__ outA,
    const u16* __restrict__ inB, u16* __restrict__ outB, int nA) {
  int tileId = blockIdx.x & 15;
  int plane = blockIdx.x >> 4;
  const u16* ip;
  u16* op;
  if (plane < nA) {
    ip = inA + (size_t)plane * NP;
    op = outA + (size_t)plane * NP;
  } else {
    ip = inB + (size_t)(plane - nA) * NP;
    op = outB + (size_t)(plane - nA) * NP;
  }
  int th = tileId >> 2, tw = tileId & 3;
  __shared__ u16 t[32][33];
  int lx = threadIdx.x & 31, ly = threadIdx.x >> 5;
  for (int i = 0; i < 32; i += 8)
    t[ly + i][lx] = ip[(size_t)(th * 32 + ly + i) * 128 + tw * 32 + lx];
  __syncthreads();
  for (int i = 0; i < 32; i += 8)
    op[(size_t)(tw * 32 + ly + i) * 128 + th * 32 + lx] = t[lx][ly + i];
}

// ---------------------------------------------------------------------------
// K7: out_w + out_h, both modules, on MFMA, flash-style. 2048 blocks =
// (b,h) x mode x m; 256 thr.
// ---------------------------------------------------------------------------
__global__ __launch_bounds__(256, 4) void k_av(
    const bf16* __restrict__ QK, const bf16* __restrict__ QKT,
    const bf16* __restrict__ V, const bf16* __restrict__ VT,
    float* __restrict__ MWp, float* __restrict__ LWp,
    float* __restrict__ MHp, float* __restrict__ LHp,
    float* __restrict__ OW, bf16* __restrict__ OHT) {
  int blk = blockIdx.x;
  int m = blk & 1, mode = (blk >> 1) & 1;
  int bid = blk >> 2;
  int b = bid >> 7, h = bid & 127;
  const bf16* qkbase = mode ? QKT : QK;
  const bf16* Qp = qkbase + (size_t)(((m * 2 + 0) * 4 + b) * 8) * NP;
  const bf16* Kp = qkbase + (size_t)(((m * 2 + 1) * 4 + b) * 8) * NP;
  const bf16* Vp = (mode ? VT : V) + (size_t)((m * 4 + b) * 64) * NP;
  __shared__ __align__(16) u16 qT[128 * 8];    // [p(j)][c]
  __shared__ __align__(16) u16 kT[128 * 8];    // [p(j)][c]
  __shared__ __align__(16) u16 Vs[64 * 136];   // [c][j], pad 136
  int tid = threadIdx.x;
  {  // q (tid<128) / k (tid>=128): 1024 u16 each, one us8 load per thread
    int c = (tid >> 4) & 7, vj = tid & 15;
    const bf16* src = (tid < 128) ? Qp : Kp;
    u16* dst = (tid < 128) ? qT : kT;
    const us8* sp = (const us8*)(src + (size_t)c * NP + (size_t)h * 128);
    us8 sv = sp[vj];
#pragma unroll
    for (int e = 0; e < 8; ++e) {
      int j = vj * 8 + e;
      int p = ((j & 7) << 4) | (j >> 3);
      dst[p * 8 + c] = sv[e];
    }
  }
  for (int i2 = tid; i2 < 1024; i2 += 256) {  // V: 8192 u16, b128 writes
    int c = i2 >> 4, vj = i2 & 15;
    const us8* vp = (const us8*)(Vp + (size_t)c * NP + (size_t)h * 128);
    us8 vv = vp[vj];
    *(us8*)&Vs[c * 136 + vj * 8] = vv;
  }
  __syncthreads();
  int lane = tid & 63, wv = tid >> 6;   // wave wv owns rows [wv*32, wv*32+32)
  int il = lane & 15, gq = lane >> 4;
  size_t sb = (size_t)(m * 4 + b) * NP;
  float* owBase = OW + (size_t)((m * 4 + b) * 64) * NP + (size_t)h * 128;
  bf16* ohBase = OHT + (size_t)((m * 4 + b) * 64) * NP + (size_t)h * 128;
#pragma unroll
  for (int sub = 0; sub < 2; ++sub) {
    int ib = wv * 32 + sub * 16;
    int i = ib + il;                 // this lane's A-row (pixel index)
    int pi = ((i & 7) << 4) | (i >> 3);
    us8 qv = *(const us8*)&qT[pi * 8];
    float qr[8];
#pragma unroll
    for (int c = 0; c < 8; ++c) qr[c] = bfu(qv[c]);
    float scr[4][8];
    float mrow = -3.0e38f;
#pragma unroll
    for (int ks = 0; ks < 4; ++ks) {
#pragma unroll
      for (int e = 0; e < 8; ++e) {
        int j = ks * 32 + gq * 8 + e;
        int pj = ((j & 7) << 4) | (j >> 3);
        us8 kv = *(const us8*)&kT[pj * 8];
        float s = 0.f;
#pragma unroll
        for (int c = 0; c < 8; ++c) s = fmaf(qr[c], bfu(kv[c]), s);
        if (mode && j == i) s = -1.0e30f;   // diag mask (exp underflows to 0)
        scr[ks][e] = s;
        mrow = fmaxf(mrow, s);
      }
    }
    mrow = fmaxf(mrow, __shfl_xor(mrow, 16, 64));
    mrow = fmaxf(mrow, __shfl_xor(mrow, 32, 64));
    float l = 0.f;
    ss8 afr[4];
#pragma unroll
    for (int ks = 0; ks < 4; ++ks) {
      ss8 af;
#pragma unroll
      for (int e = 0; e < 8; ++e) {
        float ev = __expf(scr[ks][e] - mrow);
        l += ev;
        af[e] = (short)fbu(ev);
      }
      afr[ks] = af;
    }
    l += __shfl_xor(l, 16, 64);
    l += __shfl_xor(l, 32, 64);
    if (gq == 0) {
      if (mode == 0) {
        MWp[sb + (size_t)h * 128 + i] = mrow;
        LWp[sb + (size_t)h * 128 + i] = l;
      } else {  // store [h][w]-oriented: row i is the h coordinate
        MHp[sb + (size_t)i * 128 + h] = mrow;
        LHp[sb + (size_t)i * 128 + h] = l;
      }
    }
#pragma unroll
    for (int ct = 0; ct < 4; ++ct) {
      f32x4 acc = {0.f, 0.f, 0.f, 0.f};
#pragma unroll
      for (int ks = 0; ks < 4; ++ks) {
        ss8 bv = *(const ss8*)&Vs[(ct * 16 + il) * 136 + ks * 32 + gq * 8];
        acc = __builtin_amdgcn_mfma_f32_16x16x32_bf16(afr[ks], bv, acc, 0, 0, 0);
      }
      int cch = ct * 16 + il;        // D col = channel
      int i0 = ib + gq * 4;          // D rows = 4 consecutive pixels
      if (mode == 0) {
#pragma unroll
        for (int r = 0; r < 4; ++r)
          owBase[(size_t)cch * NP + (size_t)(i0 + r)] = acc[r];
      } else {
#pragma unroll
        for (int r = 0; r < 4; ++r)
          ohBase[(size_t)cch * NP + (size_t)(i0 + r)] = f2bf(acc[r]);
      }
    }
  }
}

// ---------------------------------------------------------------------------
// K8: combine: ACC[b][c][h][w] = sum_m sc_m * (a_m*OW_m + b_m*OHT_m^T)
// where a=e^{mw-M}/L, b=e^{mh-M}/L, M=max(mw,mh), L=lw*e^{mw-M}+lh*e^{mh-M}.
// ---------------------------------------------------------------------------
__global__ __launch_bounds__(256) void k_merge2(
    const bf16* __restrict__ OHT, const float* __restrict__ OW,
    const float* __restrict__ MWp, const float* __restrict__ LWp,
    const float* __restrict__ MHp, const float* __restrict__ LHp,
    const float* __restrict__ HDR, float* __restrict__ ACC) {
  int tileId = blockIdx.x & 15;
  int plane = blockIdx.x >> 4;      // 0..255 = b*64+c
  int b = plane >> 6;
  int th = tileId >> 2, tw = tileId & 3;
  __shared__ float t0[32][33], t1[32][33];
  int lx = threadIdx.x & 31, ly = threadIdx.x >> 5;
  const bf16* ip0 = OHT + (size_t)plane * NP;
  const bf16* ip1 = OHT + (size_t)(256 + plane) * NP;
  for (int i = 0; i < 32; i += 8) {
    size_t idx = (size_t)(th * 32 + ly + i) * 128 + tw * 32 + lx;
    t0[ly + i][lx] = bf2f(ip0[idx]);
    t1[ly + i][lx] = bf2f(ip1[idx]);
  }
  __syncthreads();
  float sc0 = HDR[1], sc1 = HDR[2];
  float* op = ACC + (size_t)plane * NP;
  const float* ow0 = OW + (size_t)plane * NP;
  const float* ow1 = OW + (size_t)(256 + plane) * NP;
  size_t s0 = (size_t)b * NP, s1 = (size_t)(4 + b) * NP;
  for (int i = 0; i < 32; i += 8) {
    int hh = tw * 32 + ly + i, ww = th * 32 + lx;
    size_t idx = (size_t)hh * 128 + ww;
    float mw0 = MWp[s0 + idx], mh0 = MHp[s0 + idx];
    float M0 = fmaxf(mw0, mh0);
    float ea0 = __expf(mw0 - M0), eb0 = __expf(mh0 - M0);
    float inv0 = 1.0f / (LWp[s0 + idx] * ea0 + LHp[s0 + idx] * eb0);
    float v0 = (ea0 * ow0[idx] + eb0 * t0[lx][ly + i]) * inv0;
    float mw1 = MWp[s1 + idx], mh1 = MHp[s1 + idx];
    float M1 = fmaxf(mw1, mh1);
    float ea1 = __expf(mw1 - M1), eb1 = __expf(mh1 - M1);
    float inv1 = 1.0f / (LWp[s1 + idx] * ea1 + LHp[s1 + idx] * eb1);
    float v1 = (ea1 * ow1[idx] + eb1 * t1[lx][ly + i]) * inv1;
    op[idx] = sc0 * v0 + sc1 * v1;
  }
}

// ---------------------------------------------------------------------------
// K9: partial Gram of y=BN(Y). 512 blocks = b x ch x t.
// ---------------------------------------------------------------------------
__global__ __launch_bounds__(256) void k_gram(const bf16* __restrict__ Y,
                                              const float* __restrict__ SCALE,
                                              const float* __restrict__ SHIFT,
                                              float* __restrict__ GP) {
  int b = blockIdx.x >> 7, ch = (blockIdx.x >> 2) & 31, t = blockIdx.x & 3;
  int tid = threadIdx.x;
  __shared__ float fs[64 * 129];
  int cg = tid >> 4, dg = tid & 15;
  float acc[4][4];
#pragma unroll
  for (int i = 0; i < 4; ++i)
#pragma unroll
    for (int jx = 0; jx < 4; ++jx) acc[i][jx] = 0.f;
  const bf16* yb = Y + (size_t)b * 64 * NP + ch * 512;
  for (int idx = tid; idx < 8192; idx += 256) {
    int c = idx >> 7, j = idx & 127;
    float v = fmaf(bf2f(yb[(size_t)c * NP + t * 128 + j]), SCALE[c], SHIFT[c]);
    fs[c * 129 + j] = fmaxf(v, 0.f);
  }
  __syncthreads();
  for (int j = 0; j < 128; ++j) {
    float a[4], d[4];
#pragma unroll
    for (int i = 0; i < 4; ++i) a[i] = fs[(cg * 4 + i) * 129 + j];
#pragma unroll
    for (int i = 0; i < 4; ++i) d[i] = fs[(dg * 4 + i) * 129 + j];
#pragma unroll
    for (int i = 0; i < 4; ++i)
#pragma unroll
      for (int jx = 0; jx < 4; ++jx) acc[i][jx] = fmaf(a[i], d[jx], acc[i][jx]);
  }
  float* gp = GP + ((size_t)(b * 128) + ch * 4 + t) * 4096;
#pragma unroll
  for (int i = 0; i < 4; ++i)
#pragma unroll
    for (int jx = 0; jx < 4; ++jx)
      gp[(cg * 4 + i) * 64 + dg * 4 + jx] = acc[i][jx];
}

// K10: reduce 128 Gram partials; row softmax of (max-E). 64 blocks.
__global__ __launch_bounds__(256) void k_gram_reduce(const float* __restrict__ GP,
                                                     float* __restrict__ CATT) {
  int b = blockIdx.x >> 4, rg = blockIdx.x & 15;
  int tid = threadIdx.x;
  __shared__ float Es[256];
  int e = rg * 256 + tid;
  float s = 0.f;
  for (int k = 0; k < 128; ++k) s += GP[((size_t)b * 128 + k) * 4096 + e];
  Es[tid] = s;
  __syncthreads();
  int wv = tid >> 6, ln = tid & 63;
  float v = Es[wv * 64 + ln];
  float mn = v;
  for (int off = 32; off; off >>= 1) mn = fminf(mn, __shfl_xor(mn, off, 64));
  float ev = __expf(mn - v);
  float ssum = ev;
  for (int off = 32; off; off >>= 1) ssum += __shfl_xor(ssum, off, 64);
  CATT[((size_t)b * 64 + rg * 4 + wv) * 64 + ln] = ev / ssum;
}

// ---------------------------------------------------------------------------
// K11: out = (2+pg)*x + pg2*y + ACC + cg*(catt@y). In-place fp32 on d_out.
// ---------------------------------------------------------------------------
__global__ __launch_bounds__(256) void k_final(
    const float* __restrict__ x, const bf16* __restrict__ Y,
    const float* __restrict__ SCALE, const float* __restrict__ SHIFT,
    const float* __restrict__ CATT, const float* __restrict__ HDR,
    float* __restrict__ OUT) {
  __shared__ float attS[64 * 65], Ys[64 * 65];
  int tid = threadIdx.x;
  int b = blockIdx.x >> 8, tile = blockIdx.x & 255;
  int n0 = tile * 64;
  for (int i = tid; i < 4096; i += 256)
    attS[(i >> 6) * 65 + (i & 63)] = CATT[(size_t)b * 4096 + i];
  for (int i = tid; i < 4096; i += 256) {
    int d = i >> 6, px = i & 63;
    float v = fmaf(bf2f(Y[(size_t)(b * 64 + d) * NP + n0 + px]), SCALE[d], SHIFT[d]);
    Ys[d * 65 + px] = fmaxf(v, 0.f);
  }
  __syncthreads();
  int cg = tid >> 4, pgx = tid & 15;
  int c0 = cg * 4, p0 = pgx * 4;
  float acc[4][4];
#pragma unroll
  for (int i = 0; i < 4; ++i)
#pragma unroll
    for (int j = 0; j < 4; ++j) acc[i][j] = 0.f;
  for (int d = 0; d < 64; ++d) {
    float a[4], yv[4];
#pragma unroll
    for (int i = 0; i < 4; ++i) a[i] = attS[(c0 + i) * 65 + d];
#pragma unroll
    for (int j = 0; j < 4; ++j) yv[j] = Ys[d * 65 + p0 + j];
#pragma unroll
    for (int i = 0; i < 4; ++i)
#pragma unroll
      for (int j = 0; j < 4; ++j) acc[i][j] = fmaf(a[i], yv[j], acc[i][j]);
  }
  float c2pg = HDR[3], fpg2 = HDR[4], fcg = HDR[5];
#pragma unroll
  for (int i = 0; i < 4; ++i) {
    size_t base = (size_t)(b * 64 + c0 + i) * NP + n0 + p0;
#pragma unroll
    for (int j = 0; j < 4; ++j) {
      float yv = Ys[(c0 + i) * 65 + p0 + j];
      OUT[base + j] =
          c2pg * x[base + j] + fpg2 * yv + OUT[base + j] + fcg * acc[i][j];
    }
  }
}

// ---------------------------------------------------------------------------
extern "C" void kernel_launch(void* const* d_in, const int* in_sizes, int n_in,
                              void* d_out, int out_size, void* d_ws, size_t ws_size,
                              hipStream_t stream) {
  const float* x = (const float*)d_in[0];
  const float* fbp = (const float*)d_in[1];

  // ~107 MB of the 256 MiB workspace.
  char* base = (char*)d_ws;
  float* HDR = (float*)base;
  float* SCALE = HDR + 16;
  float* SHIFT = SCALE + 64;
  char* p = base + 4096;
  bf16* Y = (bf16*)p;    p += 8388608;   // [4][64][NP]
  bf16* QK = (bf16*)p;   p += 4194304;   // [m][q/k][4][8][NP] = 128 planes
  bf16* QKT = (bf16*)p;  p += 4194304;
  bf16* V = (bf16*)p;    p += 16777216;  // [m][4][64][NP] = 512 planes
  bf16* VT = (bf16*)p;   p += 16777216;
  float* MWp = (float*)p; p += 524288;   // [m][4][NP] raw w-dir max ([h][w])
  float* LWp = (float*)p; p += 524288;   // raw w-dir sumexp
  float* MHp = (float*)p; p += 524288;   // raw h-dir max ([h][w]-oriented)
  float* LHp = (float*)p; p += 524288;   // raw h-dir sumexp
  bf16* OHT = (bf16*)p;  p += 16777216;  // [m][4][64][NP] raw out_h [c][w][h]
  float* OW = (float*)p; p += 33554432;  // [m][4][64][NP] fp32 raw out_w
  float* GP = (float*)p; p += 8388608;   // Gram partials
  float* CATT = (float*)p; p += 1048576;
  float* ACC = (float*)d_out;
  float* PS = (float*)QK;  // stats partials (4 KB), QK unused until conv

  k_pool_conv<<<1024, 256, 0, stream>>>(fbp, (const float*)d_in[2],
                                        (const float*)d_in[3], Y);
  k_stats_p1<<<512, 256, 0, stream>>>(Y, PS);
  k_stats_p2<<<1, 64, 0, stream>>>(PS, (const float*)d_in[4],
                                   (const float*)d_in[5], SCALE, SHIFT,
                                   (const float*)d_in[12], (const float*)d_in[19],
                                   (const float*)d_in[20], (const float*)d_in[21],
                                   (const float*)d_in[22], HDR);

  // QKV conv on MFMA, both modules (1024 blocks = m x b x 128-px tile)
  k_conv_mfma<<<1024, 256, 0, stream>>>(
      x, Y, SCALE, SHIFT,
      (const float*)d_in[6], (const float*)d_in[7], (const float*)d_in[8],
      (const float*)d_in[9], (const float*)d_in[10], (const float*)d_in[11],
      (const float*)d_in[13], (const float*)d_in[14], (const float*)d_in[15],
      (const float*)d_in[16], (const float*)d_in[17], (const float*)d_in[18],
      QK, V);
  k_transpose2<<<10240, 256, 0, stream>>>((const u16*)QK, (u16*)QKT,
                                          (const u16*)V, (u16*)VT, 128);
  // flash-style attention: stats + unnormalized outputs in one pass
  k_av<<<2048, 256, 0, stream>>>(QK, QKT, V, VT, MWp, LWp, MHp, LHp, OW, OHT);
  // exact combine of both directions and both modules -> ACC (pure store)
  k_merge2<<<4096, 256, 0, stream>>>(OHT, OW, MWp, LWp, MHp, LHp, HDR, ACC);

  k_gram<<<512, 256, 0, stream>>>(Y, SCALE, SHIFT, GP);
  k_gram_reduce<<<64, 256, 0, stream>>>(GP, CATT);
  k_final<<<1024, 256, 0, stream>>>(x, Y, SCALE, SHIFT, CATT, HDR,
                                    (float*)d_out);
}